// Round 1
// baseline (13134.653 us; speedup 1.0000x reference)
//
#include <hip/hip_runtime.h>
#include <math.h>

#define SDIM 128
#define HID 64
#define DEPTH 4
#define CUTOFF_F 5.0f

__device__ __forceinline__ float silu_f(float x) {
    return x / (1.0f + __expf(-x));
}

// ---------------------------------------------------------------------------
// Index decode: harness may hand us int64 (reference dtype) or int32.
// int64-read of an int32 buffer combines two indices -> value >= 2^32 when the
// odd word != 0 (node ids are uniform in [0,50000), so this triggers ~surely).
// ---------------------------------------------------------------------------
__global__ void detect_idx_kernel(const void* ei, int N, int* flag) {
    const long long* p64 = (const long long*)ei;
    int ok64 = 1;
    for (int i = 0; i < 64; ++i) {
        long long v = p64[i];
        if (v < 0 || v >= (long long)N) { ok64 = 0; break; }
    }
    *flag = ok64;
}

__global__ void decode_idx_kernel(const void* ei, int E, int N, const int* flag,
                                  int* __restrict__ srcw, int* __restrict__ dstw) {
    int i = blockIdx.x * blockDim.x + threadIdx.x;
    if (i >= 2 * E) return;
    int v;
    if (*flag) v = (int)((const long long*)ei)[i];
    else       v = ((const int*)ei)[i];
    v = min(max(v, 0), N - 1);   // clamp: crash-proof even if decode guess is wrong
    if (i < E) srcw[i] = v; else dstw[i - E] = v;
}

// C[e] and degree histogram
__global__ void prep_kernel(const float* __restrict__ d, const int* __restrict__ dstw,
                            float* __restrict__ C, float* __restrict__ deg, int E) {
    int e = blockIdx.x * blockDim.x + threadIdx.x;
    if (e >= E) return;
    float dd = d[e];
    float c = 0.5f * (cosf(3.14159265358979323846f * dd * (1.0f / CUTOFF_F)) + 1.0f);
    C[e] = (dd < CUTOFF_F) ? c : 0.0f;
    atomicAdd(&deg[dstw[e]], 1.0f);
}

// ---------------------------------------------------------------------------
// Node-level hoist of edge GEMM1: Pa = s @ We1[0:128], Pb = s @ We1[128:256]
// Block = 256 threads, 64 nodes. lane=node-row, 16 outputs/thread.
// ---------------------------------------------------------------------------
__global__ __launch_bounds__(256) void node_pre_kernel(
    const float* __restrict__ s, const float* __restrict__ W, // (257,64) slice
    float* __restrict__ Pa, float* __restrict__ Pb, int N)
{
    __shared__ float sl[64 * 129];   // stride 129: conflict-free lane=row reads
    int t = threadIdx.x;
    int n0 = blockIdx.x * 64;
    for (int idx = t; idx < 64 * (SDIM / 4); idx += 256) {
        int rn = idx >> 5;
        int c4 = (idx & 31) << 2;
        int n = n0 + rn;
        float4 val = make_float4(0.f, 0.f, 0.f, 0.f);
        if (n < N) val = *(const float4*)(s + (size_t)n * SDIM + c4);
        sl[rn * 129 + c4 + 0] = val.x;
        sl[rn * 129 + c4 + 1] = val.y;
        sl[rn * 129 + c4 + 2] = val.z;
        sl[rn * 129 + c4 + 3] = val.w;
    }
    __syncthreads();
    int r = t & 63;
    int j0 = __builtin_amdgcn_readfirstlane((t >> 6) << 4);  // wave-uniform -> s_load weights
    float accA[16], accB[16];
#pragma unroll
    for (int i = 0; i < 16; ++i) { accA[i] = 0.f; accB[i] = 0.f; }
    for (int k = 0; k < SDIM; ++k) {
        float sv = sl[r * 129 + k];
        const float* wa = W + k * HID + j0;
        const float* wb = W + (k + 128) * HID + j0;
#pragma unroll
        for (int i = 0; i < 16; ++i) accA[i] = fmaf(sv, wa[i], accA[i]);
#pragma unroll
        for (int i = 0; i < 16; ++i) accB[i] = fmaf(sv, wb[i], accB[i]);
    }
    int n = n0 + r;
    if (n < N) {
        float* pa = Pa + (size_t)n * HID + j0;
        float* pb = Pb + (size_t)n * HID + j0;
#pragma unroll
        for (int i = 0; i < 16; i += 4) {
            *(float4*)(pa + i) = make_float4(accA[i], accA[i+1], accA[i+2], accA[i+3]);
            *(float4*)(pb + i) = make_float4(accB[i], accB[i+1], accB[i+2], accB[i+3]);
        }
    }
}

// ---------------------------------------------------------------------------
// Fused edge kernel: h1=silu(Pa[dst]+Pb[src]+d*wd+be1); h=silu(h1@We2+be2)*C;
// atomic agg_s; gates=h@Wv+bv; mv; atomic agg_v.  Block = 64 edges.
// ---------------------------------------------------------------------------
__global__ __launch_bounds__(256) void edge_kernel(
    const int* __restrict__ srcw, const int* __restrict__ dstw,
    const float* __restrict__ dvec, const float* __restrict__ Cvec,
    const float* __restrict__ Pa, const float* __restrict__ Pb,
    const float* __restrict__ wd, const float* __restrict__ be1,
    const float* __restrict__ We2, const float* __restrict__ be2,
    const float* __restrict__ Wv, const float* __restrict__ bv,
    const float* __restrict__ v, const float* __restrict__ rvec,
    float* __restrict__ agg_s, float* __restrict__ agg_v, int E)
{
    __shared__ float hp[64 * 65];
    __shared__ float gl[64 * 8];
    __shared__ int   m_src[64], m_dst[64];
    __shared__ float m_d[64], m_C[64];
    int t = threadIdx.x;
    int e0 = blockIdx.x * 64;
    if (t < 64) {
        int e = e0 + t;
        int ec = (e < E) ? e : (E - 1);
        m_src[t] = srcw[ec];
        m_dst[t] = dstw[ec];
        m_d[t]   = dvec[ec];
        m_C[t]   = (e < E) ? Cvec[ec] : 0.0f;
    }
    __syncthreads();
    int r = t & 63;
    int j0 = __builtin_amdgcn_readfirstlane((t >> 6) << 4);
    bool valid = (e0 + r) < E;
    int dstr = m_dst[r], srcr = m_src[r];
    float edv = m_d[r], eC = m_C[r];

    // phase 1: h1 + silu -> hp
    {
        const float* pa = Pa + (size_t)dstr * HID + j0;
        const float* pb = Pb + (size_t)srcr * HID + j0;
#pragma unroll
        for (int i = 0; i < 16; i += 4) {
            float4 a = *(const float4*)(pa + i);
            float4 b = *(const float4*)(pb + i);
            float h0 = a.x + b.x + edv * wd[j0+i+0] + be1[j0+i+0];
            float h1 = a.y + b.y + edv * wd[j0+i+1] + be1[j0+i+1];
            float h2 = a.z + b.z + edv * wd[j0+i+2] + be1[j0+i+2];
            float h3 = a.w + b.w + edv * wd[j0+i+3] + be1[j0+i+3];
            hp[r*65 + j0 + i + 0] = silu_f(h0);
            hp[r*65 + j0 + i + 1] = silu_f(h1);
            hp[r*65 + j0 + i + 2] = silu_f(h2);
            hp[r*65 + j0 + i + 3] = silu_f(h3);
        }
    }
    __syncthreads();

    // phase 2: h = silu(hp @ We2 + be2) * C ; atomic into agg_s
    float acc[16];
#pragma unroll
    for (int i = 0; i < 16; ++i) acc[i] = be2[j0 + i];
    for (int k = 0; k < HID; ++k) {
        float hv = hp[r * 65 + k];
        const float* w = We2 + k * HID + j0;
#pragma unroll
        for (int i = 0; i < 16; ++i) acc[i] = fmaf(hv, w[i], acc[i]);
    }
    __syncthreads();   // all hp reads done before overwrite
    float hC[16];
#pragma unroll
    for (int i = 0; i < 16; ++i) hC[i] = silu_f(acc[i]) * eC;
#pragma unroll
    for (int i = 0; i < 16; ++i) hp[r * 65 + j0 + i] = hC[i];
    if (valid) {
        float* as = agg_s + (size_t)dstr * HID + j0;
#pragma unroll
        for (int i = 0; i < 16; ++i) atomicAdd(as + i, hC[i]);
    }
    __syncthreads();

    // phase 3: gates = h @ Wv + bv  (wave q computes cols q and q+4<6)
    {
        int q = __builtin_amdgcn_readfirstlane(t >> 6);
        float g1 = bv[q];
        float g2 = (q < 2) ? bv[q + 4] : 0.0f;
        for (int k = 0; k < HID; ++k) {
            float hv = hp[r * 65 + k];
            g1 = fmaf(hv, Wv[k * 6 + q], g1);
            if (q < 2) g2 = fmaf(hv, Wv[k * 6 + q + 4], g2);
        }
        gl[r * 8 + q] = g1;
        if (q < 2) gl[r * 8 + q + 4] = g2;
    }
    __syncthreads();

    // phase 4: mv = v[src]*g1 + r*g2 ; atomic into agg_v (wave 0 only)
    if (t < 64 && valid) {
        float g1v[3] = { gl[t*8+0], gl[t*8+1], gl[t*8+2] };
        float g2v[3] = { gl[t*8+3], gl[t*8+4], gl[t*8+5] };
        const float* vr = v + (size_t)m_src[t] * 9;
        const float* rr = rvec + (size_t)(e0 + t) * 3;
        float* av = agg_v + (size_t)m_dst[t] * 9;
#pragma unroll
        for (int i = 0; i < 3; ++i) {
            float ri = rr[i];
#pragma unroll
            for (int j = 0; j < 3; ++j) {
                float mv = vr[i*3 + j] * g1v[j] + ri * g2v[j];
                atomicAdd(av + i*3 + j, mv);
            }
        }
    }
}

// ---------------------------------------------------------------------------
// Node update: u = silu([s, agg_s] @ Wn1 + bn1); s += u @ Wn2 + bn2;
// v += agg_v / max(deg,1).  Block = 64 nodes.
// ---------------------------------------------------------------------------
__global__ __launch_bounds__(256) void node_upd_kernel(
    float* __restrict__ s, float* __restrict__ vout,
    const float* __restrict__ agg_s, const float* __restrict__ agg_v,
    const float* __restrict__ deg,
    const float* __restrict__ Wn1, const float* __restrict__ bn1,
    const float* __restrict__ Wn2, const float* __restrict__ bn2,
    int N)
{
    __shared__ float xl[64 * 193];   // [s(128) | agg_s(64)] stride 193 (odd)
    int t = threadIdx.x;
    int n0 = blockIdx.x * 64;
    for (int idx = t; idx < 64 * 32; idx += 256) {
        int rn = idx >> 5, c4 = (idx & 31) << 2;
        int n = n0 + rn;
        float4 val = make_float4(0.f, 0.f, 0.f, 0.f);
        if (n < N) val = *(const float4*)(s + (size_t)n * SDIM + c4);
        xl[rn*193 + c4 + 0] = val.x;
        xl[rn*193 + c4 + 1] = val.y;
        xl[rn*193 + c4 + 2] = val.z;
        xl[rn*193 + c4 + 3] = val.w;
    }
    for (int idx = t; idx < 64 * 16; idx += 256) {
        int rn = idx >> 4, c4 = (idx & 15) << 2;
        int n = n0 + rn;
        float4 val = make_float4(0.f, 0.f, 0.f, 0.f);
        if (n < N) val = *(const float4*)(agg_s + (size_t)n * HID + c4);
        xl[rn*193 + 128 + c4 + 0] = val.x;
        xl[rn*193 + 128 + c4 + 1] = val.y;
        xl[rn*193 + 128 + c4 + 2] = val.z;
        xl[rn*193 + 128 + c4 + 3] = val.w;
    }
    __syncthreads();
    int r = t & 63;
    int j0 = __builtin_amdgcn_readfirstlane((t >> 6) << 4);
    float acc[16];
#pragma unroll
    for (int i = 0; i < 16; ++i) acc[i] = bn1[j0 + i];
    for (int k = 0; k < SDIM + HID; ++k) {
        float xv = xl[r * 193 + k];
        const float* w = Wn1 + k * HID + j0;
#pragma unroll
        for (int i = 0; i < 16; ++i) acc[i] = fmaf(xv, w[i], acc[i]);
    }
    float u[16];
#pragma unroll
    for (int i = 0; i < 16; ++i) u[i] = silu_f(acc[i]);
    __syncthreads();   // xl reads done
#pragma unroll
    for (int i = 0; i < 16; ++i) xl[r * 65 + j0 + i] = u[i];  // reuse LDS, stride 65
    __syncthreads();

    int j2 = __builtin_amdgcn_readfirstlane((t >> 6) << 5);   // 32 outputs/thread
    float acc2[32];
#pragma unroll
    for (int i = 0; i < 32; ++i) acc2[i] = bn2[j2 + i];
    for (int k = 0; k < HID; ++k) {
        float uv = xl[r * 65 + k];
        const float* w = Wn2 + k * SDIM + j2;
#pragma unroll
        for (int i = 0; i < 32; ++i) acc2[i] = fmaf(uv, w[i], acc2[i]);
    }
    int n = n0 + r;
    if (n < N) {
        float* sp = s + (size_t)n * SDIM + j2;
#pragma unroll
        for (int i = 0; i < 32; i += 4) {
            float4 so = *(const float4*)(sp + i);
            *(float4*)(sp + i) = make_float4(so.x + acc2[i], so.y + acc2[i+1],
                                             so.z + acc2[i+2], so.w + acc2[i+3]);
        }
    }
    // v += agg_v / max(deg,1): 64*9 values per block
    for (int idx = t; idx < 64 * 9; idx += 256) {
        int rn = idx / 9, c = idx - rn * 9;
        int n2 = n0 + rn;
        if (n2 < N) {
            float dg = fmaxf(deg[n2], 1.0f);
            vout[(size_t)n2 * 9 + c] += agg_v[(size_t)n2 * 9 + c] / dg;
        }
    }
}

extern "C" void kernel_launch(void* const* d_in, const int* in_sizes, int n_in,
                              void* d_out, int out_size, void* d_ws, size_t ws_size,
                              hipStream_t stream)
{
    const float* s_in  = (const float*)d_in[0];
    const float* v_in  = (const float*)d_in[1];
    const void*  ei    = d_in[2];
    const float* d_vec = (const float*)d_in[3];
    const float* r_vec = (const float*)d_in[4];
    const float* We1 = (const float*)d_in[6];
    const float* be1 = (const float*)d_in[7];
    const float* We2 = (const float*)d_in[8];
    const float* be2 = (const float*)d_in[9];
    const float* Wn1 = (const float*)d_in[10];
    const float* bn1 = (const float*)d_in[11];
    const float* Wn2 = (const float*)d_in[12];
    const float* bn2 = (const float*)d_in[13];
    const float* Wv  = (const float*)d_in[14];
    const float* bv  = (const float*)d_in[15];

    int N = in_sizes[0] / SDIM;
    int E = in_sizes[3];

    float* out_s = (float*)d_out;
    float* out_v = out_s + (size_t)N * SDIM;

    float* ws    = (float*)d_ws;
    float* Pa    = ws;                          // N*64
    float* Pb    = Pa + (size_t)N * HID;        // N*64
    float* agg_s = Pb + (size_t)N * HID;        // N*64
    float* agg_v = agg_s + (size_t)N * HID;     // N*9 (contiguous with agg_s)
    float* deg   = agg_v + (size_t)N * 9;       // N
    float* Cv    = deg + N;                     // E
    int*   srcw  = (int*)(Cv + E);              // E
    int*   dstw  = srcw + E;                    // E
    int*   flag  = dstw + E;                    // 1

    hipMemcpyAsync(out_s, s_in, (size_t)N * SDIM * sizeof(float),
                   hipMemcpyDeviceToDevice, stream);
    hipMemcpyAsync(out_v, v_in, (size_t)N * 9 * sizeof(float),
                   hipMemcpyDeviceToDevice, stream);

    detect_idx_kernel<<<1, 1, 0, stream>>>(ei, N, flag);
    decode_idx_kernel<<<(2 * E + 255) / 256, 256, 0, stream>>>(ei, E, N, flag, srcw, dstw);
    hipMemsetAsync(deg, 0, (size_t)N * sizeof(float), stream);
    prep_kernel<<<(E + 255) / 256, 256, 0, stream>>>(d_vec, dstw, Cv, deg, E);

    int nb_n = (N + 63) / 64;
    int nb_e = (E + 63) / 64;
    for (int l = 0; l < DEPTH; ++l) {
        const float* We1_l = We1 + (size_t)l * 257 * 64;
        const float* be1_l = be1 + (size_t)l * 64;
        const float* We2_l = We2 + (size_t)l * 64 * 64;
        const float* be2_l = be2 + (size_t)l * 64;
        const float* Wn1_l = Wn1 + (size_t)l * 192 * 64;
        const float* bn1_l = bn1 + (size_t)l * 64;
        const float* Wn2_l = Wn2 + (size_t)l * 64 * 128;
        const float* bn2_l = bn2 + (size_t)l * 128;
        const float* Wv_l  = Wv  + (size_t)l * 64 * 6;
        const float* bv_l  = bv  + (size_t)l * 6;

        hipMemsetAsync(agg_s, 0, (size_t)N * (HID + 9) * sizeof(float), stream);
        node_pre_kernel<<<nb_n, 256, 0, stream>>>(out_s, We1_l, Pa, Pb, N);
        edge_kernel<<<nb_e, 256, 0, stream>>>(srcw, dstw, d_vec, Cv, Pa, Pb,
                                              We1_l + 256 * 64, be1_l, We2_l, be2_l,
                                              Wv_l, bv_l, out_v, r_vec,
                                              agg_s, agg_v, E);
        node_upd_kernel<<<nb_n, 256, 0, stream>>>(out_s, out_v, agg_s, agg_v, deg,
                                                  Wn1_l, bn1_l, Wn2_l, bn2_l, N);
    }
}

// Round 2
// 1851.703 us; speedup vs baseline: 7.0933x; 7.0933x over previous
//
#include <hip/hip_runtime.h>
#include <math.h>

#define SDIM 128
#define HID 64
#define DEPTH 4
#define CUTOFF_F 5.0f

__device__ __forceinline__ float silu_f(float x) {
    return x / (1.0f + __expf(-x));
}

__device__ __forceinline__ unsigned short f2bf(float x) {
    unsigned int u = __float_as_uint(x);
    unsigned int r = (u + 0x7fffu + ((u >> 16) & 1u)) >> 16;   // RNE
    return (unsigned short)r;
}
__device__ __forceinline__ float bflo(unsigned int packed) {
    return __uint_as_float(packed << 16);
}
__device__ __forceinline__ float bfhi(unsigned int packed) {
    return __uint_as_float(packed & 0xffff0000u);
}

// ---------------------------------------------------------------------------
// Index decode: harness may hand us int64 (reference dtype) or int32.
// ---------------------------------------------------------------------------
__global__ void detect_idx_kernel(const void* ei, int N, int* flag) {
    const long long* p64 = (const long long*)ei;
    int ok64 = 1;
    for (int i = 0; i < 64; ++i) {
        long long v = p64[i];
        if (v < 0 || v >= (long long)N) { ok64 = 0; break; }
    }
    *flag = ok64;
}

__global__ void decode_idx_kernel(const void* ei, int E, int N, const int* flag,
                                  int* __restrict__ srcw, int* __restrict__ dstw) {
    int i = blockIdx.x * blockDim.x + threadIdx.x;
    if (i >= 2 * E) return;
    int v;
    if (*flag) v = (int)((const long long*)ei)[i];
    else       v = ((const int*)ei)[i];
    v = min(max(v, 0), N - 1);
    if (i < E) srcw[i] = v; else dstw[i - E] = v;
}

// C[e] and integer degree histogram
__global__ void prep_kernel(const float* __restrict__ d, const int* __restrict__ dstw,
                            float* __restrict__ C, int* __restrict__ deg_i, int E) {
    int e = blockIdx.x * blockDim.x + threadIdx.x;
    if (e >= E) return;
    float dd = d[e];
    float c = 0.5f * (cosf(3.14159265358979323846f * dd * (1.0f / CUTOFF_F)) + 1.0f);
    C[e] = (dd < CUTOFF_F) ? c : 0.0f;
    atomicAdd(&deg_i[dstw[e]], 1);
}

// ---------------------------------------------------------------------------
// Single-block exclusive scan of deg_i -> row_start[0..N]  (wave-shuffle based)
// ---------------------------------------------------------------------------
__global__ __launch_bounds__(256) void scan_kernel(const int* __restrict__ deg_i,
                                                   int* __restrict__ row_start, int N) {
    __shared__ int wsum[4];
    __shared__ int carry_s;
    int t = threadIdx.x;
    int lane = t & 63, w = t >> 6;
    if (t == 0) carry_s = 0;
    __syncthreads();
    for (int base = 0; base < N; base += 256) {
        int i = base + t;
        int v = (i < N) ? deg_i[i] : 0;
        int incl = v;
#pragma unroll
        for (int off = 1; off < 64; off <<= 1) {
            int x = __shfl_up(incl, off, 64);
            if (lane >= off) incl += x;
        }
        if (lane == 63) wsum[w] = incl;
        __syncthreads();
        int wpre = 0;
#pragma unroll
        for (int k = 0; k < 4; ++k) if (k < w) wpre += wsum[k];
        int total = wsum[0] + wsum[1] + wsum[2] + wsum[3];
        int carry = carry_s;
        if (i < N) row_start[i] = carry + wpre + incl - v;
        __syncthreads();
        if (t == 0) carry_s = carry + total;
        __syncthreads();
    }
    if (t == 0) row_start[N] = carry_s;
}

// ---------------------------------------------------------------------------
// Scatter edges into dst-sorted order; pre-permute all per-edge data.
// ---------------------------------------------------------------------------
__global__ void scatter_kernel(const int* __restrict__ srcw, const int* __restrict__ dstw,
                               const float* __restrict__ dvec, const float* __restrict__ Cv,
                               const float* __restrict__ rvec,
                               const int* __restrict__ row_start, int* __restrict__ cursor,
                               int* __restrict__ perm_src, int* __restrict__ perm_dst,
                               float* __restrict__ perm_d, float* __restrict__ perm_C,
                               float* __restrict__ perm_r, int E) {
    int e = blockIdx.x * blockDim.x + threadIdx.x;
    if (e >= E) return;
    int dd = dstw[e];
    int ofs = atomicAdd(&cursor[dd], 1);
    int pos = row_start[dd] + ofs;
    perm_src[pos] = srcw[e];
    perm_dst[pos] = dd;
    perm_d[pos]   = dvec[e];
    perm_C[pos]   = Cv[e];
    perm_r[(size_t)pos * 3 + 0] = rvec[(size_t)e * 3 + 0];
    perm_r[(size_t)pos * 3 + 1] = rvec[(size_t)e * 3 + 1];
    perm_r[(size_t)pos * 3 + 2] = rvec[(size_t)e * 3 + 2];
}

// ---------------------------------------------------------------------------
// Node-level hoist of edge GEMM1: Pa = s @ We1[0:128], Pb = s @ We1[128:256]
// ---------------------------------------------------------------------------
__global__ __launch_bounds__(256) void node_pre_kernel(
    const float* __restrict__ s, const float* __restrict__ W,
    float* __restrict__ Pa, float* __restrict__ Pb, int N)
{
    __shared__ float sl[64 * 129];
    int t = threadIdx.x;
    int n0 = blockIdx.x * 64;
    for (int idx = t; idx < 64 * (SDIM / 4); idx += 256) {
        int rn = idx >> 5;
        int c4 = (idx & 31) << 2;
        int n = n0 + rn;
        float4 val = make_float4(0.f, 0.f, 0.f, 0.f);
        if (n < N) val = *(const float4*)(s + (size_t)n * SDIM + c4);
        sl[rn * 129 + c4 + 0] = val.x;
        sl[rn * 129 + c4 + 1] = val.y;
        sl[rn * 129 + c4 + 2] = val.z;
        sl[rn * 129 + c4 + 3] = val.w;
    }
    __syncthreads();
    int r = t & 63;
    int j0 = __builtin_amdgcn_readfirstlane((t >> 6) << 4);
    float accA[16], accB[16];
#pragma unroll
    for (int i = 0; i < 16; ++i) { accA[i] = 0.f; accB[i] = 0.f; }
    for (int k = 0; k < SDIM; ++k) {
        float sv = sl[r * 129 + k];
        const float* wa = W + k * HID + j0;
        const float* wb = W + (k + 128) * HID + j0;
#pragma unroll
        for (int i = 0; i < 16; ++i) accA[i] = fmaf(sv, wa[i], accA[i]);
#pragma unroll
        for (int i = 0; i < 16; ++i) accB[i] = fmaf(sv, wb[i], accB[i]);
    }
    int n = n0 + r;
    if (n < N) {
        float* pa = Pa + (size_t)n * HID + j0;
        float* pb = Pb + (size_t)n * HID + j0;
#pragma unroll
        for (int i = 0; i < 16; i += 4) {
            *(float4*)(pa + i) = make_float4(accA[i], accA[i+1], accA[i+2], accA[i+3]);
            *(float4*)(pb + i) = make_float4(accB[i], accB[i+1], accB[i+2], accB[i+3]);
        }
    }
}

// ---------------------------------------------------------------------------
// Fused edge kernel (dst-sorted order, NO atomics):
//   h1 = silu(Pa[dst]+Pb[src]+d*wd+be1); h = silu(h1@We2+be2)*C
//   h_perm[pos] <- bf16(h); gates = h@Wv+bv; mv_perm[pos] <- mv
// ---------------------------------------------------------------------------
__global__ __launch_bounds__(256) void edge_kernel(
    const int* __restrict__ perm_src, const int* __restrict__ perm_dst,
    const float* __restrict__ perm_d, const float* __restrict__ perm_C,
    const float* __restrict__ perm_r,
    const float* __restrict__ Pa, const float* __restrict__ Pb,
    const float* __restrict__ wd, const float* __restrict__ be1,
    const float* __restrict__ We2, const float* __restrict__ be2,
    const float* __restrict__ Wv, const float* __restrict__ bv,
    const float* __restrict__ v,
    unsigned short* __restrict__ h_perm, float* __restrict__ mv_perm, int E)
{
    __shared__ float hp[64 * 65];
    __shared__ float gl[64 * 8];
    __shared__ int   m_src[64];
    __shared__ float m_d[64], m_C[64];
    __shared__ int   m_dst[64];
    int t = threadIdx.x;
    int e0 = blockIdx.x * 64;
    if (t < 64) {
        int e = e0 + t;
        int ec = (e < E) ? e : (E - 1);
        m_src[t] = perm_src[ec];
        m_dst[t] = perm_dst[ec];
        m_d[t]   = perm_d[ec];
        m_C[t]   = (e < E) ? perm_C[ec] : 0.0f;
    }
    __syncthreads();
    int r = t & 63;
    int j0 = __builtin_amdgcn_readfirstlane((t >> 6) << 4);
    bool valid = (e0 + r) < E;
    int dstr = m_dst[r], srcr = m_src[r];
    float edv = m_d[r], eC = m_C[r];

    // phase 1: h1 + silu -> hp
    {
        const float* pa = Pa + (size_t)dstr * HID + j0;
        const float* pb = Pb + (size_t)srcr * HID + j0;
#pragma unroll
        for (int i = 0; i < 16; i += 4) {
            float4 a = *(const float4*)(pa + i);
            float4 b = *(const float4*)(pb + i);
            float h0 = a.x + b.x + edv * wd[j0+i+0] + be1[j0+i+0];
            float h1 = a.y + b.y + edv * wd[j0+i+1] + be1[j0+i+1];
            float h2 = a.z + b.z + edv * wd[j0+i+2] + be1[j0+i+2];
            float h3 = a.w + b.w + edv * wd[j0+i+3] + be1[j0+i+3];
            hp[r*65 + j0 + i + 0] = silu_f(h0);
            hp[r*65 + j0 + i + 1] = silu_f(h1);
            hp[r*65 + j0 + i + 2] = silu_f(h2);
            hp[r*65 + j0 + i + 3] = silu_f(h3);
        }
    }
    __syncthreads();

    // phase 2: h = silu(hp @ We2 + be2) * C
    float acc[16];
#pragma unroll
    for (int i = 0; i < 16; ++i) acc[i] = be2[j0 + i];
    for (int k = 0; k < HID; ++k) {
        float hv = hp[r * 65 + k];
        const float* w = We2 + k * HID + j0;
#pragma unroll
        for (int i = 0; i < 16; ++i) acc[i] = fmaf(hv, w[i], acc[i]);
    }
    __syncthreads();   // all hp reads done before overwrite
    float hC[16];
#pragma unroll
    for (int i = 0; i < 16; ++i) hC[i] = silu_f(acc[i]) * eC;
#pragma unroll
    for (int i = 0; i < 16; ++i) hp[r * 65 + j0 + i] = hC[i];
    if (valid) {
        // bf16 pack -> 32B store per thread (aligned: j0*2 is a multiple of 32)
        unsigned int pk[8];
#pragma unroll
        for (int i = 0; i < 8; ++i)
            pk[i] = (unsigned int)f2bf(hC[2*i]) | ((unsigned int)f2bf(hC[2*i+1]) << 16);
        unsigned short* hdst = h_perm + (size_t)(e0 + r) * HID + j0;
        *(uint4*)(hdst + 0) = make_uint4(pk[0], pk[1], pk[2], pk[3]);
        *(uint4*)(hdst + 8) = make_uint4(pk[4], pk[5], pk[6], pk[7]);
    }
    __syncthreads();

    // phase 3: gates = h @ Wv + bv  (wave q computes cols q and q+4<6)
    {
        int q = __builtin_amdgcn_readfirstlane(t >> 6);
        float g1 = bv[q];
        float g2 = (q < 2) ? bv[q + 4] : 0.0f;
        for (int k = 0; k < HID; ++k) {
            float hv = hp[r * 65 + k];
            g1 = fmaf(hv, Wv[k * 6 + q], g1);
            if (q < 2) g2 = fmaf(hv, Wv[k * 6 + q + 4], g2);
        }
        gl[r * 8 + q] = g1;
        if (q < 2) gl[r * 8 + q + 4] = g2;
    }
    __syncthreads();

    // phase 4: mv = v[src]*g1 + r*g2 -> mv_perm (distributed over all 256 threads)
    for (int idx = t; idx < 64 * 9; idx += 256) {
        int row = idx / 9, c = idx - row * 9;
        int e = e0 + row;
        if (e < E) {
            int i = c / 3, j = c - i * 3;
            float g1 = gl[row * 8 + j];
            float g2 = gl[row * 8 + 3 + j];
            float mv = v[(size_t)m_src[row] * 9 + c] * g1
                     + perm_r[(size_t)e * 3 + i] * g2;
            mv_perm[(size_t)e * 9 + c] = mv;
        }
    }
}

// ---------------------------------------------------------------------------
// CSR gather: one wave per node, contiguous segment reads, zero atomics.
// lanes 0..31: h (bf16 pairs) -> agg_s ; lanes 32..40: mv -> agg_v/deg
// ---------------------------------------------------------------------------
__global__ __launch_bounds__(256) void gather_kernel(
    const unsigned short* __restrict__ h_perm, const float* __restrict__ mv_perm,
    const int* __restrict__ row_start,
    float* __restrict__ agg_s, float* __restrict__ agg_v, int N)
{
    int t = threadIdx.x;
    int lane = t & 63, w = t >> 6;
    int n = blockIdx.x * 4 + w;
    if (n >= N) return;
    int p0 = row_start[n], p1 = row_start[n + 1];
    if (lane < 32) {
        float a0 = 0.f, a1 = 0.f;
        for (int p = p0; p < p1; ++p) {
            unsigned int u = *(const unsigned int*)(h_perm + (size_t)p * HID + lane * 2);
            a0 += bflo(u);
            a1 += bfhi(u);
        }
        *(float2*)(agg_s + (size_t)n * HID + lane * 2) = make_float2(a0, a1);
    } else if (lane < 41) {
        int c = lane - 32;
        float a = 0.f;
        for (int p = p0; p < p1; ++p) a += mv_perm[(size_t)p * 9 + c];
        float dg = fmaxf((float)(p1 - p0), 1.0f);
        agg_v[(size_t)n * 9 + c] = a / dg;
    }
}

// ---------------------------------------------------------------------------
// Node update: u = silu([s, agg_s] @ Wn1 + bn1); s += u @ Wn2 + bn2; v += agg_v
// ---------------------------------------------------------------------------
__global__ __launch_bounds__(256) void node_upd_kernel(
    float* __restrict__ s, float* __restrict__ vout,
    const float* __restrict__ agg_s, const float* __restrict__ agg_v,
    const float* __restrict__ Wn1, const float* __restrict__ bn1,
    const float* __restrict__ Wn2, const float* __restrict__ bn2,
    int N)
{
    __shared__ float xl[64 * 193];
    int t = threadIdx.x;
    int n0 = blockIdx.x * 64;
    for (int idx = t; idx < 64 * 32; idx += 256) {
        int rn = idx >> 5, c4 = (idx & 31) << 2;
        int n = n0 + rn;
        float4 val = make_float4(0.f, 0.f, 0.f, 0.f);
        if (n < N) val = *(const float4*)(s + (size_t)n * SDIM + c4);
        xl[rn*193 + c4 + 0] = val.x;
        xl[rn*193 + c4 + 1] = val.y;
        xl[rn*193 + c4 + 2] = val.z;
        xl[rn*193 + c4 + 3] = val.w;
    }
    for (int idx = t; idx < 64 * 16; idx += 256) {
        int rn = idx >> 4, c4 = (idx & 15) << 2;
        int n = n0 + rn;
        float4 val = make_float4(0.f, 0.f, 0.f, 0.f);
        if (n < N) val = *(const float4*)(agg_s + (size_t)n * HID + c4);
        xl[rn*193 + 128 + c4 + 0] = val.x;
        xl[rn*193 + 128 + c4 + 1] = val.y;
        xl[rn*193 + 128 + c4 + 2] = val.z;
        xl[rn*193 + 128 + c4 + 3] = val.w;
    }
    __syncthreads();
    int r = t & 63;
    int j0 = __builtin_amdgcn_readfirstlane((t >> 6) << 4);
    float acc[16];
#pragma unroll
    for (int i = 0; i < 16; ++i) acc[i] = bn1[j0 + i];
    for (int k = 0; k < SDIM + HID; ++k) {
        float xv = xl[r * 193 + k];
        const float* w = Wn1 + k * HID + j0;
#pragma unroll
        for (int i = 0; i < 16; ++i) acc[i] = fmaf(xv, w[i], acc[i]);
    }
    float u[16];
#pragma unroll
    for (int i = 0; i < 16; ++i) u[i] = silu_f(acc[i]);
    __syncthreads();
#pragma unroll
    for (int i = 0; i < 16; ++i) xl[r * 65 + j0 + i] = u[i];
    __syncthreads();

    int j2 = __builtin_amdgcn_readfirstlane((t >> 6) << 5);
    float acc2[32];
#pragma unroll
    for (int i = 0; i < 32; ++i) acc2[i] = bn2[j2 + i];
    for (int k = 0; k < HID; ++k) {
        float uv = xl[r * 65 + k];
        const float* w = Wn2 + k * SDIM + j2;
#pragma unroll
        for (int i = 0; i < 32; ++i) acc2[i] = fmaf(uv, w[i], acc2[i]);
    }
    int n = n0 + r;
    if (n < N) {
        float* sp = s + (size_t)n * SDIM + j2;
#pragma unroll
        for (int i = 0; i < 32; i += 4) {
            float4 so = *(const float4*)(sp + i);
            *(float4*)(sp + i) = make_float4(so.x + acc2[i], so.y + acc2[i+1],
                                             so.z + acc2[i+2], so.w + acc2[i+3]);
        }
    }
    for (int idx = t; idx < 64 * 9; idx += 256) {
        int rn = idx / 9, c = idx - rn * 9;
        int n2 = n0 + rn;
        if (n2 < N) {
            vout[(size_t)n2 * 9 + c] += agg_v[(size_t)n2 * 9 + c];
        }
    }
}

extern "C" void kernel_launch(void* const* d_in, const int* in_sizes, int n_in,
                              void* d_out, int out_size, void* d_ws, size_t ws_size,
                              hipStream_t stream)
{
    const float* s_in  = (const float*)d_in[0];
    const float* v_in  = (const float*)d_in[1];
    const void*  ei    = d_in[2];
    const float* d_vec = (const float*)d_in[3];
    const float* r_vec = (const float*)d_in[4];
    const float* We1 = (const float*)d_in[6];
    const float* be1 = (const float*)d_in[7];
    const float* We2 = (const float*)d_in[8];
    const float* be2 = (const float*)d_in[9];
    const float* Wn1 = (const float*)d_in[10];
    const float* bn1 = (const float*)d_in[11];
    const float* Wn2 = (const float*)d_in[12];
    const float* bn2 = (const float*)d_in[13];
    const float* Wv  = (const float*)d_in[14];
    const float* bv  = (const float*)d_in[15];

    int N = in_sizes[0] / SDIM;
    int E = in_sizes[3];

    float* out_s = (float*)d_out;
    float* out_v = out_s + (size_t)N * SDIM;

    // ------ workspace layout ------
    char* wp = (char*)d_ws;
    float* Pa        = (float*)wp;  wp += (size_t)N * HID * 4;
    float* Pb        = (float*)wp;  wp += (size_t)N * HID * 4;
    float* agg_s     = (float*)wp;  wp += (size_t)N * HID * 4;
    float* agg_v     = (float*)wp;  wp += (size_t)N * 9 * 4;
    int*   deg_i     = (int*)wp;    wp += (size_t)N * 4;
    int*   cursor    = (int*)wp;    wp += (size_t)N * 4;
    int*   row_start = (int*)wp;    wp += (size_t)(N + 1) * 4;
    int*   flag      = (int*)wp;    wp += 16;  // keep 16B alignment
    int*   srcw      = (int*)wp;    wp += (size_t)E * 4;
    int*   dstw      = (int*)wp;    wp += (size_t)E * 4;
    float* Cv        = (float*)wp;  wp += (size_t)E * 4;
    int*   perm_src  = (int*)wp;    wp += (size_t)E * 4;
    int*   perm_dst  = (int*)wp;    wp += (size_t)E * 4;
    float* perm_d    = (float*)wp;  wp += (size_t)E * 4;
    float* perm_C    = (float*)wp;  wp += (size_t)E * 4;
    float* perm_r    = (float*)wp;  wp += (size_t)E * 3 * 4;
    float* mv_perm   = (float*)wp;  wp += (size_t)E * 9 * 4;
    unsigned short* h_perm = (unsigned short*)wp;  wp += (size_t)E * HID * 2;

    hipMemcpyAsync(out_s, s_in, (size_t)N * SDIM * sizeof(float),
                   hipMemcpyDeviceToDevice, stream);
    hipMemcpyAsync(out_v, v_in, (size_t)N * 9 * sizeof(float),
                   hipMemcpyDeviceToDevice, stream);

    // ------ one-time prep: decode, cosine-cutoff, degree, scan, scatter ------
    detect_idx_kernel<<<1, 1, 0, stream>>>(ei, N, flag);
    decode_idx_kernel<<<(2 * E + 255) / 256, 256, 0, stream>>>(ei, E, N, flag, srcw, dstw);
    hipMemsetAsync(deg_i, 0, (size_t)N * 2 * sizeof(int), stream);  // deg_i + cursor (adjacent)
    prep_kernel<<<(E + 255) / 256, 256, 0, stream>>>(d_vec, dstw, Cv, deg_i, E);
    scan_kernel<<<1, 256, 0, stream>>>(deg_i, row_start, N);
    scatter_kernel<<<(E + 255) / 256, 256, 0, stream>>>(srcw, dstw, d_vec, Cv, r_vec,
                                                        row_start, cursor,
                                                        perm_src, perm_dst, perm_d, perm_C,
                                                        perm_r, E);

    int nb_n = (N + 63) / 64;
    int nb_e = (E + 63) / 64;
    int nb_g = (N + 3) / 4;
    for (int l = 0; l < DEPTH; ++l) {
        const float* We1_l = We1 + (size_t)l * 257 * 64;
        const float* be1_l = be1 + (size_t)l * 64;
        const float* We2_l = We2 + (size_t)l * 64 * 64;
        const float* be2_l = be2 + (size_t)l * 64;
        const float* Wn1_l = Wn1 + (size_t)l * 192 * 64;
        const float* bn1_l = bn1 + (size_t)l * 64;
        const float* Wn2_l = Wn2 + (size_t)l * 64 * 128;
        const float* bn2_l = bn2 + (size_t)l * 128;
        const float* Wv_l  = Wv  + (size_t)l * 64 * 6;
        const float* bv_l  = bv  + (size_t)l * 6;

        node_pre_kernel<<<nb_n, 256, 0, stream>>>(out_s, We1_l, Pa, Pb, N);
        edge_kernel<<<nb_e, 256, 0, stream>>>(perm_src, perm_dst, perm_d, perm_C, perm_r,
                                              Pa, Pb,
                                              We1_l + 256 * 64, be1_l, We2_l, be2_l,
                                              Wv_l, bv_l, out_v,
                                              h_perm, mv_perm, E);
        gather_kernel<<<nb_g, 256, 0, stream>>>(h_perm, mv_perm, row_start,
                                                agg_s, agg_v, N);
        node_upd_kernel<<<nb_n, 256, 0, stream>>>(out_s, out_v, agg_s, agg_v,
                                                  Wn1_l, bn1_l, Wn2_l, bn2_l, N);
    }
}

// Round 3
// 1683.565 us; speedup vs baseline: 7.8017x; 1.0999x over previous
//
#include <hip/hip_runtime.h>
#include <math.h>

#define SDIM 128
#define HID 64
#define DEPTH 4
#define CUTOFF_F 5.0f

typedef __attribute__((ext_vector_type(8))) short bf16x8;   // 8 bf16 = 4 VGPRs
typedef __attribute__((ext_vector_type(4))) float f32x4;

__device__ __forceinline__ float silu_f(float x) {
    return x / (1.0f + __expf(-x));
}

__device__ __forceinline__ unsigned short f2bf(float x) {
    unsigned int u = __float_as_uint(x);
    unsigned int r = (u + 0x7fffu + ((u >> 16) & 1u)) >> 16;   // RNE
    return (unsigned short)r;
}
__device__ __forceinline__ float bflo(unsigned int packed) {
    return __uint_as_float(packed << 16);
}
__device__ __forceinline__ float bfhi(unsigned int packed) {
    return __uint_as_float(packed & 0xffff0000u);
}

// ---------------------------------------------------------------------------
// Index decode + degree histogram. Harness may hand int64 or int32 indices.
// ---------------------------------------------------------------------------
__global__ void detect_idx_kernel(const void* ei, int N, int* flag) {
    const long long* p64 = (const long long*)ei;
    int ok64 = 1;
    for (int i = 0; i < 64; ++i) {
        long long v = p64[i];
        if (v < 0 || v >= (long long)N) { ok64 = 0; break; }
    }
    *flag = ok64;
}

__global__ void decode_idx_kernel(const void* ei, int E, int N, const int* flag,
                                  int* __restrict__ srcw, int* __restrict__ dstw,
                                  int* __restrict__ deg_i) {
    int i = blockIdx.x * blockDim.x + threadIdx.x;
    if (i >= 2 * E) return;
    int v;
    if (*flag) v = (int)((const long long*)ei)[i];
    else       v = ((const int*)ei)[i];
    v = min(max(v, 0), N - 1);
    if (i < E) {
        srcw[i] = v;
    } else {
        dstw[i - E] = v;
        atomicAdd(&deg_i[v], 1);
    }
}

// ---------------------------------------------------------------------------
// Single-block exclusive scan of deg_i -> row_start[0..N]
// ---------------------------------------------------------------------------
__global__ __launch_bounds__(256) void scan_kernel(const int* __restrict__ deg_i,
                                                   int* __restrict__ row_start, int N) {
    __shared__ int wsum[4];
    __shared__ int carry_s;
    int t = threadIdx.x;
    int lane = t & 63, w = t >> 6;
    if (t == 0) carry_s = 0;
    __syncthreads();
    for (int base = 0; base < N; base += 256) {
        int i = base + t;
        int v = (i < N) ? deg_i[i] : 0;
        int incl = v;
#pragma unroll
        for (int off = 1; off < 64; off <<= 1) {
            int x = __shfl_up(incl, off, 64);
            if (lane >= off) incl += x;
        }
        if (lane == 63) wsum[w] = incl;
        __syncthreads();
        int wpre = 0;
#pragma unroll
        for (int k = 0; k < 4; ++k) if (k < w) wpre += wsum[k];
        int total = wsum[0] + wsum[1] + wsum[2] + wsum[3];
        int carry = carry_s;
        if (i < N) row_start[i] = carry + wpre + incl - v;
        __syncthreads();
        if (t == 0) carry_s = carry + total;
        __syncthreads();
    }
    if (t == 0) row_start[N] = carry_s;
}

// ---------------------------------------------------------------------------
// Scatter: dst-sorted permutation; one packed 32B record per edge:
//   {src, dst, d, C, rx, ry, rz, pad}
// ---------------------------------------------------------------------------
__global__ void scatter_kernel(const int* __restrict__ srcw, const int* __restrict__ dstw,
                               const float* __restrict__ dvec, const float* __restrict__ rvec,
                               const int* __restrict__ row_start, int* __restrict__ cursor,
                               float* __restrict__ rec, int E) {
    int e = blockIdx.x * blockDim.x + threadIdx.x;
    if (e >= E) return;
    int dd = dstw[e];
    int ofs = atomicAdd(&cursor[dd], 1);
    int pos = row_start[dd] + ofs;
    float dv = dvec[e];
    float c = 0.5f * (cosf(3.14159265358979323846f * dv * (1.0f / CUTOFF_F)) + 1.0f);
    c = (dv < CUTOFF_F) ? c : 0.0f;
    float4 r0 = make_float4(__int_as_float(srcw[e]), __int_as_float(dd), dv, c);
    float4 r1 = make_float4(rvec[(size_t)e * 3 + 0], rvec[(size_t)e * 3 + 1],
                            rvec[(size_t)e * 3 + 2], 0.0f);
    *(float4*)(rec + (size_t)pos * 8)     = r0;
    *(float4*)(rec + (size_t)pos * 8 + 4) = r1;
}

// ---------------------------------------------------------------------------
// Node-level hoist of edge GEMM1: Pa = s @ We1[0:128], Pb = s @ We1[128:256]
// ---------------------------------------------------------------------------
__global__ __launch_bounds__(256) void node_pre_kernel(
    const float* __restrict__ s, const float* __restrict__ W,
    float* __restrict__ Pa, float* __restrict__ Pb, int N)
{
    __shared__ float sl[64 * 129];
    int t = threadIdx.x;
    int n0 = blockIdx.x * 64;
    for (int idx = t; idx < 64 * (SDIM / 4); idx += 256) {
        int rn = idx >> 5;
        int c4 = (idx & 31) << 2;
        int n = n0 + rn;
        float4 val = make_float4(0.f, 0.f, 0.f, 0.f);
        if (n < N) val = *(const float4*)(s + (size_t)n * SDIM + c4);
        sl[rn * 129 + c4 + 0] = val.x;
        sl[rn * 129 + c4 + 1] = val.y;
        sl[rn * 129 + c4 + 2] = val.z;
        sl[rn * 129 + c4 + 3] = val.w;
    }
    __syncthreads();
    int r = t & 63;
    int j0 = __builtin_amdgcn_readfirstlane((t >> 6) << 4);
    float accA[16], accB[16];
#pragma unroll
    for (int i = 0; i < 16; ++i) { accA[i] = 0.f; accB[i] = 0.f; }
    for (int k = 0; k < SDIM; ++k) {
        float sv = sl[r * 129 + k];
        const float* wa = W + k * HID + j0;
        const float* wb = W + (k + 128) * HID + j0;
#pragma unroll
        for (int i = 0; i < 16; ++i) accA[i] = fmaf(sv, wa[i], accA[i]);
#pragma unroll
        for (int i = 0; i < 16; ++i) accB[i] = fmaf(sv, wb[i], accB[i]);
    }
    int n = n0 + r;
    if (n < N) {
        float* pa = Pa + (size_t)n * HID + j0;
        float* pb = Pb + (size_t)n * HID + j0;
#pragma unroll
        for (int i = 0; i < 16; i += 4) {
            *(float4*)(pa + i) = make_float4(accA[i], accA[i+1], accA[i+2], accA[i+3]);
            *(float4*)(pb + i) = make_float4(accB[i], accB[i+1], accB[i+2], accB[i+3]);
        }
    }
}

// ---------------------------------------------------------------------------
// Fused edge kernel, phase-2 GEMM on MFMA (bf16 in, fp32 acc):
//   h1 = silu(Pa[dst]+Pb[src]+d*wd+be1)      -> ha (bf16, LDS)
//   h  = silu(h1 @ We2 + be2) * C            via mfma_f32_16x16x32_bf16
//   h_perm[pos] <- bf16(h); gates = h@Wv+bv; mv_perm[pos] <- mv
// ---------------------------------------------------------------------------
__global__ __launch_bounds__(256) void edge_kernel(
    const float* __restrict__ rec,
    const float* __restrict__ Pa, const float* __restrict__ Pb,
    const float* __restrict__ wd, const float* __restrict__ be1,
    const float* __restrict__ We2, const float* __restrict__ be2,
    const float* __restrict__ Wv, const float* __restrict__ bv,
    const float* __restrict__ v,
    unsigned short* __restrict__ h_perm, float* __restrict__ mv_perm, int E)
{
    __shared__ unsigned short ha[64 * 72];   // h1 bf16, row-major, stride 72
    __shared__ unsigned short wt[64 * 72];   // We2^T bf16: wt[n][k]
    __shared__ float hp[64 * 65];            // h fp32 (GEMM output)
    __shared__ float gl[64 * 8];
    __shared__ int   m_src[64];
    __shared__ float m_C[64];
    __shared__ float m_r[64 * 3];
    int t = threadIdx.x;
    int e0 = blockIdx.x * 64;

    // stage We2^T as bf16 (coalesced reads; one-time per block)
    for (int idx = t; idx < 64 * 64; idx += 256) {
        int k = idx >> 6, n = idx & 63;
        wt[n * 72 + k] = f2bf(We2[idx]);
    }
    float edv_l = 0.f;
    int dst_l = 0, src_l = 0;
    if (t < 64) {
        int e = e0 + t;
        int ec = (e < E) ? e : (E - 1);
        float4 r0 = *(const float4*)(rec + (size_t)ec * 8);
        float4 r1 = *(const float4*)(rec + (size_t)ec * 8 + 4);
        m_src[t] = __float_as_int(r0.x);
        m_C[t]   = (e < E) ? r0.w : 0.0f;
        m_r[t*3+0] = r1.x; m_r[t*3+1] = r1.y; m_r[t*3+2] = r1.z;
        src_l = __float_as_int(r0.x);
        dst_l = __float_as_int(r0.y);
        edv_l = r0.z;
    }
    __syncthreads();

    int lane = t & 63;
    int w    = t >> 6;
    int j0 = __builtin_amdgcn_readfirstlane(w << 4);

    // ---- phase 1: h1 = silu(Pa[dst]+Pb[src]+d*wd+be1) -> ha (bf16) ----
    // lane = edge row r, wave covers cols j0..j0+15. Broadcast per-edge
    // scalars via shuffle is avoided: re-read from LDS mirrors.
    {
        int r = lane;
        // per-edge scalars: need dst/src/d for row r -> read from rec-backed LDS?
        // dst/src were only kept in registers of t<64; mirror via LDS:
        // (m_src holds src; dst & d needed too) -> recompute from rec for all waves.
        int e = e0 + r;
        int ec = (e < E) ? e : (E - 1);
        float4 r0 = *(const float4*)(rec + (size_t)ec * 8);
        int dstr = __float_as_int(r0.y);
        int srcr = __float_as_int(r0.x);
        float edv = r0.z;
        const float* pa = Pa + (size_t)dstr * HID + j0;
        const float* pb = Pb + (size_t)srcr * HID + j0;
        unsigned int pk[8];
#pragma unroll
        for (int i = 0; i < 16; i += 4) {
            float4 a = *(const float4*)(pa + i);
            float4 b = *(const float4*)(pb + i);
            float h0 = silu_f(a.x + b.x + edv * wd[j0+i+0] + be1[j0+i+0]);
            float h1 = silu_f(a.y + b.y + edv * wd[j0+i+1] + be1[j0+i+1]);
            float h2 = silu_f(a.z + b.z + edv * wd[j0+i+2] + be1[j0+i+2]);
            float h3 = silu_f(a.w + b.w + edv * wd[j0+i+3] + be1[j0+i+3]);
            pk[i/2+0] = (unsigned int)f2bf(h0) | ((unsigned int)f2bf(h1) << 16);
            pk[i/2+1] = (unsigned int)f2bf(h2) | ((unsigned int)f2bf(h3) << 16);
        }
        // 32B contiguous: ha[r*72 + j0 .. +15]
        unsigned short* hrow = ha + r * 72 + j0;
        *(uint4*)(hrow + 0) = make_uint4(pk[0], pk[1], pk[2], pk[3]);
        *(uint4*)(hrow + 8) = make_uint4(pk[4], pk[5], pk[6], pk[7]);
    }
    __syncthreads();

    // ---- phase 2: MFMA. wave w: edge rows m0..m0+15, all 64 cols ----
    {
        int lm = lane & 15;          // A row / B col / D col
        int lq = lane >> 4;          // quad
        int m0 = w * 16;
        bf16x8 afr0 = *(const bf16x8*)(ha + (m0 + lm) * 72 + lq * 8);
        bf16x8 afr1 = *(const bf16x8*)(ha + (m0 + lm) * 72 + lq * 8 + 32);
        f32x4 acc[4];
#pragma unroll
        for (int t4 = 0; t4 < 4; ++t4) {
            bf16x8 bfr0 = *(const bf16x8*)(wt + (t4 * 16 + lm) * 72 + lq * 8);
            bf16x8 bfr1 = *(const bf16x8*)(wt + (t4 * 16 + lm) * 72 + lq * 8 + 32);
            f32x4 a0 = {0.f, 0.f, 0.f, 0.f};
            a0 = __builtin_amdgcn_mfma_f32_16x16x32_bf16(afr0, bfr0, a0, 0, 0, 0);
            a0 = __builtin_amdgcn_mfma_f32_16x16x32_bf16(afr1, bfr1, a0, 0, 0, 0);
            acc[t4] = a0;
        }
        // D layout: col=lane&15, row=quad*4+reg
#pragma unroll
        for (int t4 = 0; t4 < 4; ++t4) {
#pragma unroll
            for (int g = 0; g < 4; ++g) {
                int er  = m0 + lq * 4 + g;
                int col = t4 * 16 + lm;
                float val = acc[t4][g] + be2[col];
                hp[er * 65 + col] = silu_f(val) * m_C[er];
            }
        }
    }
    __syncthreads();

    // ---- pack h -> h_perm (bf16) + phase 3 gates ----
    {
        int r = lane;
        bool valid = (e0 + r) < E;
        if (valid) {
            unsigned int pk[8];
#pragma unroll
            for (int i = 0; i < 8; ++i) {
                float lo = hp[r * 65 + j0 + 2*i];
                float hi = hp[r * 65 + j0 + 2*i + 1];
                pk[i] = (unsigned int)f2bf(lo) | ((unsigned int)f2bf(hi) << 16);
            }
            unsigned short* hdst = h_perm + (size_t)(e0 + r) * HID + j0;
            *(uint4*)(hdst + 0) = make_uint4(pk[0], pk[1], pk[2], pk[3]);
            *(uint4*)(hdst + 8) = make_uint4(pk[4], pk[5], pk[6], pk[7]);
        }
        int q = __builtin_amdgcn_readfirstlane(w);
        float g1 = bv[q];
        float g2 = (q < 2) ? bv[q + 4] : 0.0f;
        for (int k = 0; k < HID; ++k) {
            float hv = hp[r * 65 + k];
            g1 = fmaf(hv, Wv[k * 6 + q], g1);
            if (q < 2) g2 = fmaf(hv, Wv[k * 6 + q + 4], g2);
        }
        gl[r * 8 + q] = g1;
        if (q < 2) gl[r * 8 + q + 4] = g2;
    }
    __syncthreads();

    // ---- phase 4: mv = v[src]*g1 + r*g2 -> mv_perm ----
    for (int idx = t; idx < 64 * 9; idx += 256) {
        int row = idx / 9, c = idx - row * 9;
        int e = e0 + row;
        if (e < E) {
            int i = c / 3, j = c - i * 3;
            float g1 = gl[row * 8 + j];
            float g2 = gl[row * 8 + 3 + j];
            float mv = v[(size_t)m_src[row] * 9 + c] * g1
                     + m_r[row * 3 + i] * g2;
            mv_perm[(size_t)e * 9 + c] = mv;
        }
    }
}

// ---------------------------------------------------------------------------
// CSR gather: one wave per node, contiguous segment reads, zero atomics.
// ---------------------------------------------------------------------------
__global__ __launch_bounds__(256) void gather_kernel(
    const unsigned short* __restrict__ h_perm, const float* __restrict__ mv_perm,
    const int* __restrict__ row_start,
    float* __restrict__ agg_s, float* __restrict__ agg_v, int N)
{
    int t = threadIdx.x;
    int lane = t & 63, w = t >> 6;
    int n = blockIdx.x * 4 + w;
    if (n >= N) return;
    int p0 = row_start[n], p1 = row_start[n + 1];
    if (lane < 32) {
        float a0 = 0.f, a1 = 0.f;
        for (int p = p0; p < p1; ++p) {
            unsigned int u = *(const unsigned int*)(h_perm + (size_t)p * HID + lane * 2);
            a0 += bflo(u);
            a1 += bfhi(u);
        }
        *(float2*)(agg_s + (size_t)n * HID + lane * 2) = make_float2(a0, a1);
    } else if (lane < 41) {
        int c = lane - 32;
        float a = 0.f;
        for (int p = p0; p < p1; ++p) a += mv_perm[(size_t)p * 9 + c];
        float dg = fmaxf((float)(p1 - p0), 1.0f);
        agg_v[(size_t)n * 9 + c] = a / dg;
    }
}

// ---------------------------------------------------------------------------
// Node update: u = silu([s, agg_s] @ Wn1 + bn1); s += u @ Wn2 + bn2; v += agg_v
// ---------------------------------------------------------------------------
__global__ __launch_bounds__(256) void node_upd_kernel(
    float* __restrict__ s, float* __restrict__ vout,
    const float* __restrict__ agg_s, const float* __restrict__ agg_v,
    const float* __restrict__ Wn1, const float* __restrict__ bn1,
    const float* __restrict__ Wn2, const float* __restrict__ bn2,
    int N)
{
    __shared__ float xl[64 * 193];
    int t = threadIdx.x;
    int n0 = blockIdx.x * 64;
    for (int idx = t; idx < 64 * 32; idx += 256) {
        int rn = idx >> 5, c4 = (idx & 31) << 2;
        int n = n0 + rn;
        float4 val = make_float4(0.f, 0.f, 0.f, 0.f);
        if (n < N) val = *(const float4*)(s + (size_t)n * SDIM + c4);
        xl[rn*193 + c4 + 0] = val.x;
        xl[rn*193 + c4 + 1] = val.y;
        xl[rn*193 + c4 + 2] = val.z;
        xl[rn*193 + c4 + 3] = val.w;
    }
    for (int idx = t; idx < 64 * 16; idx += 256) {
        int rn = idx >> 4, c4 = (idx & 15) << 2;
        int n = n0 + rn;
        float4 val = make_float4(0.f, 0.f, 0.f, 0.f);
        if (n < N) val = *(const float4*)(agg_s + (size_t)n * HID + c4);
        xl[rn*193 + 128 + c4 + 0] = val.x;
        xl[rn*193 + 128 + c4 + 1] = val.y;
        xl[rn*193 + 128 + c4 + 2] = val.z;
        xl[rn*193 + 128 + c4 + 3] = val.w;
    }
    __syncthreads();
    int r = t & 63;
    int j0 = __builtin_amdgcn_readfirstlane((t >> 6) << 4);
    float acc[16];
#pragma unroll
    for (int i = 0; i < 16; ++i) acc[i] = bn1[j0 + i];
    for (int k = 0; k < SDIM + HID; ++k) {
        float xv = xl[r * 193 + k];
        const float* w = Wn1 + k * HID + j0;
#pragma unroll
        for (int i = 0; i < 16; ++i) acc[i] = fmaf(xv, w[i], acc[i]);
    }
    float u[16];
#pragma unroll
    for (int i = 0; i < 16; ++i) u[i] = silu_f(acc[i]);
    __syncthreads();
#pragma unroll
    for (int i = 0; i < 16; ++i) xl[r * 65 + j0 + i] = u[i];
    __syncthreads();

    int j2 = __builtin_amdgcn_readfirstlane((t >> 6) << 5);
    float acc2[32];
#pragma unroll
    for (int i = 0; i < 32; ++i) acc2[i] = bn2[j2 + i];
    for (int k = 0; k < HID; ++k) {
        float uv = xl[r * 65 + k];
        const float* w = Wn2 + k * SDIM + j2;
#pragma unroll
        for (int i = 0; i < 32; ++i) acc2[i] = fmaf(uv, w[i], acc2[i]);
    }
    int n = n0 + r;
    if (n < N) {
        float* sp = s + (size_t)n * SDIM + j2;
#pragma unroll
        for (int i = 0; i < 32; i += 4) {
            float4 so = *(const float4*)(sp + i);
            *(float4*)(sp + i) = make_float4(so.x + acc2[i], so.y + acc2[i+1],
                                             so.z + acc2[i+2], so.w + acc2[i+3]);
        }
    }
    for (int idx = t; idx < 64 * 9; idx += 256) {
        int rn = idx / 9, c = idx - rn * 9;
        int n2 = n0 + rn;
        if (n2 < N) {
            vout[(size_t)n2 * 9 + c] += agg_v[(size_t)n2 * 9 + c];
        }
    }
}

extern "C" void kernel_launch(void* const* d_in, const int* in_sizes, int n_in,
                              void* d_out, int out_size, void* d_ws, size_t ws_size,
                              hipStream_t stream)
{
    const float* s_in  = (const float*)d_in[0];
    const float* v_in  = (const float*)d_in[1];
    const void*  ei    = d_in[2];
    const float* d_vec = (const float*)d_in[3];
    const float* r_vec = (const float*)d_in[4];
    const float* We1 = (const float*)d_in[6];
    const float* be1 = (const float*)d_in[7];
    const float* We2 = (const float*)d_in[8];
    const float* be2 = (const float*)d_in[9];
    const float* Wn1 = (const float*)d_in[10];
    const float* bn1 = (const float*)d_in[11];
    const float* Wn2 = (const float*)d_in[12];
    const float* bn2 = (const float*)d_in[13];
    const float* Wv  = (const float*)d_in[14];
    const float* bv  = (const float*)d_in[15];

    int N = in_sizes[0] / SDIM;
    int E = in_sizes[3];

    float* out_s = (float*)d_out;
    float* out_v = out_s + (size_t)N * SDIM;

    // ------ workspace layout (every block 32B-aligned) ------
    char* wp = (char*)d_ws;
    auto alloc = [&wp](size_t bytes) -> char* {
        char* p = wp;
        wp += (bytes + 31) & ~(size_t)31;
        return p;
    };
    float* rec       = (float*)alloc((size_t)E * 8 * 4);      // 32B records
    unsigned short* h_perm = (unsigned short*)alloc((size_t)E * HID * 2);
    float* mv_perm   = (float*)alloc((size_t)E * 9 * 4);
    float* Pa        = (float*)alloc((size_t)N * HID * 4);
    float* Pb        = (float*)alloc((size_t)N * HID * 4);
    float* agg_s     = (float*)alloc((size_t)N * HID * 4);
    float* agg_v     = (float*)alloc((size_t)N * 9 * 4);
    int*   deg_i     = (int*)alloc((size_t)N * 4);
    int*   cursor    = (int*)alloc((size_t)N * 4);
    int*   row_start = (int*)alloc((size_t)(N + 1) * 4);
    int*   flag      = (int*)alloc(16);
    int*   srcw      = (int*)alloc((size_t)E * 4);
    int*   dstw      = (int*)alloc((size_t)E * 4);

    hipMemcpyAsync(out_s, s_in, (size_t)N * SDIM * sizeof(float),
                   hipMemcpyDeviceToDevice, stream);
    hipMemcpyAsync(out_v, v_in, (size_t)N * 9 * sizeof(float),
                   hipMemcpyDeviceToDevice, stream);

    // ------ one-time prep: decode+deg, scan, scatter(+C) ------
    detect_idx_kernel<<<1, 1, 0, stream>>>(ei, N, flag);
    hipMemsetAsync(deg_i, 0, (size_t)N * sizeof(int), stream);
    hipMemsetAsync(cursor, 0, (size_t)N * sizeof(int), stream);
    decode_idx_kernel<<<(2 * E + 255) / 256, 256, 0, stream>>>(ei, E, N, flag,
                                                               srcw, dstw, deg_i);
    scan_kernel<<<1, 256, 0, stream>>>(deg_i, row_start, N);
    scatter_kernel<<<(E + 255) / 256, 256, 0, stream>>>(srcw, dstw, d_vec, r_vec,
                                                        row_start, cursor, rec, E);

    int nb_n = (N + 63) / 64;
    int nb_e = (E + 63) / 64;
    int nb_g = (N + 3) / 4;
    for (int l = 0; l < DEPTH; ++l) {
        const float* We1_l = We1 + (size_t)l * 257 * 64;
        const float* be1_l = be1 + (size_t)l * 64;
        const float* We2_l = We2 + (size_t)l * 64 * 64;
        const float* be2_l = be2 + (size_t)l * 64;
        const float* Wn1_l = Wn1 + (size_t)l * 192 * 64;
        const float* bn1_l = bn1 + (size_t)l * 64;
        const float* Wn2_l = Wn2 + (size_t)l * 64 * 128;
        const float* bn2_l = bn2 + (size_t)l * 128;
        const float* Wv_l  = Wv  + (size_t)l * 64 * 6;
        const float* bv_l  = bv  + (size_t)l * 6;

        node_pre_kernel<<<nb_n, 256, 0, stream>>>(out_s, We1_l, Pa, Pb, N);
        edge_kernel<<<nb_e, 256, 0, stream>>>(rec, Pa, Pb,
                                              We1_l + 256 * 64, be1_l, We2_l, be2_l,
                                              Wv_l, bv_l, out_v,
                                              h_perm, mv_perm, E);
        gather_kernel<<<nb_g, 256, 0, stream>>>(h_perm, mv_perm, row_start,
                                                agg_s, agg_v, N);
        node_upd_kernel<<<nb_n, 256, 0, stream>>>(out_s, out_v, agg_s, agg_v,
                                                  Wn1_l, bn1_l, Wn2_l, bn2_l, N);
    }
}

// Round 4
// 1264.355 us; speedup vs baseline: 10.3884x; 1.3316x over previous
//
#include <hip/hip_runtime.h>
#include <math.h>

#define SDIM 128
#define HID 64
#define DEPTH 4
#define CUTOFF_F 5.0f

typedef __attribute__((ext_vector_type(8))) short bf16x8;   // 8 bf16 = 4 VGPRs
typedef __attribute__((ext_vector_type(4))) float f32x4;

__device__ __forceinline__ float silu_f(float x) {
    return x / (1.0f + __expf(-x));
}

__device__ __forceinline__ unsigned short f2bf(float x) {
    unsigned int u = __float_as_uint(x);
    unsigned int r = (u + 0x7fffu + ((u >> 16) & 1u)) >> 16;   // RNE
    return (unsigned short)r;
}

struct f8 { float v[8]; };
__device__ __forceinline__ f8 load8(const float* p) {
    f8 r;
    float4 a = *(const float4*)p;
    float4 b = *(const float4*)(p + 4);
    r.v[0]=a.x; r.v[1]=a.y; r.v[2]=a.z; r.v[3]=a.w;
    r.v[4]=b.x; r.v[5]=b.y; r.v[6]=b.z; r.v[7]=b.w;
    return r;
}
__device__ __forceinline__ bf16x8 pack8(const float* h) {
    bf16x8 o;
#pragma unroll
    for (int j = 0; j < 8; ++j) o[j] = (short)f2bf(h[j]);
    return o;
}

// ---------------------------------------------------------------------------
// Index decode + degree histogram. Harness may hand int64 or int32 indices.
// ---------------------------------------------------------------------------
__global__ void detect_idx_kernel(const void* ei, int N, int* flag) {
    const long long* p64 = (const long long*)ei;
    int ok64 = 1;
    for (int i = 0; i < 64; ++i) {
        long long v = p64[i];
        if (v < 0 || v >= (long long)N) { ok64 = 0; break; }
    }
    *flag = ok64;
}

__global__ void decode_idx_kernel(const void* ei, int E, int N, const int* flag,
                                  int* __restrict__ srcw, int* __restrict__ dstw,
                                  int* __restrict__ deg_i) {
    int i = blockIdx.x * blockDim.x + threadIdx.x;
    if (i >= 2 * E) return;
    int v;
    if (*flag) v = (int)((const long long*)ei)[i];
    else       v = ((const int*)ei)[i];
    v = min(max(v, 0), N - 1);
    if (i < E) {
        srcw[i] = v;
    } else {
        dstw[i - E] = v;
        atomicAdd(&deg_i[v], 1);
    }
}

// ---------------------------------------------------------------------------
// Single-block exclusive scan of deg_i -> row_start[0..N]
// ---------------------------------------------------------------------------
__global__ __launch_bounds__(256) void scan_kernel(const int* __restrict__ deg_i,
                                                   int* __restrict__ row_start, int N) {
    __shared__ int wsum[4];
    __shared__ int carry_s;
    int t = threadIdx.x;
    int lane = t & 63, w = t >> 6;
    if (t == 0) carry_s = 0;
    __syncthreads();
    for (int base = 0; base < N; base += 256) {
        int i = base + t;
        int v = (i < N) ? deg_i[i] : 0;
        int incl = v;
#pragma unroll
        for (int off = 1; off < 64; off <<= 1) {
            int x = __shfl_up(incl, off, 64);
            if (lane >= off) incl += x;
        }
        if (lane == 63) wsum[w] = incl;
        __syncthreads();
        int wpre = 0;
#pragma unroll
        for (int k = 0; k < 4; ++k) if (k < w) wpre += wsum[k];
        int total = wsum[0] + wsum[1] + wsum[2] + wsum[3];
        int carry = carry_s;
        if (i < N) row_start[i] = carry + wpre + incl - v;
        __syncthreads();
        if (t == 0) carry_s = carry + total;
        __syncthreads();
    }
    if (t == 0) row_start[N] = carry_s;
}

// ---------------------------------------------------------------------------
// Scatter: dst-sorted permutation; one packed 32B record per edge:
//   {src, dst, d, C, rx, ry, rz, pad}
// ---------------------------------------------------------------------------
__global__ void scatter_kernel(const int* __restrict__ srcw, const int* __restrict__ dstw,
                               const float* __restrict__ dvec, const float* __restrict__ rvec,
                               const int* __restrict__ row_start, int* __restrict__ cursor,
                               float* __restrict__ rec, int E) {
    int e = blockIdx.x * blockDim.x + threadIdx.x;
    if (e >= E) return;
    int dd = dstw[e];
    int ofs = atomicAdd(&cursor[dd], 1);
    int pos = row_start[dd] + ofs;
    float dv = dvec[e];
    float c = 0.5f * (cosf(3.14159265358979323846f * dv * (1.0f / CUTOFF_F)) + 1.0f);
    c = (dv < CUTOFF_F) ? c : 0.0f;
    float4 r0 = make_float4(__int_as_float(srcw[e]), __int_as_float(dd), dv, c);
    float4 r1 = make_float4(rvec[(size_t)e * 3 + 0], rvec[(size_t)e * 3 + 1],
                            rvec[(size_t)e * 3 + 2], 0.0f);
    *(float4*)(rec + (size_t)pos * 8)     = r0;
    *(float4*)(rec + (size_t)pos * 8 + 4) = r1;
}

// ---------------------------------------------------------------------------
// Per-layer weight transpose+cast: We2t[l][n][k] bf16, Wvt[l][n(16 pad)][k] bf16
// ---------------------------------------------------------------------------
__global__ __launch_bounds__(256) void wprep_kernel(
    const float* __restrict__ We2, const float* __restrict__ Wv,
    unsigned short* __restrict__ We2t, unsigned short* __restrict__ Wvt) {
    int l = blockIdx.x, t = threadIdx.x;
    const float* W2 = We2 + (size_t)l * HID * HID;
    unsigned short* T2 = We2t + (size_t)l * HID * HID;
    for (int idx = t; idx < HID * HID; idx += 256) {
        int n = idx >> 6, k = idx & 63;
        T2[n * 64 + k] = f2bf(W2[k * HID + n]);
    }
    const float* Wvl = Wv + (size_t)l * HID * 6;
    unsigned short* Tv = Wvt + (size_t)l * 16 * 64;
    for (int idx = t; idx < 16 * 64; idx += 256) {
        int n = idx >> 6, k = idx & 63;
        Tv[idx] = (n < 6) ? f2bf(Wvl[k * 6 + n]) : (unsigned short)0;
    }
}

// ---------------------------------------------------------------------------
// Node-level hoist of edge GEMM1: Pa = s @ We1[0:128] + be1, Pb = s @ We1[128:256]
// ---------------------------------------------------------------------------
__global__ __launch_bounds__(256) void node_pre_kernel(
    const float* __restrict__ s, const float* __restrict__ W,
    const float* __restrict__ be1,
    float* __restrict__ Pa, float* __restrict__ Pb, int N)
{
    __shared__ float sl[64 * 129];
    int t = threadIdx.x;
    int n0 = blockIdx.x * 64;
    for (int idx = t; idx < 64 * (SDIM / 4); idx += 256) {
        int rn = idx >> 5;
        int c4 = (idx & 31) << 2;
        int n = n0 + rn;
        float4 val = make_float4(0.f, 0.f, 0.f, 0.f);
        if (n < N) val = *(const float4*)(s + (size_t)n * SDIM + c4);
        sl[rn * 129 + c4 + 0] = val.x;
        sl[rn * 129 + c4 + 1] = val.y;
        sl[rn * 129 + c4 + 2] = val.z;
        sl[rn * 129 + c4 + 3] = val.w;
    }
    __syncthreads();
    int r = t & 63;
    int j0 = __builtin_amdgcn_readfirstlane((t >> 6) << 4);
    float accA[16], accB[16];
#pragma unroll
    for (int i = 0; i < 16; ++i) { accA[i] = be1[j0 + i]; accB[i] = 0.f; }
    for (int k = 0; k < SDIM; ++k) {
        float sv = sl[r * 129 + k];
        const float* wa = W + k * HID + j0;
        const float* wb = W + (k + 128) * HID + j0;
#pragma unroll
        for (int i = 0; i < 16; ++i) accA[i] = fmaf(sv, wa[i], accA[i]);
#pragma unroll
        for (int i = 0; i < 16; ++i) accB[i] = fmaf(sv, wb[i], accB[i]);
    }
    int n = n0 + r;
    if (n < N) {
        float* pa = Pa + (size_t)n * HID + j0;
        float* pb = Pb + (size_t)n * HID + j0;
#pragma unroll
        for (int i = 0; i < 16; i += 4) {
            *(float4*)(pa + i) = make_float4(accA[i], accA[i+1], accA[i+2], accA[i+3]);
            *(float4*)(pb + i) = make_float4(accB[i], accB[i+1], accB[i+2], accB[i+3]);
        }
    }
}

// ---------------------------------------------------------------------------
// Fully fused edge kernel (dst-sorted, segmented reduction, boundary atomics):
//  ph1: h1 = silu(Pa[dst]+Pb[src]+d*wd)        -> bf16 A-frags in REGISTERS
//  ph2: h  = silu(h1@We2 + be2)*C  (MFMA)      -> hb fp32 in LDS (stride 68)
//  gates = h@Wv + bv               (MFMA)      -> gl
//  agg_s += segmented-sum(h)   [boundary atomics]
//  agg_v += segmented-sum(v[src]*g1 + r*g2)
// ---------------------------------------------------------------------------
__global__ __launch_bounds__(256) void edge_kernel(
    const float* __restrict__ rec,
    const float* __restrict__ Pa, const float* __restrict__ Pb,
    const float* __restrict__ wd,
    const unsigned short* __restrict__ We2t, const float* __restrict__ be2,
    const unsigned short* __restrict__ Wvt, const float* __restrict__ bv,
    const float* __restrict__ v,
    float* __restrict__ agg_s, float* __restrict__ agg_v, int E)
{
    __shared__ float hb[64 * 68];       // h fp32; stride 68: 2-way (free) banking
    __shared__ float gl[64 * 8];
    __shared__ int   m_src[64], m_dst[64];
    __shared__ float m_d[64], m_C[64];
    __shared__ float m_r[64 * 3];
    int t = threadIdx.x;
    int e0 = blockIdx.x * 64;
    if (t < 64) {
        int e = e0 + t;
        int ec = (e < E) ? e : (E - 1);
        float4 r0 = *(const float4*)(rec + (size_t)ec * 8);
        float4 r1 = *(const float4*)(rec + (size_t)ec * 8 + 4);
        m_src[t] = __float_as_int(r0.x);
        m_dst[t] = __float_as_int(r0.y);
        m_d[t]   = r0.z;
        m_C[t]   = (e < E) ? r0.w : 0.0f;   // C=0 for pad rows -> h=0
        m_r[t*3+0] = r1.x; m_r[t*3+1] = r1.y; m_r[t*3+2] = r1.z;
    }
    __syncthreads();

    int lane = t & 63;
    int w    = t >> 6;
    int lm = lane & 15, lq = lane >> 4;
    int m0 = w * 16;          // this wave's 16 edge rows
    int rm = m0 + lm;         // A row for this lane
    int ka = lq * 8;          // k-block 1
    int kb = 32 + lq * 8;     // k-block 2

    // ---- phase 1: h1 in MFMA A-layout, registers only ----
    bf16x8 afr0, afr1;
    {
        int dstr = m_dst[rm], srcr = m_src[rm];
        float dv = m_d[rm];
        const float* pa = Pa + (size_t)dstr * HID;
        const float* pb = Pb + (size_t)srcr * HID;
        f8 xa = load8(pa + ka), xb = load8(pb + ka), xw = load8(wd + ka);
        float h1a[8];
#pragma unroll
        for (int j = 0; j < 8; ++j) h1a[j] = silu_f(xa.v[j] + xb.v[j] + dv * xw.v[j]);
        afr0 = pack8(h1a);
        f8 ya = load8(pa + kb), yb = load8(pb + kb), yw = load8(wd + kb);
        float h1b[8];
#pragma unroll
        for (int j = 0; j < 8; ++j) h1b[j] = silu_f(ya.v[j] + yb.v[j] + dv * yw.v[j]);
        afr1 = pack8(h1b);
    }

    // ---- phase 2: h = silu(h1@We2+be2)*C via MFMA; B from global (L2-hot) ----
#pragma unroll
    for (int t4 = 0; t4 < 4; ++t4) {
        int col = t4 * 16 + lm;
        bf16x8 b0 = *(const bf16x8*)(We2t + (size_t)col * 64 + ka);
        bf16x8 b1 = *(const bf16x8*)(We2t + (size_t)col * 64 + kb);
        f32x4 a = {0.f, 0.f, 0.f, 0.f};
        a = __builtin_amdgcn_mfma_f32_16x16x32_bf16(afr0, b0, a, 0, 0, 0);
        a = __builtin_amdgcn_mfma_f32_16x16x32_bf16(afr1, b1, a, 0, 0, 0);
        float bias = be2[col];
#pragma unroll
        for (int g = 0; g < 4; ++g) {
            int er = m0 + lq * 4 + g;            // D: col=lane&15, row=quad*4+reg
            hb[er * 68 + col] = silu_f(a[g] + bias) * m_C[er];
        }
    }
    __syncthreads();   // hb ready for gates + agg_s

    // ---- gates = h @ Wv + bv via MFMA (B = Wv^T padded to 16 rows) ----
    {
        f8 g0 = load8(&hb[rm * 68 + ka]);
        f8 g1 = load8(&hb[rm * 68 + kb]);
        bf16x8 ga0 = pack8(g0.v), ga1 = pack8(g1.v);
        bf16x8 wv0 = *(const bf16x8*)(Wvt + (size_t)lm * 64 + ka);
        bf16x8 wv1 = *(const bf16x8*)(Wvt + (size_t)lm * 64 + kb);
        f32x4 ga = {0.f, 0.f, 0.f, 0.f};
        ga = __builtin_amdgcn_mfma_f32_16x16x32_bf16(ga0, wv0, ga, 0, 0, 0);
        ga = __builtin_amdgcn_mfma_f32_16x16x32_bf16(ga1, wv1, ga, 0, 0, 0);
        if (lm < 6) {
            float bias = bv[lm];
#pragma unroll
            for (int g = 0; g < 4; ++g) {
                int er = m0 + lq * 4 + g;
                gl[er * 8 + lm] = ga[g] + bias;
            }
        }
    }

    // ---- agg_s: segmented column-sum over dst runs (thread = col × 16-row seg) ----
    {
        int c = t & 63, seg = t >> 6;
        int r0 = seg * 16;
        float acc = 0.f;
        int cur = m_dst[r0];
#pragma unroll 4
        for (int r = r0; r < r0 + 16; ++r) {
            int dr = m_dst[r];
            if (dr != cur) {
                atomicAdd(&agg_s[(size_t)cur * HID + c], acc);
                acc = 0.f; cur = dr;
            }
            acc += hb[r * 68 + c];   // pad rows contribute 0 (C=0)
        }
        atomicAdd(&agg_s[(size_t)cur * HID + c], acc);
    }
    __syncthreads();   // gl ready

    // ---- agg_v: mv = v[src]*g1 + r*g2, segmented sum (thread = col9 × 4-row seg) ----
    if (t < 144) {
        int seg = t / 9;
        int c = t - seg * 9;
        int i = c / 3, j = c - i * 3;
        int r0 = seg * 4;
        float acc = 0.f;
        int cur = m_dst[r0];
        for (int r = r0; r < r0 + 4; ++r) {
            int dr = m_dst[r];
            if (dr != cur) {
                atomicAdd(&agg_v[(size_t)cur * 9 + c], acc);
                acc = 0.f; cur = dr;
            }
            if (e0 + r < E) {
                acc += v[(size_t)m_src[r] * 9 + c] * gl[r * 8 + j]
                     + m_r[r * 3 + i] * gl[r * 8 + 3 + j];
            }
        }
        atomicAdd(&agg_v[(size_t)cur * 9 + c], acc);
    }
}

// ---------------------------------------------------------------------------
// Node update: u = silu([s, agg_s] @ Wn1 + bn1); s += u @ Wn2 + bn2;
// v += agg_v / max(deg,1)  (deg from row_start)
// ---------------------------------------------------------------------------
__global__ __launch_bounds__(256) void node_upd_kernel(
    float* __restrict__ s, float* __restrict__ vout,
    const float* __restrict__ agg_s, const float* __restrict__ agg_v,
    const int* __restrict__ row_start,
    const float* __restrict__ Wn1, const float* __restrict__ bn1,
    const float* __restrict__ Wn2, const float* __restrict__ bn2,
    int N)
{
    __shared__ float xl[64 * 193];
    int t = threadIdx.x;
    int n0 = blockIdx.x * 64;
    for (int idx = t; idx < 64 * 32; idx += 256) {
        int rn = idx >> 5, c4 = (idx & 31) << 2;
        int n = n0 + rn;
        float4 val = make_float4(0.f, 0.f, 0.f, 0.f);
        if (n < N) val = *(const float4*)(s + (size_t)n * SDIM + c4);
        xl[rn*193 + c4 + 0] = val.x;
        xl[rn*193 + c4 + 1] = val.y;
        xl[rn*193 + c4 + 2] = val.z;
        xl[rn*193 + c4 + 3] = val.w;
    }
    for (int idx = t; idx < 64 * 16; idx += 256) {
        int rn = idx >> 4, c4 = (idx & 15) << 2;
        int n = n0 + rn;
        float4 val = make_float4(0.f, 0.f, 0.f, 0.f);
        if (n < N) val = *(const float4*)(agg_s + (size_t)n * HID + c4);
        xl[rn*193 + 128 + c4 + 0] = val.x;
        xl[rn*193 + 128 + c4 + 1] = val.y;
        xl[rn*193 + 128 + c4 + 2] = val.z;
        xl[rn*193 + 128 + c4 + 3] = val.w;
    }
    __syncthreads();
    int r = t & 63;
    int j0 = __builtin_amdgcn_readfirstlane((t >> 6) << 4);
    float acc[16];
#pragma unroll
    for (int i = 0; i < 16; ++i) acc[i] = bn1[j0 + i];
    for (int k = 0; k < SDIM + HID; ++k) {
        float xv = xl[r * 193 + k];
        const float* w = Wn1 + k * HID + j0;
#pragma unroll
        for (int i = 0; i < 16; ++i) acc[i] = fmaf(xv, w[i], acc[i]);
    }
    float u[16];
#pragma unroll
    for (int i = 0; i < 16; ++i) u[i] = silu_f(acc[i]);
    __syncthreads();
#pragma unroll
    for (int i = 0; i < 16; ++i) xl[r * 65 + j0 + i] = u[i];
    __syncthreads();

    int j2 = __builtin_amdgcn_readfirstlane((t >> 6) << 5);
    float acc2[32];
#pragma unroll
    for (int i = 0; i < 32; ++i) acc2[i] = bn2[j2 + i];
    for (int k = 0; k < HID; ++k) {
        float uv = xl[r * 65 + k];
        const float* w = Wn2 + k * SDIM + j2;
#pragma unroll
        for (int i = 0; i < 32; ++i) acc2[i] = fmaf(uv, w[i], acc2[i]);
    }
    int n = n0 + r;
    if (n < N) {
        float* sp = s + (size_t)n * SDIM + j2;
#pragma unroll
        for (int i = 0; i < 32; i += 4) {
            float4 so = *(const float4*)(sp + i);
            *(float4*)(sp + i) = make_float4(so.x + acc2[i], so.y + acc2[i+1],
                                             so.z + acc2[i+2], so.w + acc2[i+3]);
        }
    }
    for (int idx = t; idx < 64 * 9; idx += 256) {
        int rn = idx / 9, c = idx - rn * 9;
        int n2 = n0 + rn;
        if (n2 < N) {
            float dg = fmaxf((float)(row_start[n2 + 1] - row_start[n2]), 1.0f);
            vout[(size_t)n2 * 9 + c] += agg_v[(size_t)n2 * 9 + c] / dg;
        }
    }
}

extern "C" void kernel_launch(void* const* d_in, const int* in_sizes, int n_in,
                              void* d_out, int out_size, void* d_ws, size_t ws_size,
                              hipStream_t stream)
{
    const float* s_in  = (const float*)d_in[0];
    const float* v_in  = (const float*)d_in[1];
    const void*  ei    = d_in[2];
    const float* d_vec = (const float*)d_in[3];
    const float* r_vec = (const float*)d_in[4];
    const float* We1 = (const float*)d_in[6];
    const float* be1 = (const float*)d_in[7];
    const float* We2 = (const float*)d_in[8];
    const float* be2 = (const float*)d_in[9];
    const float* Wn1 = (const float*)d_in[10];
    const float* bn1 = (const float*)d_in[11];
    const float* Wn2 = (const float*)d_in[12];
    const float* bn2 = (const float*)d_in[13];
    const float* Wv  = (const float*)d_in[14];
    const float* bv  = (const float*)d_in[15];

    int N = in_sizes[0] / SDIM;
    int E = in_sizes[3];

    float* out_s = (float*)d_out;
    float* out_v = out_s + (size_t)N * SDIM;

    // ------ workspace layout (32B-aligned blocks) ------
    char* wp = (char*)d_ws;
    auto alloc = [&wp](size_t bytes) -> char* {
        char* p = wp;
        wp += (bytes + 31) & ~(size_t)31;
        return p;
    };
    float* rec       = (float*)alloc((size_t)E * 8 * 4);       // 32B records
    float* Pa        = (float*)alloc((size_t)N * HID * 4);
    float* Pb        = (float*)alloc((size_t)N * HID * 4);
    float* agg_s     = (float*)alloc((size_t)N * HID * 4);     // contiguous with agg_v
    float* agg_v     = (float*)alloc((size_t)N * 9 * 4);
    int*   deg_i     = (int*)alloc((size_t)N * 4);
    int*   cursor    = (int*)alloc((size_t)N * 4);
    int*   row_start = (int*)alloc((size_t)(N + 1) * 4);
    int*   flag      = (int*)alloc(16);
    int*   srcw      = (int*)alloc((size_t)E * 4);
    int*   dstw      = (int*)alloc((size_t)E * 4);
    unsigned short* We2t = (unsigned short*)alloc((size_t)DEPTH * HID * HID * 2);
    unsigned short* Wvt  = (unsigned short*)alloc((size_t)DEPTH * 16 * 64 * 2);

    hipMemcpyAsync(out_s, s_in, (size_t)N * SDIM * sizeof(float),
                   hipMemcpyDeviceToDevice, stream);
    hipMemcpyAsync(out_v, v_in, (size_t)N * 9 * sizeof(float),
                   hipMemcpyDeviceToDevice, stream);

    // ------ one-time prep: decode+deg, scan, scatter, weight transpose ------
    detect_idx_kernel<<<1, 1, 0, stream>>>(ei, N, flag);
    hipMemsetAsync(deg_i, 0, (size_t)N * sizeof(int), stream);
    hipMemsetAsync(cursor, 0, (size_t)N * sizeof(int), stream);
    decode_idx_kernel<<<(2 * E + 255) / 256, 256, 0, stream>>>(ei, E, N, flag,
                                                               srcw, dstw, deg_i);
    scan_kernel<<<1, 256, 0, stream>>>(deg_i, row_start, N);
    scatter_kernel<<<(E + 255) / 256, 256, 0, stream>>>(srcw, dstw, d_vec, r_vec,
                                                        row_start, cursor, rec, E);
    wprep_kernel<<<DEPTH, 256, 0, stream>>>(We2, Wv, We2t, Wvt);

    int nb_n = (N + 63) / 64;
    int nb_e = (E + 63) / 64;
    for (int l = 0; l < DEPTH; ++l) {
        const float* We1_l = We1 + (size_t)l * 257 * 64;
        const float* be1_l = be1 + (size_t)l * 64;
        const float* be2_l = be2 + (size_t)l * 64;
        const float* Wn1_l = Wn1 + (size_t)l * 192 * 64;
        const float* bn1_l = bn1 + (size_t)l * 64;
        const float* Wn2_l = Wn2 + (size_t)l * 64 * 128;
        const float* bn2_l = bn2 + (size_t)l * 128;
        const float* bv_l  = bv  + (size_t)l * 6;
        const unsigned short* We2t_l = We2t + (size_t)l * HID * HID;
        const unsigned short* Wvt_l  = Wvt  + (size_t)l * 16 * 64;

        hipMemsetAsync(agg_s, 0, (size_t)N * (HID + 9) * sizeof(float), stream);
        node_pre_kernel<<<nb_n, 256, 0, stream>>>(out_s, We1_l, be1_l, Pa, Pb, N);
        edge_kernel<<<nb_e, 256, 0, stream>>>(rec, Pa, Pb,
                                              We1_l + 256 * 64,
                                              We2t_l, be2_l, Wvt_l, bv_l,
                                              out_v, agg_s, agg_v, E);
        node_upd_kernel<<<nb_n, 256, 0, stream>>>(out_s, out_v, agg_s, agg_v,
                                                  row_start,
                                                  Wn1_l, bn1_l, Wn2_l, bn2_l, N);
    }
}

// Round 5
// 1078.921 us; speedup vs baseline: 12.1739x; 1.1719x over previous
//
#include <hip/hip_runtime.h>
#include <math.h>

#define SDIM 128
#define HID 64
#define DEPTH 4
#define CUTOFF_F 5.0f

typedef __attribute__((ext_vector_type(8))) short bf16x8;   // 8 bf16 = 4 VGPRs
typedef __attribute__((ext_vector_type(4))) float f32x4;

// fast silu: v_exp + v_rcp (saves ~7 insts vs precise fp32 divide)
__device__ __forceinline__ float silu_f(float x) {
    float e = __expf(-x);
    return x * __builtin_amdgcn_rcpf(1.0f + e);
}

__device__ __forceinline__ unsigned short f2bf(float x) {
    unsigned int u = __float_as_uint(x);
    unsigned int r = (u + 0x7fffu + ((u >> 16) & 1u)) >> 16;   // RNE
    return (unsigned short)r;
}

struct f8 { float v[8]; };
__device__ __forceinline__ f8 load8(const float* p) {
    f8 r;
    float4 a = *(const float4*)p;
    float4 b = *(const float4*)(p + 4);
    r.v[0]=a.x; r.v[1]=a.y; r.v[2]=a.z; r.v[3]=a.w;
    r.v[4]=b.x; r.v[5]=b.y; r.v[6]=b.z; r.v[7]=b.w;
    return r;
}
__device__ __forceinline__ bf16x8 pack8(const float* h) {
    bf16x8 o;
#pragma unroll
    for (int j = 0; j < 8; ++j) o[j] = (short)f2bf(h[j]);
    return o;
}

// ---------------------------------------------------------------------------
// Index decode + degree histogram. Harness may hand int64 or int32 indices.
// ---------------------------------------------------------------------------
__global__ void detect_idx_kernel(const void* ei, int N, int* flag) {
    const long long* p64 = (const long long*)ei;
    int ok64 = 1;
    for (int i = 0; i < 64; ++i) {
        long long v = p64[i];
        if (v < 0 || v >= (long long)N) { ok64 = 0; break; }
    }
    *flag = ok64;
}

__global__ void decode_idx_kernel(const void* ei, int E, int N, const int* flag,
                                  int* __restrict__ srcw, int* __restrict__ dstw,
                                  int* __restrict__ deg_i) {
    int i = blockIdx.x * blockDim.x + threadIdx.x;
    if (i >= 2 * E) return;
    int v;
    if (*flag) v = (int)((const long long*)ei)[i];
    else       v = ((const int*)ei)[i];
    v = min(max(v, 0), N - 1);
    if (i < E) {
        srcw[i] = v;
    } else {
        dstw[i - E] = v;
        atomicAdd(&deg_i[v], 1);
    }
}

// ---------------------------------------------------------------------------
// Single-block exclusive scan of deg_i -> row_start[0..N]
// ---------------------------------------------------------------------------
__global__ __launch_bounds__(256) void scan_kernel(const int* __restrict__ deg_i,
                                                   int* __restrict__ row_start, int N) {
    __shared__ int wsum[4];
    __shared__ int carry_s;
    int t = threadIdx.x;
    int lane = t & 63, w = t >> 6;
    if (t == 0) carry_s = 0;
    __syncthreads();
    for (int base = 0; base < N; base += 256) {
        int i = base + t;
        int v = (i < N) ? deg_i[i] : 0;
        int incl = v;
#pragma unroll
        for (int off = 1; off < 64; off <<= 1) {
            int x = __shfl_up(incl, off, 64);
            if (lane >= off) incl += x;
        }
        if (lane == 63) wsum[w] = incl;
        __syncthreads();
        int wpre = 0;
#pragma unroll
        for (int k = 0; k < 4; ++k) if (k < w) wpre += wsum[k];
        int total = wsum[0] + wsum[1] + wsum[2] + wsum[3];
        int carry = carry_s;
        if (i < N) row_start[i] = carry + wpre + incl - v;
        __syncthreads();
        if (t == 0) carry_s = carry + total;
        __syncthreads();
    }
    if (t == 0) row_start[N] = carry_s;
}

// ---------------------------------------------------------------------------
// Scatter: dst-sorted permutation; one packed 32B record per edge:
//   {src, dst, d, C, rx, ry, rz, pad}
// ---------------------------------------------------------------------------
__global__ void scatter_kernel(const int* __restrict__ srcw, const int* __restrict__ dstw,
                               const float* __restrict__ dvec, const float* __restrict__ rvec,
                               const int* __restrict__ row_start, int* __restrict__ cursor,
                               float* __restrict__ rec, int E) {
    int e = blockIdx.x * blockDim.x + threadIdx.x;
    if (e >= E) return;
    int dd = dstw[e];
    int ofs = atomicAdd(&cursor[dd], 1);
    int pos = row_start[dd] + ofs;
    float dv = dvec[e];
    float c = 0.5f * (cosf(3.14159265358979323846f * dv * (1.0f / CUTOFF_F)) + 1.0f);
    c = (dv < CUTOFF_F) ? c : 0.0f;
    float4 r0 = make_float4(__int_as_float(srcw[e]), __int_as_float(dd), dv, c);
    float4 r1 = make_float4(rvec[(size_t)e * 3 + 0], rvec[(size_t)e * 3 + 1],
                            rvec[(size_t)e * 3 + 2], 0.0f);
    *(float4*)(rec + (size_t)pos * 8)     = r0;
    *(float4*)(rec + (size_t)pos * 8 + 4) = r1;
}

// ---------------------------------------------------------------------------
// Per-layer weight transpose+cast to bf16 [n][k] layouts for MFMA B-operands:
//   We2t 64x64, Wvt 16x64, We1t 128x128 ([Pa|Pb] cols), Wn1t 64x192, Wn2t 128x64
// ---------------------------------------------------------------------------
__global__ __launch_bounds__(256) void wprep_kernel(
    const float* __restrict__ We1, const float* __restrict__ We2,
    const float* __restrict__ Wv,  const float* __restrict__ Wn1,
    const float* __restrict__ Wn2,
    unsigned short* __restrict__ We1t, unsigned short* __restrict__ We2t,
    unsigned short* __restrict__ Wvt,  unsigned short* __restrict__ Wn1t,
    unsigned short* __restrict__ Wn2t) {
    int l = blockIdx.x, t = threadIdx.x;
    const float* W2 = We2 + (size_t)l * HID * HID;
    unsigned short* T2 = We2t + (size_t)l * HID * HID;
    for (int idx = t; idx < HID * HID; idx += 256) {
        int n = idx >> 6, k = idx & 63;
        T2[n * 64 + k] = f2bf(W2[k * HID + n]);
    }
    const float* Wvl = Wv + (size_t)l * HID * 6;
    unsigned short* Tv = Wvt + (size_t)l * 16 * 64;
    for (int idx = t; idx < 16 * 64; idx += 256) {
        int n = idx >> 6, k = idx & 63;
        Tv[idx] = (n < 6) ? f2bf(Wvl[k * 6 + n]) : (unsigned short)0;
    }
    const float* W1 = We1 + (size_t)l * 257 * 64;
    unsigned short* T1 = We1t + (size_t)l * 128 * 128;
    for (int idx = t; idx < 128 * 128; idx += 256) {
        int n = idx >> 7, k = idx & 127;
        float w = (n < 64) ? W1[(size_t)k * 64 + n] : W1[(size_t)(k + 128) * 64 + (n - 64)];
        T1[n * 128 + k] = f2bf(w);
    }
    const float* Wn1l = Wn1 + (size_t)l * 192 * 64;
    unsigned short* Tn1 = Wn1t + (size_t)l * 64 * 192;
    for (int idx = t; idx < 64 * 192; idx += 256) {
        int n = idx / 192, k = idx - n * 192;
        Tn1[idx] = f2bf(Wn1l[(size_t)k * 64 + n]);
    }
    const float* Wn2l = Wn2 + (size_t)l * 64 * 128;
    unsigned short* Tn2 = Wn2t + (size_t)l * 128 * 64;
    for (int idx = t; idx < 128 * 64; idx += 256) {
        int n = idx >> 6, k = idx & 63;
        Tn2[idx] = f2bf(Wn2l[(size_t)k * 128 + n]);
    }
}

// ---------------------------------------------------------------------------
// node_pre (MFMA): [Pa|Pb] = s @ [We1a|We1b] (+be1 on Pa).  M=64,K=128,N=128.
// ---------------------------------------------------------------------------
__global__ __launch_bounds__(256) void node_pre_kernel(
    const float* __restrict__ s, const unsigned short* __restrict__ We1t,
    const float* __restrict__ be1,
    float* __restrict__ Pa, float* __restrict__ Pb, int N)
{
    __shared__ unsigned short sa[64 * 136];   // bf16, stride 136 (=68 floats)
    int t = threadIdx.x;
    int n0 = blockIdx.x * 64;
    for (int idx = t; idx < 64 * 32; idx += 256) {
        int rn = idx >> 5, c4 = (idx & 31) << 2;
        int n = n0 + rn;
        float4 val = make_float4(0.f, 0.f, 0.f, 0.f);
        if (n < N) val = *(const float4*)(s + (size_t)n * SDIM + c4);
        unsigned int p0 = (unsigned int)f2bf(val.x) | ((unsigned int)f2bf(val.y) << 16);
        unsigned int p1 = (unsigned int)f2bf(val.z) | ((unsigned int)f2bf(val.w) << 16);
        *(uint2*)(sa + rn * 136 + c4) = make_uint2(p0, p1);
    }
    __syncthreads();
    int lane = t & 63, w = t >> 6;
    int lm = lane & 15, lq = lane >> 4;
    int m0 = w * 16, rm = m0 + lm;

    bf16x8 af[4];
#pragma unroll
    for (int kc = 0; kc < 4; ++kc)
        af[kc] = *(const bf16x8*)(sa + rm * 136 + kc * 32 + lq * 8);

#pragma unroll
    for (int ct = 0; ct < 8; ++ct) {
        int col = ct * 16 + lm;   // 0..127 over [Pa|Pb]
        f32x4 acc = {0.f, 0.f, 0.f, 0.f};
#pragma unroll
        for (int kc = 0; kc < 4; ++kc) {
            bf16x8 b = *(const bf16x8*)(We1t + (size_t)col * 128 + kc * 32 + lq * 8);
            acc = __builtin_amdgcn_mfma_f32_16x16x32_bf16(af[kc], b, acc, 0, 0, 0);
        }
        float bias = (ct < 4) ? be1[col] : 0.0f;
#pragma unroll
        for (int g = 0; g < 4; ++g) {
            int n = n0 + m0 + lq * 4 + g;
            if (n < N) {
                if (ct < 4) Pa[(size_t)n * HID + col]        = acc[g] + bias;
                else        Pb[(size_t)n * HID + (col - 64)] = acc[g];
            }
        }
    }
}

// ---------------------------------------------------------------------------
// Fully fused edge kernel (dst-sorted, segmented reduction, boundary atomics)
// ---------------------------------------------------------------------------
__global__ __launch_bounds__(256) void edge_kernel(
    const float* __restrict__ rec,
    const float* __restrict__ Pa, const float* __restrict__ Pb,
    const float* __restrict__ wd,
    const unsigned short* __restrict__ We2t, const float* __restrict__ be2,
    const unsigned short* __restrict__ Wvt, const float* __restrict__ bv,
    const float* __restrict__ v,
    float* __restrict__ agg_s, float* __restrict__ agg_v, int E)
{
    __shared__ float hb[64 * 68];       // h fp32; stride 68
    __shared__ float gl[64 * 8];
    __shared__ int   m_src[64], m_dst[64];
    __shared__ float m_d[64], m_C[64];
    __shared__ float m_r[64 * 3];
    int t = threadIdx.x;
    int e0 = blockIdx.x * 64;
    if (t < 64) {
        int e = e0 + t;
        int ec = (e < E) ? e : (E - 1);
        float4 r0 = *(const float4*)(rec + (size_t)ec * 8);
        float4 r1 = *(const float4*)(rec + (size_t)ec * 8 + 4);
        m_src[t] = __float_as_int(r0.x);
        m_dst[t] = __float_as_int(r0.y);
        m_d[t]   = r0.z;
        m_C[t]   = (e < E) ? r0.w : 0.0f;   // C=0 for pad rows -> h=0
        m_r[t*3+0] = r1.x; m_r[t*3+1] = r1.y; m_r[t*3+2] = r1.z;
    }
    __syncthreads();

    int lane = t & 63;
    int w    = t >> 6;
    int lm = lane & 15, lq = lane >> 4;
    int m0 = w * 16;
    int rm = m0 + lm;
    int ka = lq * 8;
    int kb = 32 + lq * 8;

    // ---- phase 1: h1 in MFMA A-layout, registers only ----
    bf16x8 afr0, afr1;
    {
        int dstr = m_dst[rm], srcr = m_src[rm];
        float dv = m_d[rm];
        const float* pa = Pa + (size_t)dstr * HID;
        const float* pb = Pb + (size_t)srcr * HID;
        f8 xa = load8(pa + ka), xb = load8(pb + ka), xw = load8(wd + ka);
        float h1a[8];
#pragma unroll
        for (int j = 0; j < 8; ++j) h1a[j] = silu_f(xa.v[j] + xb.v[j] + dv * xw.v[j]);
        afr0 = pack8(h1a);
        f8 ya = load8(pa + kb), yb = load8(pb + kb), yw = load8(wd + kb);
        float h1b[8];
#pragma unroll
        for (int j = 0; j < 8; ++j) h1b[j] = silu_f(ya.v[j] + yb.v[j] + dv * yw.v[j]);
        afr1 = pack8(h1b);
    }

    // ---- phase 2: h = silu(h1@We2+be2)*C via MFMA ----
#pragma unroll
    for (int t4 = 0; t4 < 4; ++t4) {
        int col = t4 * 16 + lm;
        bf16x8 b0 = *(const bf16x8*)(We2t + (size_t)col * 64 + ka);
        bf16x8 b1 = *(const bf16x8*)(We2t + (size_t)col * 64 + kb);
        f32x4 a = {0.f, 0.f, 0.f, 0.f};
        a = __builtin_amdgcn_mfma_f32_16x16x32_bf16(afr0, b0, a, 0, 0, 0);
        a = __builtin_amdgcn_mfma_f32_16x16x32_bf16(afr1, b1, a, 0, 0, 0);
        float bias = be2[col];
#pragma unroll
        for (int g = 0; g < 4; ++g) {
            int er = m0 + lq * 4 + g;
            hb[er * 68 + col] = silu_f(a[g] + bias) * m_C[er];
        }
    }
    __syncthreads();

    // ---- gates = h @ Wv + bv via MFMA ----
    {
        f8 g0 = load8(&hb[rm * 68 + ka]);
        f8 g1 = load8(&hb[rm * 68 + kb]);
        bf16x8 ga0 = pack8(g0.v), ga1 = pack8(g1.v);
        bf16x8 wv0 = *(const bf16x8*)(Wvt + (size_t)lm * 64 + ka);
        bf16x8 wv1 = *(const bf16x8*)(Wvt + (size_t)lm * 64 + kb);
        f32x4 ga = {0.f, 0.f, 0.f, 0.f};
        ga = __builtin_amdgcn_mfma_f32_16x16x32_bf16(ga0, wv0, ga, 0, 0, 0);
        ga = __builtin_amdgcn_mfma_f32_16x16x32_bf16(ga1, wv1, ga, 0, 0, 0);
        if (lm < 6) {
            float bias = bv[lm];
#pragma unroll
            for (int g = 0; g < 4; ++g) {
                int er = m0 + lq * 4 + g;
                gl[er * 8 + lm] = ga[g] + bias;
            }
        }
    }

    // ---- agg_s: segmented column-sum over dst runs ----
    {
        int c = t & 63, seg = t >> 6;
        int r0 = seg * 16;
        float acc = 0.f;
        int cur = m_dst[r0];
#pragma unroll 4
        for (int r = r0; r < r0 + 16; ++r) {
            int dr = m_dst[r];
            if (dr != cur) {
                atomicAdd(&agg_s[(size_t)cur * HID + c], acc);
                acc = 0.f; cur = dr;
            }
            acc += hb[r * 68 + c];
        }
        atomicAdd(&agg_s[(size_t)cur * HID + c], acc);
    }
    __syncthreads();

    // ---- agg_v: mv = v[src]*g1 + r*g2, segmented sum ----
    if (t < 144) {
        int seg = t / 9;
        int c = t - seg * 9;
        int i = c / 3, j = c - i * 3;
        int r0 = seg * 4;
        float acc = 0.f;
        int cur = m_dst[r0];
        for (int r = r0; r < r0 + 4; ++r) {
            int dr = m_dst[r];
            if (dr != cur) {
                atomicAdd(&agg_v[(size_t)cur * 9 + c], acc);
                acc = 0.f; cur = dr;
            }
            if (e0 + r < E) {
                acc += v[(size_t)m_src[r] * 9 + c] * gl[r * 8 + j]
                     + m_r[r * 3 + i] * gl[r * 8 + 3 + j];
            }
        }
        atomicAdd(&agg_v[(size_t)cur * 9 + c], acc);
    }
}

// ---------------------------------------------------------------------------
// node_upd (MFMA): u = silu([s,agg_s]@Wn1+bn1); s += u@Wn2+bn2;
// v += agg_v/max(deg,1).  GEMM1: M=64,K=192,N=64. GEMM2: M=64,K=64,N=128.
// ---------------------------------------------------------------------------
__global__ __launch_bounds__(256) void node_upd_kernel(
    float* __restrict__ s, float* __restrict__ vout,
    const float* __restrict__ agg_s, const float* __restrict__ agg_v,
    const int* __restrict__ row_start,
    const unsigned short* __restrict__ Wn1t, const float* __restrict__ bn1,
    const unsigned short* __restrict__ Wn2t, const float* __restrict__ bn2,
    int N)
{
    __shared__ unsigned short xa[64 * 200];  // [s(128)|agg_s(64)] bf16, stride 200
    __shared__ unsigned short ub[64 * 72];   // u bf16, stride 72
    int t = threadIdx.x;
    int n0 = blockIdx.x * 64;
    for (int idx = t; idx < 64 * 32; idx += 256) {
        int rn = idx >> 5, c4 = (idx & 31) << 2;
        int n = n0 + rn;
        float4 val = make_float4(0.f, 0.f, 0.f, 0.f);
        if (n < N) val = *(const float4*)(s + (size_t)n * SDIM + c4);
        unsigned int p0 = (unsigned int)f2bf(val.x) | ((unsigned int)f2bf(val.y) << 16);
        unsigned int p1 = (unsigned int)f2bf(val.z) | ((unsigned int)f2bf(val.w) << 16);
        *(uint2*)(xa + rn * 200 + c4) = make_uint2(p0, p1);
    }
    for (int idx = t; idx < 64 * 16; idx += 256) {
        int rn = idx >> 4, c4 = (idx & 15) << 2;
        int n = n0 + rn;
        float4 val = make_float4(0.f, 0.f, 0.f, 0.f);
        if (n < N) val = *(const float4*)(agg_s + (size_t)n * HID + c4);
        unsigned int p0 = (unsigned int)f2bf(val.x) | ((unsigned int)f2bf(val.y) << 16);
        unsigned int p1 = (unsigned int)f2bf(val.z) | ((unsigned int)f2bf(val.w) << 16);
        *(uint2*)(xa + rn * 200 + 128 + c4) = make_uint2(p0, p1);
    }
    __syncthreads();

    int lane = t & 63, w = t >> 6;
    int lm = lane & 15, lq = lane >> 4;
    int m0 = w * 16, rm = m0 + lm;

    // ---- GEMM1: u = silu(x @ Wn1 + bn1) ----
    bf16x8 af[6];
#pragma unroll
    for (int kc = 0; kc < 6; ++kc)
        af[kc] = *(const bf16x8*)(xa + rm * 200 + kc * 32 + lq * 8);

#pragma unroll
    for (int ct = 0; ct < 4; ++ct) {
        int col = ct * 16 + lm;
        f32x4 acc = {0.f, 0.f, 0.f, 0.f};
#pragma unroll
        for (int kc = 0; kc < 6; ++kc) {
            bf16x8 b = *(const bf16x8*)(Wn1t + (size_t)col * 192 + kc * 32 + lq * 8);
            acc = __builtin_amdgcn_mfma_f32_16x16x32_bf16(af[kc], b, acc, 0, 0, 0);
        }
        float bias = bn1[col];
#pragma unroll
        for (int g = 0; g < 4; ++g) {
            int er = m0 + lq * 4 + g;
            ub[er * 72 + col] = f2bf(silu_f(acc[g] + bias));
        }
    }
    __syncthreads();

    // ---- GEMM2: s += u @ Wn2 + bn2 ----
    bf16x8 uf[2];
#pragma unroll
    for (int kc = 0; kc < 2; ++kc)
        uf[kc] = *(const bf16x8*)(ub + rm * 72 + kc * 32 + lq * 8);

#pragma unroll
    for (int ct = 0; ct < 8; ++ct) {
        int col = ct * 16 + lm;
        f32x4 acc = {0.f, 0.f, 0.f, 0.f};
#pragma unroll
        for (int kc = 0; kc < 2; ++kc) {
            bf16x8 b = *(const bf16x8*)(Wn2t + (size_t)col * 64 + kc * 32 + lq * 8);
            acc = __builtin_amdgcn_mfma_f32_16x16x32_bf16(uf[kc], b, acc, 0, 0, 0);
        }
        float bias = bn2[col];
#pragma unroll
        for (int g = 0; g < 4; ++g) {
            int n = n0 + m0 + lq * 4 + g;
            if (n < N) {
                float* sp = s + (size_t)n * SDIM + col;
                *sp += acc[g] + bias;
            }
        }
    }

    // ---- v += agg_v / max(deg,1) ----
    for (int idx = t; idx < 64 * 9; idx += 256) {
        int rn = idx / 9, c = idx - rn * 9;
        int n2 = n0 + rn;
        if (n2 < N) {
            float dg = fmaxf((float)(row_start[n2 + 1] - row_start[n2]), 1.0f);
            vout[(size_t)n2 * 9 + c] += agg_v[(size_t)n2 * 9 + c] / dg;
        }
    }
}

extern "C" void kernel_launch(void* const* d_in, const int* in_sizes, int n_in,
                              void* d_out, int out_size, void* d_ws, size_t ws_size,
                              hipStream_t stream)
{
    const float* s_in  = (const float*)d_in[0];
    const float* v_in  = (const float*)d_in[1];
    const void*  ei    = d_in[2];
    const float* d_vec = (const float*)d_in[3];
    const float* r_vec = (const float*)d_in[4];
    const float* We1 = (const float*)d_in[6];
    const float* be1 = (const float*)d_in[7];
    const float* We2 = (const float*)d_in[8];
    const float* be2 = (const float*)d_in[9];
    const float* Wn1 = (const float*)d_in[10];
    const float* bn1 = (const float*)d_in[11];
    const float* Wn2 = (const float*)d_in[12];
    const float* bn2 = (const float*)d_in[13];
    const float* Wv  = (const float*)d_in[14];
    const float* bv  = (const float*)d_in[15];

    int N = in_sizes[0] / SDIM;
    int E = in_sizes[3];

    float* out_s = (float*)d_out;
    float* out_v = out_s + (size_t)N * SDIM;

    // ------ workspace layout (32B-aligned blocks) ------
    char* wp = (char*)d_ws;
    auto alloc = [&wp](size_t bytes) -> char* {
        char* p = wp;
        wp += (bytes + 31) & ~(size_t)31;
        return p;
    };
    float* rec       = (float*)alloc((size_t)E * 8 * 4);
    float* Pa        = (float*)alloc((size_t)N * HID * 4);
    float* Pb        = (float*)alloc((size_t)N * HID * 4);
    float* agg_s     = (float*)alloc((size_t)N * HID * 4);   // contiguous with agg_v
    float* agg_v     = (float*)alloc((size_t)N * 9 * 4);
    int*   deg_i     = (int*)alloc((size_t)N * 4);
    int*   cursor    = (int*)alloc((size_t)N * 4);
    int*   row_start = (int*)alloc((size_t)(N + 1) * 4);
    int*   flag      = (int*)alloc(16);
    int*   srcw      = (int*)alloc((size_t)E * 4);
    int*   dstw      = (int*)alloc((size_t)E * 4);
    unsigned short* We2t = (unsigned short*)alloc((size_t)DEPTH * HID * HID * 2);
    unsigned short* Wvt  = (unsigned short*)alloc((size_t)DEPTH * 16 * 64 * 2);
    unsigned short* We1t = (unsigned short*)alloc((size_t)DEPTH * 128 * 128 * 2);
    unsigned short* Wn1t = (unsigned short*)alloc((size_t)DEPTH * 64 * 192 * 2);
    unsigned short* Wn2t = (unsigned short*)alloc((size_t)DEPTH * 128 * 64 * 2);

    hipMemcpyAsync(out_s, s_in, (size_t)N * SDIM * sizeof(float),
                   hipMemcpyDeviceToDevice, stream);
    hipMemcpyAsync(out_v, v_in, (size_t)N * 9 * sizeof(float),
                   hipMemcpyDeviceToDevice, stream);

    // ------ one-time prep ------
    detect_idx_kernel<<<1, 1, 0, stream>>>(ei, N, flag);
    hipMemsetAsync(deg_i, 0, (size_t)N * sizeof(int), stream);
    hipMemsetAsync(cursor, 0, (size_t)N * sizeof(int), stream);
    decode_idx_kernel<<<(2 * E + 255) / 256, 256, 0, stream>>>(ei, E, N, flag,
                                                               srcw, dstw, deg_i);
    scan_kernel<<<1, 256, 0, stream>>>(deg_i, row_start, N);
    scatter_kernel<<<(E + 255) / 256, 256, 0, stream>>>(srcw, dstw, d_vec, r_vec,
                                                        row_start, cursor, rec, E);
    wprep_kernel<<<DEPTH, 256, 0, stream>>>(We1, We2, Wv, Wn1, Wn2,
                                            We1t, We2t, Wvt, Wn1t, Wn2t);

    int nb_n = (N + 63) / 64;
    int nb_e = (E + 63) / 64;
    for (int l = 0; l < DEPTH; ++l) {
        const float* We1_l = We1 + (size_t)l * 257 * 64;
        const float* be1_l = be1 + (size_t)l * 64;
        const float* be2_l = be2 + (size_t)l * 64;
        const float* bn1_l = bn1 + (size_t)l * 64;
        const float* bn2_l = bn2 + (size_t)l * 128;
        const float* bv_l  = bv  + (size_t)l * 6;
        const unsigned short* We1t_l = We1t + (size_t)l * 128 * 128;
        const unsigned short* We2t_l = We2t + (size_t)l * HID * HID;
        const unsigned short* Wvt_l  = Wvt  + (size_t)l * 16 * 64;
        const unsigned short* Wn1t_l = Wn1t + (size_t)l * 64 * 192;
        const unsigned short* Wn2t_l = Wn2t + (size_t)l * 128 * 64;

        hipMemsetAsync(agg_s, 0, (size_t)N * (HID + 9) * sizeof(float), stream);
        node_pre_kernel<<<nb_n, 256, 0, stream>>>(out_s, We1t_l, be1_l, Pa, Pb, N);
        edge_kernel<<<nb_e, 256, 0, stream>>>(rec, Pa, Pb,
                                              We1_l + 256 * 64,
                                              We2t_l, be2_l, Wvt_l, bv_l,
                                              out_v, agg_s, agg_v, E);
        node_upd_kernel<<<nb_n, 256, 0, stream>>>(out_s, out_v, agg_s, agg_v,
                                                  row_start,
                                                  Wn1t_l, bn1_l, Wn2t_l, bn2_l, N);
    }
}

// Round 6
// 900.922 us; speedup vs baseline: 14.5791x; 1.1976x over previous
//
#include <hip/hip_runtime.h>
#include <math.h>

#define SDIM 128
#define HID 64
#define DEPTH 4
#define CUTOFF_F 5.0f
#define CHUNK 4096

typedef __attribute__((ext_vector_type(8))) short bf16x8;   // 8 bf16 = 4 VGPRs
typedef __attribute__((ext_vector_type(4))) float f32x4;

// fast silu: v_exp + v_rcp
__device__ __forceinline__ float silu_f(float x) {
    float e = __expf(-x);
    return x * __builtin_amdgcn_rcpf(1.0f + e);
}

__device__ __forceinline__ unsigned short f2bf(float x) {
    unsigned int u = __float_as_uint(x);
    unsigned int r = (u + 0x7fffu + ((u >> 16) & 1u)) >> 16;   // RNE
    return (unsigned short)r;
}

struct f8 { float v[8]; };
__device__ __forceinline__ f8 load8(const float* p) {
    f8 r;
    float4 a = *(const float4*)p;
    float4 b = *(const float4*)(p + 4);
    r.v[0]=a.x; r.v[1]=a.y; r.v[2]=a.z; r.v[3]=a.w;
    r.v[4]=b.x; r.v[5]=b.y; r.v[6]=b.z; r.v[7]=b.w;
    return r;
}
__device__ __forceinline__ bf16x8 pack8(const float* h) {
    bf16x8 o;
#pragma unroll
    for (int j = 0; j < 8; ++j) o[j] = (short)f2bf(h[j]);
    return o;
}

// ---------------------------------------------------------------------------
// Index decode + degree histogram.
// ---------------------------------------------------------------------------
__global__ void detect_idx_kernel(const void* ei, int N, int* flag) {
    const long long* p64 = (const long long*)ei;
    int ok64 = 1;
    for (int i = 0; i < 64; ++i) {
        long long v = p64[i];
        if (v < 0 || v >= (long long)N) { ok64 = 0; break; }
    }
    *flag = ok64;
}

__global__ void decode_idx_kernel(const void* ei, int E, int N, const int* flag,
                                  int* __restrict__ srcw, int* __restrict__ dstw,
                                  int* __restrict__ deg_i) {
    int i = blockIdx.x * blockDim.x + threadIdx.x;
    if (i >= 2 * E) return;
    int v;
    if (*flag) v = (int)((const long long*)ei)[i];
    else       v = ((const int*)ei)[i];
    v = min(max(v, 0), N - 1);
    if (i < E) {
        srcw[i] = v;
    } else {
        dstw[i - E] = v;
        atomicAdd(&deg_i[v], 1);
    }
}

// ---------------------------------------------------------------------------
// 3-phase parallel exclusive scan: deg_i -> row_start[0..N]
// ---------------------------------------------------------------------------
__global__ __launch_bounds__(256) void scan1_kernel(const int* __restrict__ deg_i,
                                                    int* __restrict__ part, int N) {
    __shared__ int wsum[4];
    int b = blockIdx.x, t = threadIdx.x;
    int base = b * CHUNK;
    int sum = 0;
    for (int i = t; i < CHUNK; i += 256) {
        int idx = base + i;
        sum += (idx < N) ? deg_i[idx] : 0;
    }
#pragma unroll
    for (int off = 32; off; off >>= 1) sum += __shfl_down(sum, off, 64);
    if ((t & 63) == 0) wsum[t >> 6] = sum;
    __syncthreads();
    if (t == 0) part[b] = wsum[0] + wsum[1] + wsum[2] + wsum[3];
}

__global__ void scan2_kernel(int* __restrict__ part, int* __restrict__ row_start,
                             int B1, int N) {
    int t = threadIdx.x;   // 64 threads
    int v = (t < B1) ? part[t] : 0;
    int incl = v;
#pragma unroll
    for (int off = 1; off < 64; off <<= 1) {
        int x = __shfl_up(incl, off, 64);
        if (t >= off) incl += x;
    }
    if (t < B1) part[t] = incl - v;      // exclusive
    if (t == 63) row_start[N] = incl;    // grand total
}

__global__ __launch_bounds__(256) void scan3_kernel(const int* __restrict__ deg_i,
                                                    const int* __restrict__ part,
                                                    int* __restrict__ row_start, int N) {
    __shared__ int wsum[4];
    __shared__ int carry_s;
    int b = blockIdx.x, t = threadIdx.x;
    int lane = t & 63, w = t >> 6;
    if (t == 0) carry_s = part[b];
    __syncthreads();
    int base0 = b * CHUNK;
    for (int base = base0; base < base0 + CHUNK; base += 256) {
        int i = base + t;
        int v = (i < N) ? deg_i[i] : 0;
        int incl = v;
#pragma unroll
        for (int off = 1; off < 64; off <<= 1) {
            int x = __shfl_up(incl, off, 64);
            if (lane >= off) incl += x;
        }
        if (lane == 63) wsum[w] = incl;
        __syncthreads();
        int wpre = 0;
#pragma unroll
        for (int k = 0; k < 4; ++k) if (k < w) wpre += wsum[k];
        int total = wsum[0] + wsum[1] + wsum[2] + wsum[3];
        int carry = carry_s;
        if (i < N) row_start[i] = carry + wpre + incl - v;
        __syncthreads();
        if (t == 0) carry_s = carry + total;
        __syncthreads();
    }
}

// ---------------------------------------------------------------------------
// Scatter: dst-sorted permutation; one packed 32B record per edge.
// ---------------------------------------------------------------------------
__global__ void scatter_kernel(const int* __restrict__ srcw, const int* __restrict__ dstw,
                               const float* __restrict__ dvec, const float* __restrict__ rvec,
                               const int* __restrict__ row_start, int* __restrict__ cursor,
                               float* __restrict__ rec, int E) {
    int e = blockIdx.x * blockDim.x + threadIdx.x;
    if (e >= E) return;
    int dd = dstw[e];
    int ofs = atomicAdd(&cursor[dd], 1);
    int pos = row_start[dd] + ofs;
    float dv = dvec[e];
    float c = 0.5f * (cosf(3.14159265358979323846f * dv * (1.0f / CUTOFF_F)) + 1.0f);
    c = (dv < CUTOFF_F) ? c : 0.0f;
    float4 r0 = make_float4(__int_as_float(srcw[e]), __int_as_float(dd), dv, c);
    float4 r1 = make_float4(rvec[(size_t)e * 3 + 0], rvec[(size_t)e * 3 + 1],
                            rvec[(size_t)e * 3 + 2], 0.0f);
    *(float4*)(rec + (size_t)pos * 8)     = r0;
    *(float4*)(rec + (size_t)pos * 8 + 4) = r1;
}

// ---------------------------------------------------------------------------
// Weight transpose+cast to bf16 [n][k] for MFMA B-operands.
// ---------------------------------------------------------------------------
__global__ __launch_bounds__(256) void wprep_kernel(
    const float* __restrict__ We1, const float* __restrict__ We2,
    const float* __restrict__ Wv,  const float* __restrict__ Wn1,
    const float* __restrict__ Wn2,
    unsigned short* __restrict__ We1t, unsigned short* __restrict__ We2t,
    unsigned short* __restrict__ Wvt,  unsigned short* __restrict__ Wn1t,
    unsigned short* __restrict__ Wn2t) {
    int l = blockIdx.x, t = threadIdx.x;
    const float* W2 = We2 + (size_t)l * HID * HID;
    unsigned short* T2 = We2t + (size_t)l * HID * HID;
    for (int idx = t; idx < HID * HID; idx += 256) {
        int n = idx >> 6, k = idx & 63;
        T2[n * 64 + k] = f2bf(W2[k * HID + n]);
    }
    const float* Wvl = Wv + (size_t)l * HID * 6;
    unsigned short* Tv = Wvt + (size_t)l * 16 * 64;
    for (int idx = t; idx < 16 * 64; idx += 256) {
        int n = idx >> 6, k = idx & 63;
        Tv[idx] = (n < 6) ? f2bf(Wvl[k * 6 + n]) : (unsigned short)0;
    }
    const float* W1 = We1 + (size_t)l * 257 * 64;
    unsigned short* T1 = We1t + (size_t)l * 128 * 128;
    for (int idx = t; idx < 128 * 128; idx += 256) {
        int n = idx >> 7, k = idx & 127;
        float w = (n < 64) ? W1[(size_t)k * 64 + n] : W1[(size_t)(k + 128) * 64 + (n - 64)];
        T1[n * 128 + k] = f2bf(w);
    }
    const float* Wn1l = Wn1 + (size_t)l * 192 * 64;
    unsigned short* Tn1 = Wn1t + (size_t)l * 64 * 192;
    for (int idx = t; idx < 64 * 192; idx += 256) {
        int n = idx / 192, k = idx - n * 192;
        Tn1[idx] = f2bf(Wn1l[(size_t)k * 64 + n]);
    }
    const float* Wn2l = Wn2 + (size_t)l * 64 * 128;
    unsigned short* Tn2 = Wn2t + (size_t)l * 128 * 64;
    for (int idx = t; idx < 128 * 64; idx += 256) {
        int n = idx >> 6, k = idx & 63;
        Tn2[idx] = f2bf(Wn2l[(size_t)k * 128 + n]);
    }
}

// ---------------------------------------------------------------------------
// node_pre (layer 0 only): [Pa|Pb] = s @ [We1a|We1b] (+be1 on Pa)
// ---------------------------------------------------------------------------
__global__ __launch_bounds__(256) void node_pre_kernel(
    const float* __restrict__ s, const unsigned short* __restrict__ We1t,
    const float* __restrict__ be1,
    float* __restrict__ Pa, float* __restrict__ Pb, int N)
{
    __shared__ unsigned short sa[64 * 136];
    int t = threadIdx.x;
    int n0 = blockIdx.x * 64;
    for (int idx = t; idx < 64 * 32; idx += 256) {
        int rn = idx >> 5, c4 = (idx & 31) << 2;
        int n = n0 + rn;
        float4 val = make_float4(0.f, 0.f, 0.f, 0.f);
        if (n < N) val = *(const float4*)(s + (size_t)n * SDIM + c4);
        unsigned int p0 = (unsigned int)f2bf(val.x) | ((unsigned int)f2bf(val.y) << 16);
        unsigned int p1 = (unsigned int)f2bf(val.z) | ((unsigned int)f2bf(val.w) << 16);
        *(uint2*)(sa + rn * 136 + c4) = make_uint2(p0, p1);
    }
    __syncthreads();
    int lane = t & 63, w = t >> 6;
    int lm = lane & 15, lq = lane >> 4;
    int m0 = w * 16, rm = m0 + lm;

    bf16x8 af[4];
#pragma unroll
    for (int kc = 0; kc < 4; ++kc)
        af[kc] = *(const bf16x8*)(sa + rm * 136 + kc * 32 + lq * 8);

#pragma unroll
    for (int ct = 0; ct < 8; ++ct) {
        int col = ct * 16 + lm;
        f32x4 acc = {0.f, 0.f, 0.f, 0.f};
#pragma unroll
        for (int kc = 0; kc < 4; ++kc) {
            bf16x8 b = *(const bf16x8*)(We1t + (size_t)col * 128 + kc * 32 + lq * 8);
            acc = __builtin_amdgcn_mfma_f32_16x16x32_bf16(af[kc], b, acc, 0, 0, 0);
        }
        float bias = (ct < 4) ? be1[col] : 0.0f;
#pragma unroll
        for (int g = 0; g < 4; ++g) {
            int n = n0 + m0 + lq * 4 + g;
            if (n < N) {
                if (ct < 4) Pa[(size_t)n * HID + col]        = acc[g] + bias;
                else        Pb[(size_t)n * HID + (col - 64)] = acc[g];
            }
        }
    }
}

// ---------------------------------------------------------------------------
// Fused edge kernel (dst-sorted, segmented reduction, boundary atomics).
// v[src] prefetched into registers right after the index barrier.
// ---------------------------------------------------------------------------
__global__ __launch_bounds__(256) void edge_kernel(
    const float* __restrict__ rec,
    const float* __restrict__ Pa, const float* __restrict__ Pb,
    const float* __restrict__ wd,
    const unsigned short* __restrict__ We2t, const float* __restrict__ be2,
    const unsigned short* __restrict__ Wvt, const float* __restrict__ bv,
    const float* __restrict__ v,
    float* __restrict__ agg_s, float* __restrict__ agg_v, int E)
{
    __shared__ float hb[64 * 68];
    __shared__ float gl[64 * 8];
    __shared__ int   m_src[64], m_dst[64];
    __shared__ float m_d[64], m_C[64];
    __shared__ float m_r[64 * 3];
    int t = threadIdx.x;
    int e0 = blockIdx.x * 64;
    if (t < 64) {
        int e = e0 + t;
        int ec = (e < E) ? e : (E - 1);
        float4 r0 = *(const float4*)(rec + (size_t)ec * 8);
        float4 r1 = *(const float4*)(rec + (size_t)ec * 8 + 4);
        m_src[t] = __float_as_int(r0.x);
        m_dst[t] = __float_as_int(r0.y);
        m_d[t]   = r0.z;
        m_C[t]   = (e < E) ? r0.w : 0.0f;
        m_r[t*3+0] = r1.x; m_r[t*3+1] = r1.y; m_r[t*3+2] = r1.z;
    }
    __syncthreads();

    int lane = t & 63;
    int w    = t >> 6;
    int lm = lane & 15, lq = lane >> 4;
    int m0 = w * 16;
    int rm = m0 + lm;
    int ka = lq * 8;
    int kb = 32 + lq * 8;

    // ---- prefetch v[src] (consumed after 2 barriers in agg_v) ----
    float vp[4] = {0.f, 0.f, 0.f, 0.f};
    if (t < 144) {
        int segv = t / 9, cv = t - segv * 9;
        int r0v = segv * 4;
#pragma unroll
        for (int r = 0; r < 4; ++r)
            vp[r] = v[(size_t)m_src[r0v + r] * 9 + cv];
    }
    // ---- prefetch Wv^T fragments (consumed after phase 2) ----
    bf16x8 wv0 = *(const bf16x8*)(Wvt + (size_t)lm * 64 + ka);
    bf16x8 wv1 = *(const bf16x8*)(Wvt + (size_t)lm * 64 + kb);

    // ---- phase 1: h1 in MFMA A-layout, registers only ----
    bf16x8 afr0, afr1;
    {
        int dstr = m_dst[rm], srcr = m_src[rm];
        float dv = m_d[rm];
        const float* pa = Pa + (size_t)dstr * HID;
        const float* pb = Pb + (size_t)srcr * HID;
        f8 xa = load8(pa + ka), xb = load8(pb + ka), xw = load8(wd + ka);
        float h1a[8];
#pragma unroll
        for (int j = 0; j < 8; ++j) h1a[j] = silu_f(xa.v[j] + xb.v[j] + dv * xw.v[j]);
        afr0 = pack8(h1a);
        f8 ya = load8(pa + kb), yb = load8(pb + kb), yw = load8(wd + kb);
        float h1b[8];
#pragma unroll
        for (int j = 0; j < 8; ++j) h1b[j] = silu_f(ya.v[j] + yb.v[j] + dv * yw.v[j]);
        afr1 = pack8(h1b);
    }

    // ---- phase 2: h = silu(h1@We2+be2)*C via MFMA ----
#pragma unroll
    for (int t4 = 0; t4 < 4; ++t4) {
        int col = t4 * 16 + lm;
        bf16x8 b0 = *(const bf16x8*)(We2t + (size_t)col * 64 + ka);
        bf16x8 b1 = *(const bf16x8*)(We2t + (size_t)col * 64 + kb);
        f32x4 a = {0.f, 0.f, 0.f, 0.f};
        a = __builtin_amdgcn_mfma_f32_16x16x32_bf16(afr0, b0, a, 0, 0, 0);
        a = __builtin_amdgcn_mfma_f32_16x16x32_bf16(afr1, b1, a, 0, 0, 0);
        float bias = be2[col];
#pragma unroll
        for (int g = 0; g < 4; ++g) {
            int er = m0 + lq * 4 + g;
            hb[er * 68 + col] = silu_f(a[g] + bias) * m_C[er];
        }
    }
    __syncthreads();

    // ---- gates = h @ Wv + bv via MFMA ----
    {
        f8 g0 = load8(&hb[rm * 68 + ka]);
        f8 g1 = load8(&hb[rm * 68 + kb]);
        bf16x8 ga0 = pack8(g0.v), ga1 = pack8(g1.v);
        f32x4 ga = {0.f, 0.f, 0.f, 0.f};
        ga = __builtin_amdgcn_mfma_f32_16x16x32_bf16(ga0, wv0, ga, 0, 0, 0);
        ga = __builtin_amdgcn_mfma_f32_16x16x32_bf16(ga1, wv1, ga, 0, 0, 0);
        if (lm < 6) {
            float bias = bv[lm];
#pragma unroll
            for (int g = 0; g < 4; ++g) {
                int er = m0 + lq * 4 + g;
                gl[er * 8 + lm] = ga[g] + bias;
            }
        }
    }

    // ---- agg_s: segmented column-sum over dst runs ----
    {
        int c = t & 63, seg = t >> 6;
        int r0 = seg * 16;
        float acc = 0.f;
        int cur = m_dst[r0];
#pragma unroll 4
        for (int r = r0; r < r0 + 16; ++r) {
            int dr = m_dst[r];
            if (dr != cur) {
                atomicAdd(&agg_s[(size_t)cur * HID + c], acc);
                acc = 0.f; cur = dr;
            }
            acc += hb[r * 68 + c];
        }
        atomicAdd(&agg_s[(size_t)cur * HID + c], acc);
    }
    __syncthreads();

    // ---- agg_v: mv = v[src]*g1 + r*g2, segmented sum (uses prefetched vp) ----
    if (t < 144) {
        int seg = t / 9;
        int c = t - seg * 9;
        int i = c / 3, j = c - i * 3;
        int r0 = seg * 4;
        float acc = 0.f;
        int cur = m_dst[r0];
#pragma unroll
        for (int r = 0; r < 4; ++r) {
            int rr = r0 + r;
            int dr = m_dst[rr];
            if (dr != cur) {
                atomicAdd(&agg_v[(size_t)cur * 9 + c], acc);
                acc = 0.f; cur = dr;
            }
            if (e0 + rr < E) {
                acc += vp[r] * gl[rr * 8 + j] + m_r[rr * 3 + i] * gl[rr * 8 + 3 + j];
            }
        }
        atomicAdd(&agg_v[(size_t)cur * 9 + c], acc);
    }
}

// ---------------------------------------------------------------------------
// Fused node kernel: u = silu([s,agg_s]@Wn1+bn1); s += u@Wn2+bn2;
// v += agg_v/deg; then (do_pre) [Pa|Pb] = s_new @ We1(l+1) — s_new stays on-chip.
// Also zeroes agg_s/agg_v for the next layer (zero-after-read).
// ---------------------------------------------------------------------------
__global__ __launch_bounds__(256) void node_fused_kernel(
    float* __restrict__ s, float* __restrict__ vout,
    float* __restrict__ agg_s, float* __restrict__ agg_v,
    const int* __restrict__ row_start,
    const unsigned short* __restrict__ Wn1t, const float* __restrict__ bn1,
    const unsigned short* __restrict__ Wn2t, const float* __restrict__ bn2,
    const unsigned short* __restrict__ We1tn, const float* __restrict__ be1n,
    float* __restrict__ Pa, float* __restrict__ Pb,
    int N, int do_pre)
{
    __shared__ unsigned short xa[64 * 200];  // phase A: [s|agg_s]; phase B (alias): s_new bf16, stride 136
    __shared__ unsigned short ub[64 * 72];
    int t = threadIdx.x;
    int n0 = blockIdx.x * 64;
    for (int idx = t; idx < 64 * 32; idx += 256) {
        int rn = idx >> 5, c4 = (idx & 31) << 2;
        int n = n0 + rn;
        float4 val = make_float4(0.f, 0.f, 0.f, 0.f);
        if (n < N) val = *(const float4*)(s + (size_t)n * SDIM + c4);
        unsigned int p0 = (unsigned int)f2bf(val.x) | ((unsigned int)f2bf(val.y) << 16);
        unsigned int p1 = (unsigned int)f2bf(val.z) | ((unsigned int)f2bf(val.w) << 16);
        *(uint2*)(xa + rn * 200 + c4) = make_uint2(p0, p1);
    }
    for (int idx = t; idx < 64 * 16; idx += 256) {
        int rn = idx >> 4, c4 = (idx & 15) << 2;
        int n = n0 + rn;
        float4 val = make_float4(0.f, 0.f, 0.f, 0.f);
        if (n < N) {
            float* ap = agg_s + (size_t)n * HID + c4;
            val = *(const float4*)ap;
            *(float4*)ap = make_float4(0.f, 0.f, 0.f, 0.f);   // zero for next layer
        }
        unsigned int p0 = (unsigned int)f2bf(val.x) | ((unsigned int)f2bf(val.y) << 16);
        unsigned int p1 = (unsigned int)f2bf(val.z) | ((unsigned int)f2bf(val.w) << 16);
        *(uint2*)(xa + rn * 200 + 128 + c4) = make_uint2(p0, p1);
    }
    __syncthreads();

    int lane = t & 63, w = t >> 6;
    int lm = lane & 15, lq = lane >> 4;
    int m0 = w * 16, rm = m0 + lm;

    // ---- GEMM1: u = silu(x @ Wn1 + bn1) ----
    bf16x8 af[6];
#pragma unroll
    for (int kc = 0; kc < 6; ++kc)
        af[kc] = *(const bf16x8*)(xa + rm * 200 + kc * 32 + lq * 8);

#pragma unroll
    for (int ct = 0; ct < 4; ++ct) {
        int col = ct * 16 + lm;
        f32x4 acc = {0.f, 0.f, 0.f, 0.f};
#pragma unroll
        for (int kc = 0; kc < 6; ++kc) {
            bf16x8 b = *(const bf16x8*)(Wn1t + (size_t)col * 192 + kc * 32 + lq * 8);
            acc = __builtin_amdgcn_mfma_f32_16x16x32_bf16(af[kc], b, acc, 0, 0, 0);
        }
        float bias = bn1[col];
#pragma unroll
        for (int g = 0; g < 4; ++g) {
            int er = m0 + lq * 4 + g;
            ub[er * 72 + col] = f2bf(silu_f(acc[g] + bias));
        }
    }
    __syncthreads();   // ub ready; xa reads done -> reusable

    // ---- GEMM2: s_new = s + u @ Wn2 + bn2 ; stash s_new bf16 in LDS ----
    unsigned short* sa = xa;   // alias (stride 136)
    bf16x8 uf[2];
#pragma unroll
    for (int kc = 0; kc < 2; ++kc)
        uf[kc] = *(const bf16x8*)(ub + rm * 72 + kc * 32 + lq * 8);

#pragma unroll
    for (int ct = 0; ct < 8; ++ct) {
        int col = ct * 16 + lm;
        f32x4 acc = {0.f, 0.f, 0.f, 0.f};
#pragma unroll
        for (int kc = 0; kc < 2; ++kc) {
            bf16x8 b = *(const bf16x8*)(Wn2t + (size_t)col * 64 + kc * 32 + lq * 8);
            acc = __builtin_amdgcn_mfma_f32_16x16x32_bf16(uf[kc], b, acc, 0, 0, 0);
        }
        float bias = bn2[col];
#pragma unroll
        for (int g = 0; g < 4; ++g) {
            int er = m0 + lq * 4 + g;
            int n = n0 + er;
            if (n < N) {
                float* sp = s + (size_t)n * SDIM + col;
                float sv = *sp + acc[g] + bias;
                *sp = sv;
                sa[er * 136 + col] = f2bf(sv);
            } else {
                sa[er * 136 + col] = 0;
            }
        }
    }
    __syncthreads();   // sa ready

    // ---- pre-GEMM for next layer: [Pa|Pb] = s_new @ We1(l+1) ----
    if (do_pre) {
        bf16x8 pf[4];
#pragma unroll
        for (int kc = 0; kc < 4; ++kc)
            pf[kc] = *(const bf16x8*)(sa + rm * 136 + kc * 32 + lq * 8);

#pragma unroll
        for (int ct = 0; ct < 8; ++ct) {
            int col = ct * 16 + lm;
            f32x4 acc = {0.f, 0.f, 0.f, 0.f};
#pragma unroll
            for (int kc = 0; kc < 4; ++kc) {
                bf16x8 b = *(const bf16x8*)(We1tn + (size_t)col * 128 + kc * 32 + lq * 8);
                acc = __builtin_amdgcn_mfma_f32_16x16x32_bf16(pf[kc], b, acc, 0, 0, 0);
            }
            float bias = (ct < 4) ? be1n[col] : 0.0f;
#pragma unroll
            for (int g = 0; g < 4; ++g) {
                int n = n0 + m0 + lq * 4 + g;
                if (n < N) {
                    if (ct < 4) Pa[(size_t)n * HID + col]        = acc[g] + bias;
                    else        Pb[(size_t)n * HID + (col - 64)] = acc[g];
                }
            }
        }
    }

    // ---- v += agg_v / max(deg,1) ; zero agg_v for next layer ----
    for (int idx = t; idx < 64 * 9; idx += 256) {
        int rn = idx / 9, c = idx - rn * 9;
        int n2 = n0 + rn;
        if (n2 < N) {
            float av = agg_v[(size_t)n2 * 9 + c];
            agg_v[(size_t)n2 * 9 + c] = 0.f;
            float dg = fmaxf((float)(row_start[n2 + 1] - row_start[n2]), 1.0f);
            vout[(size_t)n2 * 9 + c] += av / dg;
        }
    }
}

extern "C" void kernel_launch(void* const* d_in, const int* in_sizes, int n_in,
                              void* d_out, int out_size, void* d_ws, size_t ws_size,
                              hipStream_t stream)
{
    const float* s_in  = (const float*)d_in[0];
    const float* v_in  = (const float*)d_in[1];
    const void*  ei    = d_in[2];
    const float* d_vec = (const float*)d_in[3];
    const float* r_vec = (const float*)d_in[4];
    const float* We1 = (const float*)d_in[6];
    const float* be1 = (const float*)d_in[7];
    const float* We2 = (const float*)d_in[8];
    const float* be2 = (const float*)d_in[9];
    const float* Wn1 = (const float*)d_in[10];
    const float* bn1 = (const float*)d_in[11];
    const float* Wn2 = (const float*)d_in[12];
    const float* bn2 = (const float*)d_in[13];
    const float* Wv  = (const float*)d_in[14];
    const float* bv  = (const float*)d_in[15];

    int N = in_sizes[0] / SDIM;
    int E = in_sizes[3];

    float* out_s = (float*)d_out;
    float* out_v = out_s + (size_t)N * SDIM;

    // ------ workspace layout (32B-aligned blocks) ------
    char* wp = (char*)d_ws;
    auto alloc = [&wp](size_t bytes) -> char* {
        char* p = wp;
        wp += (bytes + 31) & ~(size_t)31;
        return p;
    };
    float* rec       = (float*)alloc((size_t)E * 8 * 4);
    float* Pa        = (float*)alloc((size_t)N * HID * 4);
    float* Pb        = (float*)alloc((size_t)N * HID * 4);
    float* agg_s     = (float*)alloc((size_t)N * HID * 4);   // contiguous with agg_v
    float* agg_v     = (float*)alloc((size_t)N * 9 * 4);
    int*   deg_i     = (int*)alloc((size_t)N * 4);           // contiguous with cursor
    int*   cursor    = (int*)alloc((size_t)N * 4);
    int*   row_start = (int*)alloc((size_t)(N + 1) * 4);
    int*   part      = (int*)alloc(64 * 4);
    int*   flag      = (int*)alloc(16);
    int*   srcw      = (int*)alloc((size_t)E * 4);
    int*   dstw      = (int*)alloc((size_t)E * 4);
    unsigned short* We2t = (unsigned short*)alloc((size_t)DEPTH * HID * HID * 2);
    unsigned short* Wvt  = (unsigned short*)alloc((size_t)DEPTH * 16 * 64 * 2);
    unsigned short* We1t = (unsigned short*)alloc((size_t)DEPTH * 128 * 128 * 2);
    unsigned short* Wn1t = (unsigned short*)alloc((size_t)DEPTH * 64 * 192 * 2);
    unsigned short* Wn2t = (unsigned short*)alloc((size_t)DEPTH * 128 * 64 * 2);

    hipMemcpyAsync(out_s, s_in, (size_t)N * SDIM * sizeof(float),
                   hipMemcpyDeviceToDevice, stream);
    hipMemcpyAsync(out_v, v_in, (size_t)N * 9 * sizeof(float),
                   hipMemcpyDeviceToDevice, stream);

    // ------ one-time prep ------
    detect_idx_kernel<<<1, 1, 0, stream>>>(ei, N, flag);
    hipMemsetAsync(deg_i, 0, (size_t)N * 2 * sizeof(int), stream);    // deg_i + cursor
    hipMemsetAsync(agg_s, 0, (size_t)N * (HID + 9) * sizeof(float), stream);
    decode_idx_kernel<<<(2 * E + 255) / 256, 256, 0, stream>>>(ei, E, N, flag,
                                                               srcw, dstw, deg_i);
    int B1 = (N + CHUNK - 1) / CHUNK;
    scan1_kernel<<<B1, 256, 0, stream>>>(deg_i, part, N);
    scan2_kernel<<<1, 64, 0, stream>>>(part, row_start, B1, N);
    scan3_kernel<<<B1, 256, 0, stream>>>(deg_i, part, row_start, N);
    scatter_kernel<<<(E + 255) / 256, 256, 0, stream>>>(srcw, dstw, d_vec, r_vec,
                                                        row_start, cursor, rec, E);
    wprep_kernel<<<DEPTH, 256, 0, stream>>>(We1, We2, Wv, Wn1, Wn2,
                                            We1t, We2t, Wvt, Wn1t, Wn2t);

    int nb_n = (N + 63) / 64;
    int nb_e = (E + 63) / 64;
    node_pre_kernel<<<nb_n, 256, 0, stream>>>(out_s, We1t, be1, Pa, Pb, N);
    for (int l = 0; l < DEPTH; ++l) {
        int ln = (l + 1 < DEPTH) ? (l + 1) : 0;
        const float* We1_l = We1 + (size_t)l * 257 * 64;
        const float* be2_l = be2 + (size_t)l * 64;
        const float* bn1_l = bn1 + (size_t)l * 64;
        const float* bn2_l = bn2 + (size_t)l * 128;
        const float* bv_l  = bv  + (size_t)l * 6;
        const float* be1_n = be1 + (size_t)ln * 64;
        const unsigned short* We2t_l = We2t + (size_t)l * HID * HID;
        const unsigned short* Wvt_l  = Wvt  + (size_t)l * 16 * 64;
        const unsigned short* Wn1t_l = Wn1t + (size_t)l * 64 * 192;
        const unsigned short* Wn2t_l = Wn2t + (size_t)l * 128 * 64;
        const unsigned short* We1t_n = We1t + (size_t)ln * 128 * 128;

        edge_kernel<<<nb_e, 256, 0, stream>>>(rec, Pa, Pb,
                                              We1_l + 256 * 64,
                                              We2t_l, be2_l, Wvt_l, bv_l,
                                              out_v, agg_s, agg_v, E);
        node_fused_kernel<<<nb_n, 256, 0, stream>>>(out_s, out_v, agg_s, agg_v,
                                                    row_start,
                                                    Wn1t_l, bn1_l, Wn2t_l, bn2_l,
                                                    We1t_n, be1_n, Pa, Pb,
                                                    N, (l + 1 < DEPTH) ? 1 : 0);
    }
}

// Round 7
// 814.549 us; speedup vs baseline: 16.1251x; 1.1060x over previous
//
#include <hip/hip_runtime.h>
#include <math.h>

#define SDIM 128
#define HID 64
#define DEPTH 4
#define CUTOFF_F 5.0f
#define CHUNK 4096

typedef __attribute__((ext_vector_type(8))) short bf16x8;   // 8 bf16 = 4 VGPRs
typedef __attribute__((ext_vector_type(4))) float f32x4;

// fast silu: v_exp + v_rcp
__device__ __forceinline__ float silu_f(float x) {
    float e = __expf(-x);
    return x * __builtin_amdgcn_rcpf(1.0f + e);
}

__device__ __forceinline__ unsigned short f2bf(float x) {
    unsigned int u = __float_as_uint(x);
    unsigned int r = (u + 0x7fffu + ((u >> 16) & 1u)) >> 16;   // RNE
    return (unsigned short)r;
}

struct f8 { float v[8]; };
__device__ __forceinline__ f8 load8(const float* p) {
    f8 r;
    float4 a = *(const float4*)p;
    float4 b = *(const float4*)(p + 4);
    r.v[0]=a.x; r.v[1]=a.y; r.v[2]=a.z; r.v[3]=a.w;
    r.v[4]=b.x; r.v[5]=b.y; r.v[6]=b.z; r.v[7]=b.w;
    return r;
}
__device__ __forceinline__ bf16x8 pack8(const float* h) {
    bf16x8 o;
#pragma unroll
    for (int j = 0; j < 8; ++j) o[j] = (short)f2bf(h[j]);
    return o;
}
__device__ __forceinline__ void unpack8(bf16x8 b, float* o) {
#pragma unroll
    for (int j = 0; j < 8; ++j)
        o[j] = __uint_as_float(((unsigned int)(unsigned short)b[j]) << 16);
}

// ---------------------------------------------------------------------------
// Index decode + degree histogram.
// ---------------------------------------------------------------------------
__global__ void detect_idx_kernel(const void* ei, int N, int* flag) {
    const long long* p64 = (const long long*)ei;
    int ok64 = 1;
    for (int i = 0; i < 64; ++i) {
        long long v = p64[i];
        if (v < 0 || v >= (long long)N) { ok64 = 0; break; }
    }
    *flag = ok64;
}

__global__ void decode_idx_kernel(const void* ei, int E, int N, const int* flag,
                                  int* __restrict__ srcw, int* __restrict__ dstw,
                                  int* __restrict__ deg_i) {
    int i = blockIdx.x * blockDim.x + threadIdx.x;
    if (i >= 2 * E) return;
    int v;
    if (*flag) v = (int)((const long long*)ei)[i];
    else       v = ((const int*)ei)[i];
    v = min(max(v, 0), N - 1);
    if (i < E) {
        srcw[i] = v;
    } else {
        dstw[i - E] = v;
        atomicAdd(&deg_i[v], 1);
    }
}

// ---------------------------------------------------------------------------
// 3-phase parallel exclusive scan: deg_i -> row_start[0..N]
// ---------------------------------------------------------------------------
__global__ __launch_bounds__(256) void scan1_kernel(const int* __restrict__ deg_i,
                                                    int* __restrict__ part, int N) {
    __shared__ int wsum[4];
    int b = blockIdx.x, t = threadIdx.x;
    int base = b * CHUNK;
    int sum = 0;
    for (int i = t; i < CHUNK; i += 256) {
        int idx = base + i;
        sum += (idx < N) ? deg_i[idx] : 0;
    }
#pragma unroll
    for (int off = 32; off; off >>= 1) sum += __shfl_down(sum, off, 64);
    if ((t & 63) == 0) wsum[t >> 6] = sum;
    __syncthreads();
    if (t == 0) part[b] = wsum[0] + wsum[1] + wsum[2] + wsum[3];
}

__global__ void scan2_kernel(int* __restrict__ part, int* __restrict__ row_start,
                             int B1, int N) {
    int t = threadIdx.x;   // 64 threads
    int v = (t < B1) ? part[t] : 0;
    int incl = v;
#pragma unroll
    for (int off = 1; off < 64; off <<= 1) {
        int x = __shfl_up(incl, off, 64);
        if (t >= off) incl += x;
    }
    if (t < B1) part[t] = incl - v;      // exclusive
    if (t == 63) row_start[N] = incl;    // grand total
}

__global__ __launch_bounds__(256) void scan3_kernel(const int* __restrict__ deg_i,
                                                    const int* __restrict__ part,
                                                    int* __restrict__ row_start, int N) {
    __shared__ int wsum[4];
    __shared__ int carry_s;
    int b = blockIdx.x, t = threadIdx.x;
    int lane = t & 63, w = t >> 6;
    if (t == 0) carry_s = part[b];
    __syncthreads();
    int base0 = b * CHUNK;
    for (int base = base0; base < base0 + CHUNK; base += 256) {
        int i = base + t;
        int v = (i < N) ? deg_i[i] : 0;
        int incl = v;
#pragma unroll
        for (int off = 1; off < 64; off <<= 1) {
            int x = __shfl_up(incl, off, 64);
            if (lane >= off) incl += x;
        }
        if (lane == 63) wsum[w] = incl;
        __syncthreads();
        int wpre = 0;
#pragma unroll
        for (int k = 0; k < 4; ++k) if (k < w) wpre += wsum[k];
        int total = wsum[0] + wsum[1] + wsum[2] + wsum[3];
        int carry = carry_s;
        if (i < N) row_start[i] = carry + wpre + incl - v;
        __syncthreads();
        if (t == 0) carry_s = carry + total;
        __syncthreads();
    }
}

// ---------------------------------------------------------------------------
// Scatter: dst-sorted permutation; one packed 32B record per edge.
// ---------------------------------------------------------------------------
__global__ void scatter_kernel(const int* __restrict__ srcw, const int* __restrict__ dstw,
                               const float* __restrict__ dvec, const float* __restrict__ rvec,
                               const int* __restrict__ row_start, int* __restrict__ cursor,
                               float* __restrict__ rec, int E) {
    int e = blockIdx.x * blockDim.x + threadIdx.x;
    if (e >= E) return;
    int dd = dstw[e];
    int ofs = atomicAdd(&cursor[dd], 1);
    int pos = row_start[dd] + ofs;
    float dv = dvec[e];
    float c = 0.5f * (cosf(3.14159265358979323846f * dv * (1.0f / CUTOFF_F)) + 1.0f);
    c = (dv < CUTOFF_F) ? c : 0.0f;
    float4 r0 = make_float4(__int_as_float(srcw[e]), __int_as_float(dd), dv, c);
    float4 r1 = make_float4(rvec[(size_t)e * 3 + 0], rvec[(size_t)e * 3 + 1],
                            rvec[(size_t)e * 3 + 2], 0.0f);
    *(float4*)(rec + (size_t)pos * 8)     = r0;
    *(float4*)(rec + (size_t)pos * 8 + 4) = r1;
}

// ---------------------------------------------------------------------------
// Weight transpose+cast to bf16 [n][k] for MFMA B-operands.
// ---------------------------------------------------------------------------
__global__ __launch_bounds__(256) void wprep_kernel(
    const float* __restrict__ We1, const float* __restrict__ We2,
    const float* __restrict__ Wv,  const float* __restrict__ Wn1,
    const float* __restrict__ Wn2,
    unsigned short* __restrict__ We1t, unsigned short* __restrict__ We2t,
    unsigned short* __restrict__ Wvt,  unsigned short* __restrict__ Wn1t,
    unsigned short* __restrict__ Wn2t) {
    int l = blockIdx.x, t = threadIdx.x;
    const float* W2 = We2 + (size_t)l * HID * HID;
    unsigned short* T2 = We2t + (size_t)l * HID * HID;
    for (int idx = t; idx < HID * HID; idx += 256) {
        int n = idx >> 6, k = idx & 63;
        T2[n * 64 + k] = f2bf(W2[k * HID + n]);
    }
    const float* Wvl = Wv + (size_t)l * HID * 6;
    unsigned short* Tv = Wvt + (size_t)l * 16 * 64;
    for (int idx = t; idx < 16 * 64; idx += 256) {
        int n = idx >> 6, k = idx & 63;
        Tv[idx] = (n < 6) ? f2bf(Wvl[k * 6 + n]) : (unsigned short)0;
    }
    const float* W1 = We1 + (size_t)l * 257 * 64;
    unsigned short* T1 = We1t + (size_t)l * 128 * 128;
    for (int idx = t; idx < 128 * 128; idx += 256) {
        int n = idx >> 7, k = idx & 127;
        float w = (n < 64) ? W1[(size_t)k * 64 + n] : W1[(size_t)(k + 128) * 64 + (n - 64)];
        T1[n * 128 + k] = f2bf(w);
    }
    const float* Wn1l = Wn1 + (size_t)l * 192 * 64;
    unsigned short* Tn1 = Wn1t + (size_t)l * 64 * 192;
    for (int idx = t; idx < 64 * 192; idx += 256) {
        int n = idx / 192, k = idx - n * 192;
        Tn1[idx] = f2bf(Wn1l[(size_t)k * 64 + n]);
    }
    const float* Wn2l = Wn2 + (size_t)l * 64 * 128;
    unsigned short* Tn2 = Wn2t + (size_t)l * 128 * 64;
    for (int idx = t; idx < 128 * 64; idx += 256) {
        int n = idx >> 6, k = idx & 63;
        Tn2[idx] = f2bf(Wn2l[(size_t)k * 128 + n]);
    }
}

// ---------------------------------------------------------------------------
// node_pre (layer 0 only): [Pa|Pb] = s @ [We1a|We1b] (+be1 on Pa), bf16 out
// ---------------------------------------------------------------------------
__global__ __launch_bounds__(256) void node_pre_kernel(
    const float* __restrict__ s, const unsigned short* __restrict__ We1t,
    const float* __restrict__ be1,
    unsigned short* __restrict__ Pa, unsigned short* __restrict__ Pb, int N)
{
    __shared__ unsigned short sa[64 * 136];
    int t = threadIdx.x;
    int n0 = blockIdx.x * 64;
    for (int idx = t; idx < 64 * 32; idx += 256) {
        int rn = idx >> 5, c4 = (idx & 31) << 2;
        int n = n0 + rn;
        float4 val = make_float4(0.f, 0.f, 0.f, 0.f);
        if (n < N) val = *(const float4*)(s + (size_t)n * SDIM + c4);
        unsigned int p0 = (unsigned int)f2bf(val.x) | ((unsigned int)f2bf(val.y) << 16);
        unsigned int p1 = (unsigned int)f2bf(val.z) | ((unsigned int)f2bf(val.w) << 16);
        *(uint2*)(sa + rn * 136 + c4) = make_uint2(p0, p1);
    }
    __syncthreads();
    int lane = t & 63, w = t >> 6;
    int lm = lane & 15, lq = lane >> 4;
    int m0 = w * 16, rm = m0 + lm;

    bf16x8 af[4];
#pragma unroll
    for (int kc = 0; kc < 4; ++kc)
        af[kc] = *(const bf16x8*)(sa + rm * 136 + kc * 32 + lq * 8);

#pragma unroll
    for (int ct = 0; ct < 8; ++ct) {
        int col = ct * 16 + lm;
        f32x4 acc = {0.f, 0.f, 0.f, 0.f};
#pragma unroll
        for (int kc = 0; kc < 4; ++kc) {
            bf16x8 b = *(const bf16x8*)(We1t + (size_t)col * 128 + kc * 32 + lq * 8);
            acc = __builtin_amdgcn_mfma_f32_16x16x32_bf16(af[kc], b, acc, 0, 0, 0);
        }
        float bias = (ct < 4) ? be1[col] : 0.0f;
#pragma unroll
        for (int g = 0; g < 4; ++g) {
            int n = n0 + m0 + lq * 4 + g;
            if (n < N) {
                if (ct < 4) Pa[(size_t)n * HID + col]        = f2bf(acc[g] + bias);
                else        Pb[(size_t)n * HID + (col - 64)] = f2bf(acc[g]);
            }
        }
    }
}

// ---------------------------------------------------------------------------
// Fused edge kernel (dst-sorted, segmented reduction, boundary atomics).
// Pa/Pb gathered as bf16 (one 128B line per edge per matrix).
// ---------------------------------------------------------------------------
__global__ __launch_bounds__(256) void edge_kernel(
    const float* __restrict__ rec,
    const unsigned short* __restrict__ Pa, const unsigned short* __restrict__ Pb,
    const float* __restrict__ wd,
    const unsigned short* __restrict__ We2t, const float* __restrict__ be2,
    const unsigned short* __restrict__ Wvt, const float* __restrict__ bv,
    const float* __restrict__ v,
    float* __restrict__ agg_s, float* __restrict__ agg_v, int E)
{
    __shared__ float hb[64 * 68];
    __shared__ float gl[64 * 8];
    __shared__ int   m_src[64], m_dst[64];
    __shared__ float m_d[64], m_C[64];
    __shared__ float m_r[64 * 3];
    int t = threadIdx.x;
    int e0 = blockIdx.x * 64;
    if (t < 64) {
        int e = e0 + t;
        int ec = (e < E) ? e : (E - 1);
        float4 r0 = *(const float4*)(rec + (size_t)ec * 8);
        float4 r1 = *(const float4*)(rec + (size_t)ec * 8 + 4);
        m_src[t] = __float_as_int(r0.x);
        m_dst[t] = __float_as_int(r0.y);
        m_d[t]   = r0.z;
        m_C[t]   = (e < E) ? r0.w : 0.0f;
        m_r[t*3+0] = r1.x; m_r[t*3+1] = r1.y; m_r[t*3+2] = r1.z;
    }
    __syncthreads();

    int lane = t & 63;
    int w    = t >> 6;
    int lm = lane & 15, lq = lane >> 4;
    int m0 = w * 16;
    int rm = m0 + lm;
    int ka = lq * 8;
    int kb = 32 + lq * 8;

    // ---- prefetch v[src] (consumed after 2 barriers in agg_v) ----
    float vp[4] = {0.f, 0.f, 0.f, 0.f};
    if (t < 144) {
        int segv = t / 9, cv = t - segv * 9;
        int r0v = segv * 4;
#pragma unroll
        for (int r = 0; r < 4; ++r)
            vp[r] = v[(size_t)m_src[r0v + r] * 9 + cv];
    }
    // ---- prefetch Wv^T fragments (consumed after phase 2) ----
    bf16x8 wv0 = *(const bf16x8*)(Wvt + (size_t)lm * 64 + ka);
    bf16x8 wv1 = *(const bf16x8*)(Wvt + (size_t)lm * 64 + kb);

    // ---- phase 1: h1 in MFMA A-layout, registers only (bf16 gathers) ----
    bf16x8 afr0, afr1;
    {
        int dstr = m_dst[rm], srcr = m_src[rm];
        float dv = m_d[rm];
        const unsigned short* pa = Pa + (size_t)dstr * HID;
        const unsigned short* pb = Pb + (size_t)srcr * HID;
        bf16x8 ba0 = *(const bf16x8*)(pa + ka);
        bf16x8 bb0 = *(const bf16x8*)(pb + ka);
        bf16x8 ba1 = *(const bf16x8*)(pa + kb);
        bf16x8 bb1 = *(const bf16x8*)(pb + kb);
        f8 xw = load8(wd + ka), yw = load8(wd + kb);
        float fa[8], fb[8], h1[8];
        unpack8(ba0, fa); unpack8(bb0, fb);
#pragma unroll
        for (int j = 0; j < 8; ++j) h1[j] = silu_f(fa[j] + fb[j] + dv * xw.v[j]);
        afr0 = pack8(h1);
        unpack8(ba1, fa); unpack8(bb1, fb);
#pragma unroll
        for (int j = 0; j < 8; ++j) h1[j] = silu_f(fa[j] + fb[j] + dv * yw.v[j]);
        afr1 = pack8(h1);
    }

    // ---- phase 2: h = silu(h1@We2+be2)*C via MFMA ----
#pragma unroll
    for (int t4 = 0; t4 < 4; ++t4) {
        int col = t4 * 16 + lm;
        bf16x8 b0 = *(const bf16x8*)(We2t + (size_t)col * 64 + ka);
        bf16x8 b1 = *(const bf16x8*)(We2t + (size_t)col * 64 + kb);
        f32x4 a = {0.f, 0.f, 0.f, 0.f};
        a = __builtin_amdgcn_mfma_f32_16x16x32_bf16(afr0, b0, a, 0, 0, 0);
        a = __builtin_amdgcn_mfma_f32_16x16x32_bf16(afr1, b1, a, 0, 0, 0);
        float bias = be2[col];
#pragma unroll
        for (int g = 0; g < 4; ++g) {
            int er = m0 + lq * 4 + g;
            hb[er * 68 + col] = silu_f(a[g] + bias) * m_C[er];
        }
    }
    __syncthreads();

    // ---- gates = h @ Wv + bv via MFMA ----
    {
        f8 g0 = load8(&hb[rm * 68 + ka]);
        f8 g1 = load8(&hb[rm * 68 + kb]);
        bf16x8 ga0 = pack8(g0.v), ga1 = pack8(g1.v);
        f32x4 ga = {0.f, 0.f, 0.f, 0.f};
        ga = __builtin_amdgcn_mfma_f32_16x16x32_bf16(ga0, wv0, ga, 0, 0, 0);
        ga = __builtin_amdgcn_mfma_f32_16x16x32_bf16(ga1, wv1, ga, 0, 0, 0);
        if (lm < 6) {
            float bias = bv[lm];
#pragma unroll
            for (int g = 0; g < 4; ++g) {
                int er = m0 + lq * 4 + g;
                gl[er * 8 + lm] = ga[g] + bias;
            }
        }
    }

    // ---- agg_s: segmented column-sum over dst runs ----
    {
        int c = t & 63, seg = t >> 6;
        int r0 = seg * 16;
        float acc = 0.f;
        int cur = m_dst[r0];
#pragma unroll 4
        for (int r = r0; r < r0 + 16; ++r) {
            int dr = m_dst[r];
            if (dr != cur) {
                atomicAdd(&agg_s[(size_t)cur * HID + c], acc);
                acc = 0.f; cur = dr;
            }
            acc += hb[r * 68 + c];
        }
        atomicAdd(&agg_s[(size_t)cur * HID + c], acc);
    }
    __syncthreads();

    // ---- agg_v: mv = v[src]*g1 + r*g2, segmented sum (uses prefetched vp) ----
    if (t < 144) {
        int seg = t / 9;
        int c = t - seg * 9;
        int i = c / 3, j = c - i * 3;
        int r0 = seg * 4;
        float acc = 0.f;
        int cur = m_dst[r0];
#pragma unroll
        for (int r = 0; r < 4; ++r) {
            int rr = r0 + r;
            int dr = m_dst[rr];
            if (dr != cur) {
                atomicAdd(&agg_v[(size_t)cur * 9 + c], acc);
                acc = 0.f; cur = dr;
            }
            if (e0 + rr < E) {
                acc += vp[r] * gl[rr * 8 + j] + m_r[rr * 3 + i] * gl[rr * 8 + 3 + j];
            }
        }
        atomicAdd(&agg_v[(size_t)cur * 9 + c], acc);
    }
}

// ---------------------------------------------------------------------------
// Fused node kernel: u = silu([s,agg_s]@Wn1+bn1); s += u@Wn2+bn2;
// v += agg_v/deg; then (do_pre) [Pa|Pb] = s_new @ We1(l+1) (bf16 out).
// Zeroes agg_s/agg_v for the next layer (zero-after-read).
// ---------------------------------------------------------------------------
__global__ __launch_bounds__(256) void node_fused_kernel(
    float* __restrict__ s, float* __restrict__ vout,
    float* __restrict__ agg_s, float* __restrict__ agg_v,
    const int* __restrict__ row_start,
    const unsigned short* __restrict__ Wn1t, const float* __restrict__ bn1,
    const unsigned short* __restrict__ Wn2t, const float* __restrict__ bn2,
    const unsigned short* __restrict__ We1tn, const float* __restrict__ be1n,
    unsigned short* __restrict__ Pa, unsigned short* __restrict__ Pb,
    int N, int do_pre)
{
    __shared__ unsigned short xa[64 * 200];  // phase A: [s|agg_s]; phase B alias: s_new (stride 136)
    __shared__ unsigned short ub[64 * 72];
    int t = threadIdx.x;
    int n0 = blockIdx.x * 64;
    for (int idx = t; idx < 64 * 32; idx += 256) {
        int rn = idx >> 5, c4 = (idx & 31) << 2;
        int n = n0 + rn;
        float4 val = make_float4(0.f, 0.f, 0.f, 0.f);
        if (n < N) val = *(const float4*)(s + (size_t)n * SDIM + c4);
        unsigned int p0 = (unsigned int)f2bf(val.x) | ((unsigned int)f2bf(val.y) << 16);
        unsigned int p1 = (unsigned int)f2bf(val.z) | ((unsigned int)f2bf(val.w) << 16);
        *(uint2*)(xa + rn * 200 + c4) = make_uint2(p0, p1);
    }
    for (int idx = t; idx < 64 * 16; idx += 256) {
        int rn = idx >> 4, c4 = (idx & 15) << 2;
        int n = n0 + rn;
        float4 val = make_float4(0.f, 0.f, 0.f, 0.f);
        if (n < N) {
            float* ap = agg_s + (size_t)n * HID + c4;
            val = *(const float4*)ap;
            *(float4*)ap = make_float4(0.f, 0.f, 0.f, 0.f);   // zero for next layer
        }
        unsigned int p0 = (unsigned int)f2bf(val.x) | ((unsigned int)f2bf(val.y) << 16);
        unsigned int p1 = (unsigned int)f2bf(val.z) | ((unsigned int)f2bf(val.w) << 16);
        *(uint2*)(xa + rn * 200 + 128 + c4) = make_uint2(p0, p1);
    }
    __syncthreads();

    int lane = t & 63, w = t >> 6;
    int lm = lane & 15, lq = lane >> 4;
    int m0 = w * 16, rm = m0 + lm;

    // ---- GEMM1: u = silu(x @ Wn1 + bn1) ----
    bf16x8 af[6];
#pragma unroll
    for (int kc = 0; kc < 6; ++kc)
        af[kc] = *(const bf16x8*)(xa + rm * 200 + kc * 32 + lq * 8);

#pragma unroll
    for (int ct = 0; ct < 4; ++ct) {
        int col = ct * 16 + lm;
        f32x4 acc = {0.f, 0.f, 0.f, 0.f};
#pragma unroll
        for (int kc = 0; kc < 6; ++kc) {
            bf16x8 b = *(const bf16x8*)(Wn1t + (size_t)col * 192 + kc * 32 + lq * 8);
            acc = __builtin_amdgcn_mfma_f32_16x16x32_bf16(af[kc], b, acc, 0, 0, 0);
        }
        float bias = bn1[col];
#pragma unroll
        for (int g = 0; g < 4; ++g) {
            int er = m0 + lq * 4 + g;
            ub[er * 72 + col] = f2bf(silu_f(acc[g] + bias));
        }
    }
    __syncthreads();   // ub ready; xa reads done -> reusable

    // ---- GEMM2: s_new = s + u @ Wn2 + bn2 ; stash s_new bf16 in LDS ----
    unsigned short* sa = xa;   // alias (stride 136)
    bf16x8 uf[2];
#pragma unroll
    for (int kc = 0; kc < 2; ++kc)
        uf[kc] = *(const bf16x8*)(ub + rm * 72 + kc * 32 + lq * 8);

#pragma unroll
    for (int ct = 0; ct < 8; ++ct) {
        int col = ct * 16 + lm;
        f32x4 acc = {0.f, 0.f, 0.f, 0.f};
#pragma unroll
        for (int kc = 0; kc < 2; ++kc) {
            bf16x8 b = *(const bf16x8*)(Wn2t + (size_t)col * 64 + kc * 32 + lq * 8);
            acc = __builtin_amdgcn_mfma_f32_16x16x32_bf16(uf[kc], b, acc, 0, 0, 0);
        }
        float bias = bn2[col];
#pragma unroll
        for (int g = 0; g < 4; ++g) {
            int er = m0 + lq * 4 + g;
            int n = n0 + er;
            if (n < N) {
                float* sp = s + (size_t)n * SDIM + col;
                float sv = *sp + acc[g] + bias;
                *sp = sv;
                sa[er * 136 + col] = f2bf(sv);
            } else {
                sa[er * 136 + col] = 0;
            }
        }
    }
    __syncthreads();   // sa ready

    // ---- pre-GEMM for next layer: [Pa|Pb] = s_new @ We1(l+1) (bf16 out) ----
    if (do_pre) {
        bf16x8 pf[4];
#pragma unroll
        for (int kc = 0; kc < 4; ++kc)
            pf[kc] = *(const bf16x8*)(sa + rm * 136 + kc * 32 + lq * 8);

#pragma unroll
        for (int ct = 0; ct < 8; ++ct) {
            int col = ct * 16 + lm;
            f32x4 acc = {0.f, 0.f, 0.f, 0.f};
#pragma unroll
            for (int kc = 0; kc < 4; ++kc) {
                bf16x8 b = *(const bf16x8*)(We1tn + (size_t)col * 128 + kc * 32 + lq * 8);
                acc = __builtin_amdgcn_mfma_f32_16x16x32_bf16(pf[kc], b, acc, 0, 0, 0);
            }
            float bias = (ct < 4) ? be1n[col] : 0.0f;
#pragma unroll
            for (int g = 0; g < 4; ++g) {
                int n = n0 + m0 + lq * 4 + g;
                if (n < N) {
                    if (ct < 4) Pa[(size_t)n * HID + col]        = f2bf(acc[g] + bias);
                    else        Pb[(size_t)n * HID + (col - 64)] = f2bf(acc[g]);
                }
            }
        }
    }

    // ---- v += agg_v / max(deg,1) ; zero agg_v for next layer ----
    for (int idx = t; idx < 64 * 9; idx += 256) {
        int rn = idx / 9, c = idx - rn * 9;
        int n2 = n0 + rn;
        if (n2 < N) {
            float av = agg_v[(size_t)n2 * 9 + c];
            agg_v[(size_t)n2 * 9 + c] = 0.f;
            float dg = fmaxf((float)(row_start[n2 + 1] - row_start[n2]), 1.0f);
            vout[(size_t)n2 * 9 + c] += av / dg;
        }
    }
}

extern "C" void kernel_launch(void* const* d_in, const int* in_sizes, int n_in,
                              void* d_out, int out_size, void* d_ws, size_t ws_size,
                              hipStream_t stream)
{
    const float* s_in  = (const float*)d_in[0];
    const float* v_in  = (const float*)d_in[1];
    const void*  ei    = d_in[2];
    const float* d_vec = (const float*)d_in[3];
    const float* r_vec = (const float*)d_in[4];
    const float* We1 = (const float*)d_in[6];
    const float* be1 = (const float*)d_in[7];
    const float* We2 = (const float*)d_in[8];
    const float* be2 = (const float*)d_in[9];
    const float* Wn1 = (const float*)d_in[10];
    const float* bn1 = (const float*)d_in[11];
    const float* Wn2 = (const float*)d_in[12];
    const float* bn2 = (const float*)d_in[13];
    const float* Wv  = (const float*)d_in[14];
    const float* bv  = (const float*)d_in[15];

    int N = in_sizes[0] / SDIM;
    int E = in_sizes[3];

    float* out_s = (float*)d_out;
    float* out_v = out_s + (size_t)N * SDIM;

    // ------ workspace layout (32B-aligned blocks) ------
    char* wp = (char*)d_ws;
    auto alloc = [&wp](size_t bytes) -> char* {
        char* p = wp;
        wp += (bytes + 31) & ~(size_t)31;
        return p;
    };
    float* rec       = (float*)alloc((size_t)E * 8 * 4);
    unsigned short* Pa = (unsigned short*)alloc((size_t)N * HID * 2);
    unsigned short* Pb = (unsigned short*)alloc((size_t)N * HID * 2);
    float* agg_s     = (float*)alloc((size_t)N * HID * 4);   // contiguous with agg_v
    float* agg_v     = (float*)alloc((size_t)N * 9 * 4);
    int*   deg_i     = (int*)alloc((size_t)N * 4);           // contiguous with cursor
    int*   cursor    = (int*)alloc((size_t)N * 4);
    int*   row_start = (int*)alloc((size_t)(N + 1) * 4);
    int*   part      = (int*)alloc(64 * 4);
    int*   flag      = (int*)alloc(16);
    int*   srcw      = (int*)alloc((size_t)E * 4);
    int*   dstw      = (int*)alloc((size_t)E * 4);
    unsigned short* We2t = (unsigned short*)alloc((size_t)DEPTH * HID * HID * 2);
    unsigned short* Wvt  = (unsigned short*)alloc((size_t)DEPTH * 16 * 64 * 2);
    unsigned short* We1t = (unsigned short*)alloc((size_t)DEPTH * 128 * 128 * 2);
    unsigned short* Wn1t = (unsigned short*)alloc((size_t)DEPTH * 64 * 192 * 2);
    unsigned short* Wn2t = (unsigned short*)alloc((size_t)DEPTH * 128 * 64 * 2);

    hipMemcpyAsync(out_s, s_in, (size_t)N * SDIM * sizeof(float),
                   hipMemcpyDeviceToDevice, stream);
    hipMemcpyAsync(out_v, v_in, (size_t)N * 9 * sizeof(float),
                   hipMemcpyDeviceToDevice, stream);

    // ------ one-time prep ------
    detect_idx_kernel<<<1, 1, 0, stream>>>(ei, N, flag);
    hipMemsetAsync(deg_i, 0, (size_t)N * 2 * sizeof(int), stream);    // deg_i + cursor
    hipMemsetAsync(agg_s, 0, (size_t)N * (HID + 9) * sizeof(float), stream);
    decode_idx_kernel<<<(2 * E + 255) / 256, 256, 0, stream>>>(ei, E, N, flag,
                                                               srcw, dstw, deg_i);
    int B1 = (N + CHUNK - 1) / CHUNK;
    scan1_kernel<<<B1, 256, 0, stream>>>(deg_i, part, N);
    scan2_kernel<<<1, 64, 0, stream>>>(part, row_start, B1, N);
    scan3_kernel<<<B1, 256, 0, stream>>>(deg_i, part, row_start, N);
    scatter_kernel<<<(E + 255) / 256, 256, 0, stream>>>(srcw, dstw, d_vec, r_vec,
                                                        row_start, cursor, rec, E);
    wprep_kernel<<<DEPTH, 256, 0, stream>>>(We1, We2, Wv, Wn1, Wn2,
                                            We1t, We2t, Wvt, Wn1t, Wn2t);

    int nb_n = (N + 63) / 64;
    int nb_e = (E + 63) / 64;
    node_pre_kernel<<<nb_n, 256, 0, stream>>>(out_s, We1t, be1, Pa, Pb, N);
    for (int l = 0; l < DEPTH; ++l) {
        int ln = (l + 1 < DEPTH) ? (l + 1) : 0;
        const float* We1_l = We1 + (size_t)l * 257 * 64;
        const float* be2_l = be2 + (size_t)l * 64;
        const float* bn1_l = bn1 + (size_t)l * 64;
        const float* bn2_l = bn2 + (size_t)l * 128;
        const float* bv_l  = bv  + (size_t)l * 6;
        const float* be1_n = be1 + (size_t)ln * 64;
        const unsigned short* We2t_l = We2t + (size_t)l * HID * HID;
        const unsigned short* Wvt_l  = Wvt  + (size_t)l * 16 * 64;
        const unsigned short* Wn1t_l = Wn1t + (size_t)l * 64 * 192;
        const unsigned short* Wn2t_l = Wn2t + (size_t)l * 128 * 64;
        const unsigned short* We1t_n = We1t + (size_t)ln * 128 * 128;

        edge_kernel<<<nb_e, 256, 0, stream>>>(rec, Pa, Pb,
                                              We1_l + 256 * 64,
                                              We2t_l, be2_l, Wvt_l, bv_l,
                                              out_v, agg_s, agg_v, E);
        node_fused_kernel<<<nb_n, 256, 0, stream>>>(out_s, out_v, agg_s, agg_v,
                                                    row_start,
                                                    Wn1t_l, bn1_l, Wn2t_l, bn2_l,
                                                    We1t_n, be1_n, Pa, Pb,
                                                    N, (l + 1 < DEPTH) ? 1 : 0);
    }
}

// Round 8
// 812.607 us; speedup vs baseline: 16.1636x; 1.0024x over previous
//
#include <hip/hip_runtime.h>
#include <math.h>

#define SDIM 128
#define HID 64
#define DEPTH 4
#define CUTOFF_F 5.0f
#define CHUNK 4096

typedef __attribute__((ext_vector_type(8))) short bf16x8;   // 8 bf16 = 4 VGPRs
typedef __attribute__((ext_vector_type(4))) float f32x4;
typedef float4 __attribute__((aligned(4))) float4_u;        // 4B-aligned float4 load

// fast silu: v_exp + v_rcp
__device__ __forceinline__ float silu_f(float x) {
    float e = __expf(-x);
    return x * __builtin_amdgcn_rcpf(1.0f + e);
}

__device__ __forceinline__ unsigned short f2bf(float x) {
    unsigned int u = __float_as_uint(x);
    unsigned int r = (u + 0x7fffu + ((u >> 16) & 1u)) >> 16;   // RNE
    return (unsigned short)r;
}
__device__ __forceinline__ float bf2f(unsigned short u) {
    return __uint_as_float(((unsigned int)u) << 16);
}

struct f8 { float v[8]; };
__device__ __forceinline__ f8 load8(const float* p) {
    f8 r;
    float4 a = *(const float4*)p;
    float4 b = *(const float4*)(p + 4);
    r.v[0]=a.x; r.v[1]=a.y; r.v[2]=a.z; r.v[3]=a.w;
    r.v[4]=b.x; r.v[5]=b.y; r.v[6]=b.z; r.v[7]=b.w;
    return r;
}
__device__ __forceinline__ bf16x8 pack8(const float* h) {
    bf16x8 o;
#pragma unroll
    for (int j = 0; j < 8; ++j) o[j] = (short)f2bf(h[j]);
    return o;
}
__device__ __forceinline__ void unpack8(bf16x8 b, float* o) {
#pragma unroll
    for (int j = 0; j < 8; ++j)
        o[j] = __uint_as_float(((unsigned int)(unsigned short)b[j]) << 16);
}

// ---------------------------------------------------------------------------
// Index decode + degree histogram.
// ---------------------------------------------------------------------------
__global__ void detect_idx_kernel(const void* ei, int N, int* flag) {
    int lane = threadIdx.x;   // 64 lanes
    const long long* p64 = (const long long*)ei;
    long long v = p64[lane];
    bool ok = (v >= 0 && v < (long long)N);
    unsigned long long m = __ballot(ok);
    if (lane == 0) *flag = (m == ~0ull) ? 1 : 0;
}

__global__ void decode_idx_kernel(const void* ei, int E, int N, const int* flag,
                                  int* __restrict__ srcw, int* __restrict__ dstw,
                                  int* __restrict__ deg_i) {
    int i = blockIdx.x * blockDim.x + threadIdx.x;
    if (i >= 2 * E) return;
    int v;
    if (*flag) v = (int)((const long long*)ei)[i];
    else       v = ((const int*)ei)[i];
    v = min(max(v, 0), N - 1);
    if (i < E) {
        srcw[i] = v;
    } else {
        dstw[i - E] = v;
        atomicAdd(&deg_i[v], 1);
    }
}

// ---------------------------------------------------------------------------
// 3-phase parallel exclusive scan: deg_i -> row_start[0..N]
// ---------------------------------------------------------------------------
__global__ __launch_bounds__(256) void scan1_kernel(const int* __restrict__ deg_i,
                                                    int* __restrict__ part, int N) {
    __shared__ int wsum[4];
    int b = blockIdx.x, t = threadIdx.x;
    int base = b * CHUNK;
    int sum = 0;
    for (int i = t; i < CHUNK; i += 256) {
        int idx = base + i;
        sum += (idx < N) ? deg_i[idx] : 0;
    }
#pragma unroll
    for (int off = 32; off; off >>= 1) sum += __shfl_down(sum, off, 64);
    if ((t & 63) == 0) wsum[t >> 6] = sum;
    __syncthreads();
    if (t == 0) part[b] = wsum[0] + wsum[1] + wsum[2] + wsum[3];
}

__global__ void scan2_kernel(int* __restrict__ part, int* __restrict__ row_start,
                             int B1, int N) {
    int t = threadIdx.x;   // 64 threads
    int v = (t < B1) ? part[t] : 0;
    int incl = v;
#pragma unroll
    for (int off = 1; off < 64; off <<= 1) {
        int x = __shfl_up(incl, off, 64);
        if (t >= off) incl += x;
    }
    if (t < B1) part[t] = incl - v;      // exclusive
    if (t == 63) row_start[N] = incl;    // grand total
}

__global__ __launch_bounds__(256) void scan3_kernel(const int* __restrict__ deg_i,
                                                    const int* __restrict__ part,
                                                    int* __restrict__ row_start, int N) {
    __shared__ int wsum[4];
    __shared__ int carry_s;
    int b = blockIdx.x, t = threadIdx.x;
    int lane = t & 63, w = t >> 6;
    if (t == 0) carry_s = part[b];
    __syncthreads();
    int base0 = b * CHUNK;
    for (int base = base0; base < base0 + CHUNK; base += 256) {
        int i = base + t;
        int v = (i < N) ? deg_i[i] : 0;
        int incl = v;
#pragma unroll
        for (int off = 1; off < 64; off <<= 1) {
            int x = __shfl_up(incl, off, 64);
            if (lane >= off) incl += x;
        }
        if (lane == 63) wsum[w] = incl;
        __syncthreads();
        int wpre = 0;
#pragma unroll
        for (int k = 0; k < 4; ++k) if (k < w) wpre += wsum[k];
        int total = wsum[0] + wsum[1] + wsum[2] + wsum[3];
        int carry = carry_s;
        if (i < N) row_start[i] = carry + wpre + incl - v;
        __syncthreads();
        if (t == 0) carry_s = carry + total;
        __syncthreads();
    }
}

// ---------------------------------------------------------------------------
// Scatter: dst-sorted permutation; one packed 32B record per edge.
// ---------------------------------------------------------------------------
__global__ void scatter_kernel(const int* __restrict__ srcw, const int* __restrict__ dstw,
                               const float* __restrict__ dvec, const float* __restrict__ rvec,
                               const int* __restrict__ row_start, int* __restrict__ cursor,
                               float* __restrict__ rec, int E) {
    int e = blockIdx.x * blockDim.x + threadIdx.x;
    if (e >= E) return;
    int dd = dstw[e];
    int ofs = atomicAdd(&cursor[dd], 1);
    int pos = row_start[dd] + ofs;
    float dv = dvec[e];
    float c = 0.5f * (cosf(3.14159265358979323846f * dv * (1.0f / CUTOFF_F)) + 1.0f);
    c = (dv < CUTOFF_F) ? c : 0.0f;
    float4 r0 = make_float4(__int_as_float(srcw[e]), __int_as_float(dd), dv, c);
    float4 r1 = make_float4(rvec[(size_t)e * 3 + 0], rvec[(size_t)e * 3 + 1],
                            rvec[(size_t)e * 3 + 2], 0.0f);
    *(float4*)(rec + (size_t)pos * 8)     = r0;
    *(float4*)(rec + (size_t)pos * 8 + 4) = r1;
}

// ---------------------------------------------------------------------------
// Weight transpose+cast to bf16 [n][k] for MFMA B-operands.
// ---------------------------------------------------------------------------
__global__ __launch_bounds__(256) void wprep_kernel(
    const float* __restrict__ We1, const float* __restrict__ We2,
    const float* __restrict__ Wv,  const float* __restrict__ Wn1,
    const float* __restrict__ Wn2,
    unsigned short* __restrict__ We1t, unsigned short* __restrict__ We2t,
    unsigned short* __restrict__ Wvt,  unsigned short* __restrict__ Wn1t,
    unsigned short* __restrict__ Wn2t) {
    int l = blockIdx.x, t = threadIdx.x;
    const float* W2 = We2 + (size_t)l * HID * HID;
    unsigned short* T2 = We2t + (size_t)l * HID * HID;
    for (int idx = t; idx < HID * HID; idx += 256) {
        int n = idx >> 6, k = idx & 63;
        T2[n * 64 + k] = f2bf(W2[k * HID + n]);
    }
    const float* Wvl = Wv + (size_t)l * HID * 6;
    unsigned short* Tv = Wvt + (size_t)l * 16 * 64;
    for (int idx = t; idx < 16 * 64; idx += 256) {
        int n = idx >> 6, k = idx & 63;
        Tv[idx] = (n < 6) ? f2bf(Wvl[k * 6 + n]) : (unsigned short)0;
    }
    const float* W1 = We1 + (size_t)l * 257 * 64;
    unsigned short* T1 = We1t + (size_t)l * 128 * 128;
    for (int idx = t; idx < 128 * 128; idx += 256) {
        int n = idx >> 7, k = idx & 127;
        float w = (n < 64) ? W1[(size_t)k * 64 + n] : W1[(size_t)(k + 128) * 64 + (n - 64)];
        T1[n * 128 + k] = f2bf(w);
    }
    const float* Wn1l = Wn1 + (size_t)l * 192 * 64;
    unsigned short* Tn1 = Wn1t + (size_t)l * 64 * 192;
    for (int idx = t; idx < 64 * 192; idx += 256) {
        int n = idx / 192, k = idx - n * 192;
        Tn1[idx] = f2bf(Wn1l[(size_t)k * 64 + n]);
    }
    const float* Wn2l = Wn2 + (size_t)l * 64 * 128;
    unsigned short* Tn2 = Wn2t + (size_t)l * 128 * 64;
    for (int idx = t; idx < 128 * 64; idx += 256) {
        int n = idx >> 6, k = idx & 63;
        Tn2[idx] = f2bf(Wn2l[(size_t)k * 128 + n]);
    }
}

// ---------------------------------------------------------------------------
// node_pre (layer 0 only): [Pa|Pb] = s @ [We1a|We1b] (+be1 on Pa), bf16 out
// ---------------------------------------------------------------------------
__global__ __launch_bounds__(256) void node_pre_kernel(
    const float* __restrict__ s, const unsigned short* __restrict__ We1t,
    const float* __restrict__ be1,
    unsigned short* __restrict__ Pa, unsigned short* __restrict__ Pb, int N)
{
    __shared__ unsigned short sa[64 * 136];
    int t = threadIdx.x;
    int n0 = blockIdx.x * 64;
    for (int idx = t; idx < 64 * 32; idx += 256) {
        int rn = idx >> 5, c4 = (idx & 31) << 2;
        int n = n0 + rn;
        float4 val = make_float4(0.f, 0.f, 0.f, 0.f);
        if (n < N) val = *(const float4*)(s + (size_t)n * SDIM + c4);
        unsigned int p0 = (unsigned int)f2bf(val.x) | ((unsigned int)f2bf(val.y) << 16);
        unsigned int p1 = (unsigned int)f2bf(val.z) | ((unsigned int)f2bf(val.w) << 16);
        *(uint2*)(sa + rn * 136 + c4) = make_uint2(p0, p1);
    }
    __syncthreads();
    int lane = t & 63, w = t >> 6;
    int lm = lane & 15, lq = lane >> 4;
    int m0 = w * 16, rm = m0 + lm;

    bf16x8 af[4];
#pragma unroll
    for (int kc = 0; kc < 4; ++kc)
        af[kc] = *(const bf16x8*)(sa + rm * 136 + kc * 32 + lq * 8);

#pragma unroll
    for (int ct = 0; ct < 8; ++ct) {
        int col = ct * 16 + lm;
        f32x4 acc = {0.f, 0.f, 0.f, 0.f};
#pragma unroll
        for (int kc = 0; kc < 4; ++kc) {
            bf16x8 b = *(const bf16x8*)(We1t + (size_t)col * 128 + kc * 32 + lq * 8);
            acc = __builtin_amdgcn_mfma_f32_16x16x32_bf16(af[kc], b, acc, 0, 0, 0);
        }
        float bias = (ct < 4) ? be1[col] : 0.0f;
#pragma unroll
        for (int g = 0; g < 4; ++g) {
            int n = n0 + m0 + lq * 4 + g;
            if (n < N) {
                if (ct < 4) Pa[(size_t)n * HID + col]        = f2bf(acc[g] + bias);
                else        Pb[(size_t)n * HID + (col - 64)] = f2bf(acc[g]);
            }
        }
    }
}

// ---------------------------------------------------------------------------
// Fused edge kernel (dst-sorted, segmented reduction, boundary atomics).
// hb in LDS as bf16 (stride 72 -> 16B-aligned rows); v[src] staged row-wise.
// ---------------------------------------------------------------------------
__global__ __launch_bounds__(256) void edge_kernel(
    const float* __restrict__ rec,
    const unsigned short* __restrict__ Pa, const unsigned short* __restrict__ Pb,
    const float* __restrict__ wd,
    const unsigned short* __restrict__ We2t, const float* __restrict__ be2,
    const unsigned short* __restrict__ Wvt, const float* __restrict__ bv,
    const float* __restrict__ v,
    float* __restrict__ agg_s, float* __restrict__ agg_v, int E)
{
    __shared__ unsigned short hb[64 * 72];   // h bf16, stride 72 shorts (144B)
    __shared__ float gl[64 * 8];
    __shared__ float vb[64 * 12];            // v[src] rows (9 used, pad 12)
    __shared__ int   m_src[64], m_dst[64];
    __shared__ float m_d[64], m_C[64];
    __shared__ float m_r[64 * 3];
    int t = threadIdx.x;
    int e0 = blockIdx.x * 64;
    if (t < 64) {
        int e = e0 + t;
        int ec = (e < E) ? e : (E - 1);
        float4 r0 = *(const float4*)(rec + (size_t)ec * 8);
        float4 r1 = *(const float4*)(rec + (size_t)ec * 8 + 4);
        m_src[t] = __float_as_int(r0.x);
        m_dst[t] = __float_as_int(r0.y);
        m_d[t]   = r0.z;
        m_C[t]   = (e < E) ? r0.w : 0.0f;
        m_r[t*3+0] = r1.x; m_r[t*3+1] = r1.y; m_r[t*3+2] = r1.z;
    }
    __syncthreads();

    int lane = t & 63;
    int w    = t >> 6;
    int lm = lane & 15, lq = lane >> 4;
    int m0 = w * 16;
    int rm = m0 + lm;
    int ka = lq * 8;
    int kb = 32 + lq * 8;

    // ---- stage v[src] rows into LDS (3 requests/row; consumed after hb barrier) ----
    if (t < 64) {
        const float* vr = v + (size_t)m_src[t] * 9;
        float4_u a = *(const float4_u*)vr;
        float4_u b = *(const float4_u*)(vr + 4);
        float c = vr[8];
        vb[t*12+0]=a.x; vb[t*12+1]=a.y; vb[t*12+2]=a.z; vb[t*12+3]=a.w;
        vb[t*12+4]=b.x; vb[t*12+5]=b.y; vb[t*12+6]=b.z; vb[t*12+7]=b.w;
        vb[t*12+8]=c;
    }
    // ---- prefetch Wv^T fragments (consumed after phase 2) ----
    bf16x8 wv0 = *(const bf16x8*)(Wvt + (size_t)lm * 64 + ka);
    bf16x8 wv1 = *(const bf16x8*)(Wvt + (size_t)lm * 64 + kb);

    // ---- phase 1: h1 in MFMA A-layout, registers only (bf16 gathers) ----
    bf16x8 afr0, afr1;
    {
        int dstr = m_dst[rm], srcr = m_src[rm];
        float dv = m_d[rm];
        const unsigned short* pa = Pa + (size_t)dstr * HID;
        const unsigned short* pb = Pb + (size_t)srcr * HID;
        bf16x8 ba0 = *(const bf16x8*)(pa + ka);
        bf16x8 bb0 = *(const bf16x8*)(pb + ka);
        bf16x8 ba1 = *(const bf16x8*)(pa + kb);
        bf16x8 bb1 = *(const bf16x8*)(pb + kb);
        f8 xw = load8(wd + ka), yw = load8(wd + kb);
        float fa[8], fb[8], h1[8];
        unpack8(ba0, fa); unpack8(bb0, fb);
#pragma unroll
        for (int j = 0; j < 8; ++j) h1[j] = silu_f(fa[j] + fb[j] + dv * xw.v[j]);
        afr0 = pack8(h1);
        unpack8(ba1, fa); unpack8(bb1, fb);
#pragma unroll
        for (int j = 0; j < 8; ++j) h1[j] = silu_f(fa[j] + fb[j] + dv * yw.v[j]);
        afr1 = pack8(h1);
    }

    // ---- phase 2: h = silu(h1@We2+be2)*C via MFMA -> hb bf16 ----
#pragma unroll
    for (int t4 = 0; t4 < 4; ++t4) {
        int col = t4 * 16 + lm;
        bf16x8 b0 = *(const bf16x8*)(We2t + (size_t)col * 64 + ka);
        bf16x8 b1 = *(const bf16x8*)(We2t + (size_t)col * 64 + kb);
        f32x4 a = {0.f, 0.f, 0.f, 0.f};
        a = __builtin_amdgcn_mfma_f32_16x16x32_bf16(afr0, b0, a, 0, 0, 0);
        a = __builtin_amdgcn_mfma_f32_16x16x32_bf16(afr1, b1, a, 0, 0, 0);
        float bias = be2[col];
#pragma unroll
        for (int g = 0; g < 4; ++g) {
            int er = m0 + lq * 4 + g;
            hb[er * 72 + col] = f2bf(silu_f(a[g] + bias) * m_C[er]);
        }
    }
    __syncthreads();

    // ---- gates = h @ Wv + bv via MFMA (A-frags straight from bf16 LDS) ----
    {
        bf16x8 ga0 = *(const bf16x8*)(hb + rm * 72 + ka);
        bf16x8 ga1 = *(const bf16x8*)(hb + rm * 72 + kb);
        f32x4 ga = {0.f, 0.f, 0.f, 0.f};
        ga = __builtin_amdgcn_mfma_f32_16x16x32_bf16(ga0, wv0, ga, 0, 0, 0);
        ga = __builtin_amdgcn_mfma_f32_16x16x32_bf16(ga1, wv1, ga, 0, 0, 0);
        if (lm < 6) {
            float bias = bv[lm];
#pragma unroll
            for (int g = 0; g < 4; ++g) {
                int er = m0 + lq * 4 + g;
                gl[er * 8 + lm] = ga[g] + bias;
            }
        }
    }

    // ---- agg_s: segmented column-sum over dst runs (bf16 reads) ----
    {
        int c = t & 63, seg = t >> 6;
        int r0 = seg * 16;
        float acc = 0.f;
        int cur = m_dst[r0];
#pragma unroll 4
        for (int r = r0; r < r0 + 16; ++r) {
            int dr = m_dst[r];
            if (dr != cur) {
                atomicAdd(&agg_s[(size_t)cur * HID + c], acc);
                acc = 0.f; cur = dr;
            }
            acc += bf2f(hb[r * 72 + c]);
        }
        atomicAdd(&agg_s[(size_t)cur * HID + c], acc);
    }
    __syncthreads();

    // ---- agg_v: mv = v[src]*g1 + r*g2, segmented sum (v rows from LDS) ----
    if (t < 144) {
        int seg = t / 9;
        int c = t - seg * 9;
        int i = c / 3, j = c - i * 3;
        int r0 = seg * 4;
        float acc = 0.f;
        int cur = m_dst[r0];
#pragma unroll
        for (int r = 0; r < 4; ++r) {
            int rr = r0 + r;
            int dr = m_dst[rr];
            if (dr != cur) {
                atomicAdd(&agg_v[(size_t)cur * 9 + c], acc);
                acc = 0.f; cur = dr;
            }
            if (e0 + rr < E) {
                acc += vb[rr * 12 + c] * gl[rr * 8 + j]
                     + m_r[rr * 3 + i] * gl[rr * 8 + 3 + j];
            }
        }
        atomicAdd(&agg_v[(size_t)cur * 9 + c], acc);
    }
}

// ---------------------------------------------------------------------------
// Fused node kernel: u = silu([s,agg_s]@Wn1+bn1); s += u@Wn2+bn2;
// v += agg_v/deg; then (do_pre) [Pa|Pb] = s_new @ We1(l+1) (bf16 out).
// Zeroes agg_s/agg_v for the next layer (zero-after-read).
// ---------------------------------------------------------------------------
__global__ __launch_bounds__(256) void node_fused_kernel(
    float* __restrict__ s, float* __restrict__ vout,
    float* __restrict__ agg_s, float* __restrict__ agg_v,
    const int* __restrict__ row_start,
    const unsigned short* __restrict__ Wn1t, const float* __restrict__ bn1,
    const unsigned short* __restrict__ Wn2t, const float* __restrict__ bn2,
    const unsigned short* __restrict__ We1tn, const float* __restrict__ be1n,
    unsigned short* __restrict__ Pa, unsigned short* __restrict__ Pb,
    int N, int do_pre)
{
    __shared__ unsigned short xa[64 * 200];  // phase A: [s|agg_s]; phase B alias: s_new (stride 136)
    __shared__ unsigned short ub[64 * 72];
    int t = threadIdx.x;
    int n0 = blockIdx.x * 64;
    for (int idx = t; idx < 64 * 32; idx += 256) {
        int rn = idx >> 5, c4 = (idx & 31) << 2;
        int n = n0 + rn;
        float4 val = make_float4(0.f, 0.f, 0.f, 0.f);
        if (n < N) val = *(const float4*)(s + (size_t)n * SDIM + c4);
        unsigned int p0 = (unsigned int)f2bf(val.x) | ((unsigned int)f2bf(val.y) << 16);
        unsigned int p1 = (unsigned int)f2bf(val.z) | ((unsigned int)f2bf(val.w) << 16);
        *(uint2*)(xa + rn * 200 + c4) = make_uint2(p0, p1);
    }
    for (int idx = t; idx < 64 * 16; idx += 256) {
        int rn = idx >> 4, c4 = (idx & 15) << 2;
        int n = n0 + rn;
        float4 val = make_float4(0.f, 0.f, 0.f, 0.f);
        if (n < N) {
            float* ap = agg_s + (size_t)n * HID + c4;
            val = *(const float4*)ap;
            *(float4*)ap = make_float4(0.f, 0.f, 0.f, 0.f);   // zero for next layer
        }
        unsigned int p0 = (unsigned int)f2bf(val.x) | ((unsigned int)f2bf(val.y) << 16);
        unsigned int p1 = (unsigned int)f2bf(val.z) | ((unsigned int)f2bf(val.w) << 16);
        *(uint2*)(xa + rn * 200 + 128 + c4) = make_uint2(p0, p1);
    }
    __syncthreads();

    int lane = t & 63, w = t >> 6;
    int lm = lane & 15, lq = lane >> 4;
    int m0 = w * 16, rm = m0 + lm;

    // ---- GEMM1: u = silu(x @ Wn1 + bn1) ----
    bf16x8 af[6];
#pragma unroll
    for (int kc = 0; kc < 6; ++kc)
        af[kc] = *(const bf16x8*)(xa + rm * 200 + kc * 32 + lq * 8);

#pragma unroll
    for (int ct = 0; ct < 4; ++ct) {
        int col = ct * 16 + lm;
        f32x4 acc = {0.f, 0.f, 0.f, 0.f};
#pragma unroll
        for (int kc = 0; kc < 6; ++kc) {
            bf16x8 b = *(const bf16x8*)(Wn1t + (size_t)col * 192 + kc * 32 + lq * 8);
            acc = __builtin_amdgcn_mfma_f32_16x16x32_bf16(af[kc], b, acc, 0, 0, 0);
        }
        float bias = bn1[col];
#pragma unroll
        for (int g = 0; g < 4; ++g) {
            int er = m0 + lq * 4 + g;
            ub[er * 72 + col] = f2bf(silu_f(acc[g] + bias));
        }
    }
    __syncthreads();   // ub ready; xa reads done -> reusable

    // ---- GEMM2: s_new = s + u @ Wn2 + bn2 ; stash s_new bf16 in LDS ----
    unsigned short* sa = xa;   // alias (stride 136)
    bf16x8 uf[2];
#pragma unroll
    for (int kc = 0; kc < 2; ++kc)
        uf[kc] = *(const bf16x8*)(ub + rm * 72 + kc * 32 + lq * 8);

#pragma unroll
    for (int ct = 0; ct < 8; ++ct) {
        int col = ct * 16 + lm;
        f32x4 acc = {0.f, 0.f, 0.f, 0.f};
#pragma unroll
        for (int kc = 0; kc < 2; ++kc) {
            bf16x8 b = *(const bf16x8*)(Wn2t + (size_t)col * 64 + kc * 32 + lq * 8);
            acc = __builtin_amdgcn_mfma_f32_16x16x32_bf16(uf[kc], b, acc, 0, 0, 0);
        }
        float bias = bn2[col];
#pragma unroll
        for (int g = 0; g < 4; ++g) {
            int er = m0 + lq * 4 + g;
            int n = n0 + er;
            if (n < N) {
                float* sp = s + (size_t)n * SDIM + col;
                float sv = *sp + acc[g] + bias;
                *sp = sv;
                sa[er * 136 + col] = f2bf(sv);
            } else {
                sa[er * 136 + col] = 0;
            }
        }
    }
    __syncthreads();   // sa ready

    // ---- pre-GEMM for next layer: [Pa|Pb] = s_new @ We1(l+1) (bf16 out) ----
    if (do_pre) {
        bf16x8 pf[4];
#pragma unroll
        for (int kc = 0; kc < 4; ++kc)
            pf[kc] = *(const bf16x8*)(sa + rm * 136 + kc * 32 + lq * 8);

#pragma unroll
        for (int ct = 0; ct < 8; ++ct) {
            int col = ct * 16 + lm;
            f32x4 acc = {0.f, 0.f, 0.f, 0.f};
#pragma unroll
            for (int kc = 0; kc < 4; ++kc) {
                bf16x8 b = *(const bf16x8*)(We1tn + (size_t)col * 128 + kc * 32 + lq * 8);
                acc = __builtin_amdgcn_mfma_f32_16x16x32_bf16(pf[kc], b, acc, 0, 0, 0);
            }
            float bias = (ct < 4) ? be1n[col] : 0.0f;
#pragma unroll
            for (int g = 0; g < 4; ++g) {
                int n = n0 + m0 + lq * 4 + g;
                if (n < N) {
                    if (ct < 4) Pa[(size_t)n * HID + col]        = f2bf(acc[g] + bias);
                    else        Pb[(size_t)n * HID + (col - 64)] = f2bf(acc[g]);
                }
            }
        }
    }

    // ---- v += agg_v / max(deg,1) ; zero agg_v for next layer ----
    for (int idx = t; idx < 64 * 9; idx += 256) {
        int rn = idx / 9, c = idx - rn * 9;
        int n2 = n0 + rn;
        if (n2 < N) {
            float av = agg_v[(size_t)n2 * 9 + c];
            agg_v[(size_t)n2 * 9 + c] = 0.f;
            float dg = fmaxf((float)(row_start[n2 + 1] - row_start[n2]), 1.0f);
            vout[(size_t)n2 * 9 + c] += av / dg;
        }
    }
}

extern "C" void kernel_launch(void* const* d_in, const int* in_sizes, int n_in,
                              void* d_out, int out_size, void* d_ws, size_t ws_size,
                              hipStream_t stream)
{
    const float* s_in  = (const float*)d_in[0];
    const float* v_in  = (const float*)d_in[1];
    const void*  ei    = d_in[2];
    const float* d_vec = (const float*)d_in[3];
    const float* r_vec = (const float*)d_in[4];
    const float* We1 = (const float*)d_in[6];
    const float* be1 = (const float*)d_in[7];
    const float* We2 = (const float*)d_in[8];
    const float* be2 = (const float*)d_in[9];
    const float* Wn1 = (const float*)d_in[10];
    const float* bn1 = (const float*)d_in[11];
    const float* Wn2 = (const float*)d_in[12];
    const float* bn2 = (const float*)d_in[13];
    const float* Wv  = (const float*)d_in[14];
    const float* bv  = (const float*)d_in[15];

    int N = in_sizes[0] / SDIM;
    int E = in_sizes[3];

    float* out_s = (float*)d_out;
    float* out_v = out_s + (size_t)N * SDIM;

    // ------ workspace layout (32B-aligned blocks) ------
    char* wp = (char*)d_ws;
    auto alloc = [&wp](size_t bytes) -> char* {
        char* p = wp;
        wp += (bytes + 31) & ~(size_t)31;
        return p;
    };
    float* rec       = (float*)alloc((size_t)E * 8 * 4);
    unsigned short* Pa = (unsigned short*)alloc((size_t)N * HID * 2);
    unsigned short* Pb = (unsigned short*)alloc((size_t)N * HID * 2);
    float* agg_s     = (float*)alloc((size_t)N * HID * 4);   // contiguous with agg_v
    float* agg_v     = (float*)alloc((size_t)N * 9 * 4);
    int*   deg_i     = (int*)alloc((size_t)N * 4);           // contiguous with cursor
    int*   cursor    = (int*)alloc((size_t)N * 4);
    int*   row_start = (int*)alloc((size_t)(N + 1) * 4);
    int*   part      = (int*)alloc(64 * 4);
    int*   flag      = (int*)alloc(16);
    int*   srcw      = (int*)alloc((size_t)E * 4);
    int*   dstw      = (int*)alloc((size_t)E * 4);
    unsigned short* We2t = (unsigned short*)alloc((size_t)DEPTH * HID * HID * 2);
    unsigned short* Wvt  = (unsigned short*)alloc((size_t)DEPTH * 16 * 64 * 2);
    unsigned short* We1t = (unsigned short*)alloc((size_t)DEPTH * 128 * 128 * 2);
    unsigned short* Wn1t = (unsigned short*)alloc((size_t)DEPTH * 64 * 192 * 2);
    unsigned short* Wn2t = (unsigned short*)alloc((size_t)DEPTH * 128 * 64 * 2);

    hipMemcpyAsync(out_s, s_in, (size_t)N * SDIM * sizeof(float),
                   hipMemcpyDeviceToDevice, stream);
    hipMemcpyAsync(out_v, v_in, (size_t)N * 9 * sizeof(float),
                   hipMemcpyDeviceToDevice, stream);

    // ------ one-time prep ------
    detect_idx_kernel<<<1, 64, 0, stream>>>(ei, N, flag);
    hipMemsetAsync(deg_i, 0, (size_t)N * 2 * sizeof(int), stream);    // deg_i + cursor
    hipMemsetAsync(agg_s, 0, (size_t)N * (HID + 9) * sizeof(float), stream);
    decode_idx_kernel<<<(2 * E + 255) / 256, 256, 0, stream>>>(ei, E, N, flag,
                                                               srcw, dstw, deg_i);
    int B1 = (N + CHUNK - 1) / CHUNK;
    scan1_kernel<<<B1, 256, 0, stream>>>(deg_i, part, N);
    scan2_kernel<<<1, 64, 0, stream>>>(part, row_start, B1, N);
    scan3_kernel<<<B1, 256, 0, stream>>>(deg_i, part, row_start, N);
    scatter_kernel<<<(E + 255) / 256, 256, 0, stream>>>(srcw, dstw, d_vec, r_vec,
                                                        row_start, cursor, rec, E);
    wprep_kernel<<<DEPTH, 256, 0, stream>>>(We1, We2, Wv, Wn1, Wn2,
                                            We1t, We2t, Wvt, Wn1t, Wn2t);

    int nb_n = (N + 63) / 64;
    int nb_e = (E + 63) / 64;
    node_pre_kernel<<<nb_n, 256, 0, stream>>>(out_s, We1t, be1, Pa, Pb, N);
    for (int l = 0; l < DEPTH; ++l) {
        int ln = (l + 1 < DEPTH) ? (l + 1) : 0;
        const float* We1_l = We1 + (size_t)l * 257 * 64;
        const float* be2_l = be2 + (size_t)l * 64;
        const float* bn1_l = bn1 + (size_t)l * 64;
        const float* bn2_l = bn2 + (size_t)l * 128;
        const float* bv_l  = bv  + (size_t)l * 6;
        const float* be1_n = be1 + (size_t)ln * 64;
        const unsigned short* We2t_l = We2t + (size_t)l * HID * HID;
        const unsigned short* Wvt_l  = Wvt  + (size_t)l * 16 * 64;
        const unsigned short* Wn1t_l = Wn1t + (size_t)l * 64 * 192;
        const unsigned short* Wn2t_l = Wn2t + (size_t)l * 128 * 64;
        const unsigned short* We1t_n = We1t + (size_t)ln * 128 * 128;

        edge_kernel<<<nb_e, 256, 0, stream>>>(rec, Pa, Pb,
                                              We1_l + 256 * 64,
                                              We2t_l, be2_l, Wvt_l, bv_l,
                                              out_v, agg_s, agg_v, E);
        node_fused_kernel<<<nb_n, 256, 0, stream>>>(out_s, out_v, agg_s, agg_v,
                                                    row_start,
                                                    Wn1t_l, bn1_l, Wn2t_l, bn2_l,
                                                    We1t_n, be1_n, Pa, Pb,
                                                    N, (l + 1 < DEPTH) ? 1 : 0);
    }
}